// Round 10
// baseline (695.835 us; speedup 1.0000x reference)
//
#include <hip/hip_runtime.h>
#include <math.h>

#define FDIM 32
#define NBASIS 8
#define QP 40     // A-stage row pad (f16 units) -> 80B rows, 16B-aligned quads
#define EP 20     // D-stage edge-dim pad (f16 units)

constexpr float RCUT_C = 20.0f;
constexpr float PI_F = 3.14159265358979323846f;
constexpr float EV2KJ_C = 96.4853f;
constexpr float NM2A_C = 10.0f;

typedef _Float16 f16x8 __attribute__((ext_vector_type(8)));
typedef _Float16 f16x4 __attribute__((ext_vector_type(4)));
typedef float f32x4 __attribute__((ext_vector_type(4)));

__device__ __forceinline__ float sigmoidf_(float z) { return 1.0f / (1.0f + __expf(-z)); }

// ---------------- CSR build: histogram, scan, scatter ----------------
__global__ __launch_bounds__(256) void hist_dst(
    const int* __restrict__ eidx, int* __restrict__ counts, int E)
{
    for (int e = blockIdx.x * 256 + threadIdx.x; e < E; e += gridDim.x * 256)
        atomicAdd(&counts[eidx[E + e]], 1);
}

__global__ __launch_bounds__(1024) void scan_counts(
    const int* __restrict__ counts, int* __restrict__ cursor, int N)
{
    __shared__ int lds[1024];
    const int t = threadIdx.x;
    const int chunk = (N + 1023) / 1024;
    const int start = t * chunk;
    const int end = min(start + chunk, N);
    int local = 0;
    for (int i = start; i < end; i++) local += counts[i];
    lds[t] = local;
    __syncthreads();
    for (int off = 1; off < 1024; off <<= 1) {
        int v = (t >= off) ? lds[t - off] : 0;
        __syncthreads();
        lds[t] += v;
        __syncthreads();
    }
    int run = lds[t] - local;
    for (int i = start; i < end; i++) {
        cursor[i] = run;
        run += counts[i];
    }
}

__global__ __launch_bounds__(256) void scatter_edges(
    const int* __restrict__ eidx, int* __restrict__ cursor,
    int2* __restrict__ order_sd, int E)
{
    for (int e = blockIdx.x * 256 + threadIdx.x; e < E; e += gridDim.x * 256) {
        int dst = eidx[E + e];
        int p = atomicAdd(&cursor[dst], 1);
        order_sd[p] = make_int2(eidx[e], dst);
    }
}

// ---------------- edge forward: dual-MFMA, LDS-aliased, 4 tiles/wave ----------------
__global__ __launch_bounds__(256) void edge_fwd_mfma(
    const float* __restrict__ pos, const int* __restrict__ types,
    const int2* __restrict__ order_sd,
    const float* __restrict__ Wr1, const float* __restrict__ br1,
    const float* __restrict__ Wr2, const float* __restrict__ temb,
    float* __restrict__ s_acc, float* __restrict__ v_acc, int E)
{
    __shared__ union UAD {
        _Float16 A[4][16][QP];
        _Float16 D[4][64][EP];
    } u;
    __shared__ _Float16 sQ[4][16][QP];
    __shared__ float sSt[4][16][4];         // env, rhx, rhy, rhz

    const int lane = threadIdx.x & 63;
    const int l32 = threadIdx.x & 31;
    const int hw = (threadIdx.x >> 5) & 1;
    const int w = threadIdx.x >> 6;
    const int base_w = blockIdx.x * 256 + w * 64;

    const float te0 = temb[l32], te1 = temb[FDIM + l32], te2 = temb[2 * FDIM + l32];

    const int kb = (lane >> 4) * 8, nb = lane & 15;
    f16x8 bz[2];
    #pragma unroll
    for (int t = 0; t < 2; t++)
        #pragma unroll
        for (int j = 0; j < 8; j++) {
            int k = kb + j;
            bz[t][j] = (k < 8) ? (_Float16)Wr1[k * FDIM + t * 16 + nb] : (_Float16)0.0f;
        }
    f16x8 bf[4];
    #pragma unroll
    for (int t = 0; t < 4; t++)
        #pragma unroll
        for (int j = 0; j < 8; j++)
            bf[t][j] = (_Float16)Wr2[(kb + j) * 64 + t * 16 + nb];

    const float bb0 = br1[lane & 15], bb1 = br1[16 + (lane & 15)];

    int runKey = -1;
    float sAcc = 0.f, vXA = 0.f, vYA = 0.f, vZA = 0.f;

    for (int tile = 0; tile < 4; tile++) {
        const int base = base_w + tile * 16;
        if (base >= E) break;

        // ---- phase 0: lane-parallel geometry + basis (lanes 0..15) ----
        if (lane < 16) {
            const int p = base + lane;
            int2 sd = (p < E) ? order_sd[p] : make_int2(0, 0);
            float rx = (pos[sd.y * 3 + 0] - pos[sd.x * 3 + 0]) * NM2A_C;
            float ry = (pos[sd.y * 3 + 1] - pos[sd.x * 3 + 1]) * NM2A_C;
            float rz = (pos[sd.y * 3 + 2] - pos[sd.x * 3 + 2]) * NM2A_C;
            float r2 = rx * rx + ry * ry + rz * rz + 1e-12f;
            float r = sqrtf(r2);
            float rinv = 1.0f / r;
            float x = r * (1.0f / RCUT_C);
            float x2 = x * x, x4 = x2 * x2, x6 = x4 * x2, x7 = x6 * x, x8 = x6 * x2;
            float env = (x < 1.0f) ? (1.0f - 28.0f * x6 + 48.0f * x7 - 21.0f * x8) : 0.0f;

            float th = PI_F * x, s1, c1;
            __sincosf(th, &s1, &c1);
            float sp = 0.0f, sn = s1;
            _Float16 av[8];
            #pragma unroll
            for (int n = 0; n < NBASIS; n++) {
                av[n] = (_Float16)(sn * rinv);
                float snx = 2.0f * c1 * sn - sp; sp = sn; sn = snx;
            }
            *(f16x8*)&u.A[w][lane][0] = *(f16x8*)&av[0];
            *(float4*)&u.A[w][lane][8]  = make_float4(0.f, 0.f, 0.f, 0.f);
            *(float4*)&u.A[w][lane][16] = make_float4(0.f, 0.f, 0.f, 0.f);
            *(float4*)&u.A[w][lane][24] = make_float4(0.f, 0.f, 0.f, 0.f);
            sSt[w][lane][0] = env;
            sSt[w][lane][1] = rx * rinv;
            sSt[w][lane][2] = ry * rinv;
            sSt[w][lane][3] = rz * rinv;
        }

        // ---- phase 1: MFMA basis layer -> z, silu -> sQ ----
        {
            f16x8 a1 = *(const f16x8*)&u.A[w][lane & 15][kb];
            const f32x4 z4 = {0.f, 0.f, 0.f, 0.f};
            f32x4 Dz0 = __builtin_amdgcn_mfma_f32_16x16x32_f16(a1, bz[0], z4, 0, 0, 0);
            f32x4 Dz1 = __builtin_amdgcn_mfma_f32_16x16x32_f16(a1, bz[1], z4, 0, 0, 0);
            const int f0 = lane & 15, e0 = (lane >> 4) * 4;
            #pragma unroll
            for (int t = 0; t < 2; t++) {
                f32x4 Dz = t ? Dz1 : Dz0;
                float bb = t ? bb1 : bb0;
                #pragma unroll
                for (int r = 0; r < 4; r++) {
                    float z = Dz[r] + bb;
                    float q = z * sigmoidf_(z);
                    sQ[w][e0 + r][t * 16 + f0] = (_Float16)q;
                }
            }
        }

        // ---- phase 2: MFMA W2 -> D ----
        {
            f16x8 aq = *(const f16x8*)&sQ[w][lane & 15][kb];
            const f32x4 z4 = {0.f, 0.f, 0.f, 0.f};
            const int cb = lane & 15, e0 = (lane >> 4) * 4;
            #pragma unroll
            for (int t = 0; t < 4; t++) {
                f32x4 d = __builtin_amdgcn_mfma_f32_16x16x32_f16(aq, bf[t], z4, 0, 0, 0);
                f16x4 dh;
                #pragma unroll
                for (int r = 0; r < 4; r++) dh[r] = (_Float16)d[r];
                *(f16x4*)&u.D[w][t * 16 + cb][e0] = dh;
            }
        }

        // ---- phase 3: epilogue (run-merge carried across tiles) ----
        #pragma unroll
        for (int i = 0; i < 8; i++) {
            const int m = hw * 8 + i;
            const int p = base + m;
            if (p >= E) break;
            int2 sd = order_sd[p];
            if (sd.y != runKey) {
                if (runKey >= 0) {
                    unsafeAtomicAdd(&s_acc[(size_t)runKey * 32 + l32], sAcc);
                    unsafeAtomicAdd(&v_acc[(size_t)runKey * 96 + 0 * 32 + l32], vXA);
                    unsafeAtomicAdd(&v_acc[(size_t)runKey * 96 + 1 * 32 + l32], vYA);
                    unsafeAtomicAdd(&v_acc[(size_t)runKey * 96 + 2 * 32 + l32], vZA);
                }
                runKey = sd.y;
                sAcc = vXA = vYA = vZA = 0.f;
            }
            float env = sSt[w][m][0], rhx = sSt[w][m][1], rhy = sSt[w][m][2], rhz = sSt[w][m][3];
            float rw0 = (float)u.D[w][l32][m];
            float rw1 = (float)u.D[w][32 + l32][m];
            int tyi = types[sd.x];
            float hs = (tyi == 0) ? te0 : ((tyi == 1) ? te1 : te2);
            sAcc += hs * rw0 * env;
            float hw1 = hs * rw1 * env;
            vXA += hw1 * rhx; vYA += hw1 * rhy; vZA += hw1 * rhz;
        }
    }
    if (runKey >= 0) {
        unsafeAtomicAdd(&s_acc[(size_t)runKey * 32 + l32], sAcc);
        unsafeAtomicAdd(&v_acc[(size_t)runKey * 96 + 0 * 32 + l32], vXA);
        unsafeAtomicAdd(&v_acc[(size_t)runKey * 96 + 1 * 32 + l32], vYA);
        unsafeAtomicAdd(&v_acc[(size_t)runKey * 96 + 2 * 32 + l32], vZA);
    }
}

// -------- atom MLP: 64 atoms/block, weights preloaded once --------
__global__ __launch_bounds__(256) void atom_mlp(
    const int* __restrict__ types, const float* __restrict__ temb,
    const float* __restrict__ Wself, const float* __restrict__ Wo1,
    const float* __restrict__ bo1, const float* __restrict__ Wo2,
    float* __restrict__ s_acc, float* __restrict__ v_acc,
    float* __restrict__ e_partial, int N)
{
    __shared__ float sWs[FDIM * FDIM], sWsT[FDIM * FDIM];
    __shared__ float sWo1[2 * FDIM * FDIM], sWo1T[2 * FDIM * FDIM];
    __shared__ float sb[FDIM], sW2o[FDIM], sTE[96];
    __shared__ float gred[8];
    for (int i = threadIdx.x; i < FDIM * FDIM; i += 256) {
        sWs[i] = Wself[i];
        sWsT[i] = Wself[(i & 31) * FDIM + (i >> 5)];
    }
    for (int i = threadIdx.x; i < 2 * FDIM * FDIM; i += 256) {
        sWo1[i] = Wo1[i];
        sWo1T[i] = Wo1[(i & 63) * FDIM + (i >> 6)];
    }
    for (int i = threadIdx.x; i < FDIM; i += 256) { sb[i] = bo1[i]; sW2o[i] = Wo2[i]; }
    for (int i = threadIdx.x; i < 96; i += 256) sTE[i] = temb[i];
    __syncthreads();

    const int lane = threadIdx.x & 31;
    const int g = threadIdx.x >> 5;
    float eAcc = 0.0f;

    for (int it = 0; it < 8; it++) {
        int a = blockIdx.x * 64 + it * 8 + g;
        const bool valid = (a < N);
        if (!valid) a = 0;

        float sv = s_acc[(size_t)a * FDIM + lane];
        float vx = v_acc[(size_t)a * 96 + 0 * 32 + lane];
        float vy = v_acc[(size_t)a * 96 + 1 * 32 + lane];
        float vz = v_acc[(size_t)a * 96 + 2 * 32 + lane];
        float h = sTE[types[a] * FDIM + lane];
        float vn = sqrtf(vx * vx + vy * vy + vz * vz + 1e-12f);

        float row = h;
        #pragma unroll
        for (int f = 0; f < FDIM; f++) {
            float t = __shfl(sv, f, 32);
            row += t * sWs[f * FDIM + lane];
        }
        float u = sb[lane];
        #pragma unroll
        for (int j = 0; j < FDIM; j++) {
            float rv = __shfl(row, j, 32);
            float vv = __shfl(vn, j, 32);
            u += rv * sWo1[j * FDIM + lane] + vv * sWo1[(j + FDIM) * FDIM + lane];
        }
        float sg = sigmoidf_(u);
        float au = u * sg;
        float pa = valid ? au * sW2o[lane] : 0.0f;
        #pragma unroll
        for (int m = 16; m; m >>= 1) pa += __shfl_xor(pa, m, 32);
        if (lane == 0) eAcc += pa;

        float gu = sW2o[lane] * (sg * (1.0f + u * (1.0f - sg)));
        float gfr = 0.0f, gfv = 0.0f;
        #pragma unroll
        for (int k = 0; k < FDIM; k++) {
            float gv_ = __shfl(gu, k, 32);
            gfr += gv_ * sWo1T[k * 64 + lane];
            gfv += gv_ * sWo1T[k * 64 + 32 + lane];
        }
        float gs = 0.0f;
        #pragma unroll
        for (int k = 0; k < FDIM; k++) {
            float gr = __shfl(gfr, k, 32);
            gs += gr * sWsT[k * FDIM + lane];
        }
        if (valid) {
            s_acc[(size_t)a * FDIM + lane] = gs;
            float sc = gfv / vn;
            v_acc[(size_t)a * 96 + 0 * 32 + lane] = sc * vx;
            v_acc[(size_t)a * 96 + 1 * 32 + lane] = sc * vy;
            v_acc[(size_t)a * 96 + 2 * 32 + lane] = sc * vz;
        }
    }
    if (lane == 0) gred[g] = eAcc;
    __syncthreads();
    if (threadIdx.x == 0) {
        float t = 0.0f;
        #pragma unroll
        for (int i = 0; i < 8; i++) t += gred[i];
        e_partial[blockIdx.x] = t;
    }
}

// ---------------- edge backward: dual-MFMA, LDS-aliased, gm run-cache, 4 tiles/wave ----------------
__global__ __launch_bounds__(256) void edge_bwd_mfma(
    const float* __restrict__ pos, const int* __restrict__ types,
    const int2* __restrict__ order_sd,
    const float* __restrict__ Wr1, const float* __restrict__ br1,
    const float* __restrict__ Wr2, const float* __restrict__ temb,
    const float* __restrict__ g_s, const float* __restrict__ g_v,
    float* __restrict__ forces, int E)
{
    __shared__ union UA {
        _Float16 A[4][16][QP];
        _Float16 Dq[4][64][EP];
    } u1;
    __shared__ union UB {
        _Float16 Q[4][16][QP];
        _Float16 Dt[4][64][EP];
    } u2;
    __shared__ _Float16 sT[4][16][QP];
    __shared__ float sSt[4][16][8];       // rinv, env, denv, rhx, rhy, rhz

    const int lane = threadIdx.x & 63;
    const int l32 = threadIdx.x & 31;
    const int hw = (threadIdx.x >> 5) & 1;
    const int w = threadIdx.x >> 6;
    const int base_w = blockIdx.x * 256 + w * 64;

    const float te0 = temb[l32], te1 = temb[FDIM + l32], te2 = temb[2 * FDIM + l32];

    const int kb = (lane >> 4) * 8, nb = lane & 15;
    f16x8 bz[2], bt[2];
    #pragma unroll
    for (int t = 0; t < 2; t++)
        #pragma unroll
        for (int j = 0; j < 8; j++) {
            int k = kb + j;
            bz[t][j] = (k < 8) ? (_Float16)Wr1[k * FDIM + t * 16 + nb] : (_Float16)0.0f;
            bt[t][j] = (k >= 8 && k < 16) ? (_Float16)Wr1[(k - 8) * FDIM + t * 16 + nb] : (_Float16)0.0f;
        }
    f16x8 bf[4];
    #pragma unroll
    for (int t = 0; t < 4; t++)
        #pragma unroll
        for (int j = 0; j < 8; j++)
            bf[t][j] = (_Float16)Wr2[(kb + j) * 64 + t * 16 + nb];

    const float bb0 = br1[lane & 15], bb1 = br1[16 + (lane & 15)];
    const float SC = EV2KJ_C * NM2A_C;

    int runKey = -1;
    float fAcc = 0.f;
    float gm0 = 0.f, gm1x = 0.f, gm1y = 0.f, gm1z = 0.f;

    for (int tile = 0; tile < 4; tile++) {
        const int base = base_w + tile * 16;
        if (base >= E) break;

        // ---- phase 0: lane-parallel geometry + basis/dbasis ----
        if (lane < 16) {
            const int p = base + lane;
            int2 sd = (p < E) ? order_sd[p] : make_int2(0, 0);
            float rx = (pos[sd.y * 3 + 0] - pos[sd.x * 3 + 0]) * NM2A_C;
            float ry = (pos[sd.y * 3 + 1] - pos[sd.x * 3 + 1]) * NM2A_C;
            float rz = (pos[sd.y * 3 + 2] - pos[sd.x * 3 + 2]) * NM2A_C;
            float r2 = rx * rx + ry * ry + rz * rz + 1e-12f;
            float r = sqrtf(r2);
            float rinv = 1.0f / r;
            float x = r * (1.0f / RCUT_C);
            float x2 = x * x, x4 = x2 * x2, x5 = x4 * x, x6 = x4 * x2, x7 = x6 * x, x8 = x6 * x2;
            float env = (x < 1.0f) ? (1.0f - 28.0f * x6 + 48.0f * x7 - 21.0f * x8) : 0.0f;
            float denv = (x < 1.0f) ? (-168.0f * x5 + 336.0f * x6 - 168.0f * x7) * (1.0f / RCUT_C) : 0.0f;

            float th = PI_F * x, s1, c1;
            __sincosf(th, &s1, &c1);
            float sp = 0.0f, sn = s1, cp = 1.0f, cn = c1;
            _Float16 av[16];
            #pragma unroll
            for (int n = 0; n < NBASIS; n++) {
                float basis = sn * rinv;
                float dbdr = (PI_F * (float)(n + 1) * (1.0f / RCUT_C)) * cn * rinv - basis * rinv;
                av[n] = (_Float16)basis;
                av[8 + n] = (_Float16)dbdr;
                float snx = 2.0f * c1 * sn - sp; sp = sn; sn = snx;
                float cnx = 2.0f * c1 * cn - cp; cp = cn; cn = cnx;
            }
            *(f16x8*)&u1.A[w][lane][0] = *(f16x8*)&av[0];
            *(f16x8*)&u1.A[w][lane][8] = *(f16x8*)&av[8];
            *(float4*)&u1.A[w][lane][16] = make_float4(0.f, 0.f, 0.f, 0.f);
            *(float4*)&u1.A[w][lane][24] = make_float4(0.f, 0.f, 0.f, 0.f);
            sSt[w][lane][0] = rinv;
            sSt[w][lane][1] = env;
            sSt[w][lane][2] = denv;
            sSt[w][lane][3] = rx * rinv;
            sSt[w][lane][4] = ry * rinv;
            sSt[w][lane][5] = rz * rinv;
        }

        // ---- phase 1: MFMA basis layer -> z, tacc; silu/tf -> Q/T ----
        {
            f16x8 a1 = *(const f16x8*)&u1.A[w][lane & 15][kb];
            const f32x4 z4 = {0.f, 0.f, 0.f, 0.f};
            f32x4 Dz0 = __builtin_amdgcn_mfma_f32_16x16x32_f16(a1, bz[0], z4, 0, 0, 0);
            f32x4 Dz1 = __builtin_amdgcn_mfma_f32_16x16x32_f16(a1, bz[1], z4, 0, 0, 0);
            f32x4 Dt0 = __builtin_amdgcn_mfma_f32_16x16x32_f16(a1, bt[0], z4, 0, 0, 0);
            f32x4 Dt1 = __builtin_amdgcn_mfma_f32_16x16x32_f16(a1, bt[1], z4, 0, 0, 0);
            const int f0 = lane & 15, e0 = (lane >> 4) * 4;
            #pragma unroll
            for (int t = 0; t < 2; t++) {
                f32x4 Dz = t ? Dz1 : Dz0;
                f32x4 Dt = t ? Dt1 : Dt0;
                float bb = t ? bb1 : bb0;
                #pragma unroll
                for (int r = 0; r < 4; r++) {
                    float z = Dz[r] + bb;
                    float sg = sigmoidf_(z);
                    float q = z * sg;
                    float tf = (sg * (1.0f + z * (1.0f - sg))) * Dt[r];
                    u2.Q[w][e0 + r][t * 16 + f0] = (_Float16)q;
                    sT[w][e0 + r][t * 16 + f0] = (_Float16)tf;
                }
            }
        }

        // ---- phase 2: 8 MFMAs (W2 on q and tf) ----
        {
            f16x8 aq = *(const f16x8*)&u2.Q[w][lane & 15][kb];
            f16x8 at = *(const f16x8*)&sT[w][lane & 15][kb];
            const f32x4 z4 = {0.f, 0.f, 0.f, 0.f};
            const int cb = lane & 15, e0 = (lane >> 4) * 4;
            #pragma unroll
            for (int t = 0; t < 4; t++) {
                f32x4 dq = __builtin_amdgcn_mfma_f32_16x16x32_f16(aq, bf[t], z4, 0, 0, 0);
                f32x4 dt = __builtin_amdgcn_mfma_f32_16x16x32_f16(at, bf[t], z4, 0, 0, 0);
                f16x4 hq, ht;
                #pragma unroll
                for (int r = 0; r < 4; r++) { hq[r] = (_Float16)dq[r]; ht[r] = (_Float16)dt[r]; }
                *(f16x4*)&u1.Dq[w][t * 16 + cb][e0] = hq;
                *(f16x4*)&u2.Dt[w][t * 16 + cb][e0] = ht;
            }
        }

        // ---- phase 3: epilogue (gm cached per dst-run, run carried across tiles) ----
        #pragma unroll
        for (int i = 0; i < 8; i++) {
            const int m = hw * 8 + i;
            const int p = base + m;
            if (p >= E) break;
            int2 sd = order_sd[p];
            if (sd.y != runKey) {
                if (runKey >= 0 && l32 < 3)
                    unsafeAtomicAdd(&forces[(size_t)runKey * 3 + l32], -SC * fAcc);
                runKey = sd.y;
                fAcc = 0.f;
                gm0  = g_s[(size_t)sd.y * FDIM + l32];
                gm1x = g_v[(size_t)sd.y * 96 + 0 * 32 + l32];
                gm1y = g_v[(size_t)sd.y * 96 + 1 * 32 + l32];
                gm1z = g_v[(size_t)sd.y * 96 + 2 * 32 + l32];
            }
            float rinv = sSt[w][m][0], env = sSt[w][m][1], denv = sSt[w][m][2];
            float rhx = sSt[w][m][3], rhy = sSt[w][m][4], rhz = sSt[w][m][5];
            float rw0 = (float)u1.Dq[w][l32][m];
            float rw1 = (float)u1.Dq[w][32 + l32][m];
            float u0  = (float)u2.Dt[w][l32][m];
            float u1v = (float)u2.Dt[w][32 + l32][m];

            int tyi = types[sd.x];
            float hs = (tyi == 0) ? te0 : ((tyi == 1) ? te1 : te2);

            float gw0 = hs * gm0;
            float gw1 = hs * (gm1x * rhx + gm1y * rhy + gm1z * rhz);
            float hw1 = hs * rw1 * env;
            float grx = hw1 * gm1x, gry = hw1 * gm1y, grz = hw1 * gm1z;
            float genv = gw0 * rw0 + gw1 * rw1;
            float pc = (gw0 * env) * u0 + (gw1 * env) * u1v + genv * denv;
            float pg = pc - (grx * rhx + gry * rhy + grz * rhz) * rinv;

            // channel-packed butterfly: lane%4 -> {Gx,Gy,Gz,beta}
            float a1 = grx + __shfl_xor(grx, 1, 32);
            float b1v = gry + __shfl_xor(gry, 1, 32);
            float c1v = grz + __shfl_xor(grz, 1, 32);
            float d1 = pg + __shfl_xor(pg, 1, 32);
            float e0v = (l32 & 1) ? b1v : a1;
            float e1v = (l32 & 1) ? d1 : c1v;
            e0v += __shfl_xor(e0v, 2, 32);
            e1v += __shfl_xor(e1v, 2, 32);
            float v = (l32 & 2) ? e1v : e0v;
            v += __shfl_xor(v, 4, 32);
            v += __shfl_xor(v, 8, 32);
            v += __shfl_xor(v, 16, 32);
            float beta = __shfl(v, l32 | 3, 32);

            if (l32 < 3) {
                float rh_l = (l32 == 0) ? rhx : ((l32 == 1) ? rhy : rhz);
                float comp = v * rinv + rh_l * beta;
                unsafeAtomicAdd(&forces[(size_t)sd.x * 3 + l32], SC * comp);
                fAcc += comp;
            }
        }
    }
    if (runKey >= 0 && l32 < 3)
        unsafeAtomicAdd(&forces[(size_t)runKey * 3 + l32], -SC * fAcc);
}

// ---------------- reductions & correction ----------------
__global__ __launch_bounds__(256) void reduce_energy(
    const float* __restrict__ e_partial, int n, float* __restrict__ out)
{
    __shared__ float red[256];
    float s = 0.0f;
    for (int i = threadIdx.x; i < n; i += 256) s += e_partial[i];
    red[threadIdx.x] = s;
    __syncthreads();
    for (int k = 128; k; k >>= 1) {
        if (threadIdx.x < k) red[threadIdx.x] += red[threadIdx.x + k];
        __syncthreads();
    }
    if (threadIdx.x == 0) out[0] = red[0] * EV2KJ_C;
}

__global__ __launch_bounds__(256) void reduce_net(
    const float* __restrict__ f, const float* __restrict__ masses,
    float* __restrict__ accum, int N)
{
    float nx = 0, ny = 0, nz = 0, ms = 0;
    for (int i = blockIdx.x * 256 + threadIdx.x; i < N; i += gridDim.x * 256) {
        nx += f[i * 3 + 0]; ny += f[i * 3 + 1]; nz += f[i * 3 + 2]; ms += masses[i];
    }
    #pragma unroll
    for (int m = 32; m; m >>= 1) {
        nx += __shfl_xor(nx, m, 64);
        ny += __shfl_xor(ny, m, 64);
        nz += __shfl_xor(nz, m, 64);
        ms += __shfl_xor(ms, m, 64);
    }
    __shared__ float red[4][4];
    int w = threadIdx.x >> 6;
    if ((threadIdx.x & 63) == 0) { red[w][0] = nx; red[w][1] = ny; red[w][2] = nz; red[w][3] = ms; }
    __syncthreads();
    if (threadIdx.x == 0) {
        float a0 = 0, a1 = 0, a2 = 0, a3 = 0;
        for (int i = 0; i < 4; i++) { a0 += red[i][0]; a1 += red[i][1]; a2 += red[i][2]; a3 += red[i][3]; }
        unsafeAtomicAdd(accum + 0, a0);
        unsafeAtomicAdd(accum + 1, a1);
        unsafeAtomicAdd(accum + 2, a2);
        unsafeAtomicAdd(accum + 3, a3);
    }
}

__global__ __launch_bounds__(256) void correct_forces(
    float* __restrict__ f, const float* __restrict__ masses,
    const float* __restrict__ accum, int N)
{
    int i = blockIdx.x * 256 + threadIdx.x;
    if (i < N) {
        float c = masses[i] / accum[3];
        f[i * 3 + 0] -= c * accum[0];
        f[i * 3 + 1] -= c * accum[1];
        f[i * 3 + 2] -= c * accum[2];
    }
}

extern "C" void kernel_launch(void* const* d_in, const int* in_sizes, int n_in,
                              void* d_out, int out_size, void* d_ws, size_t ws_size,
                              hipStream_t stream)
{
    (void)n_in; (void)ws_size;
    const float* pos    = (const float*)d_in[0];
    const float* masses = (const float*)d_in[1];
    const float* temb   = (const float*)d_in[2];
    const float* Wr1    = (const float*)d_in[3];
    const float* br1    = (const float*)d_in[4];
    const float* Wr2    = (const float*)d_in[5];
    const float* Wself  = (const float*)d_in[6];
    const float* Wo1    = (const float*)d_in[7];
    const float* bo1    = (const float*)d_in[8];
    const float* Wo2    = (const float*)d_in[9];
    const int* types    = (const int*)d_in[10];
    const int* eidx     = (const int*)d_in[11];
    const int N = in_sizes[1];
    const int E = in_sizes[11] / 2;

    float* out = (float*)d_out;
    float* forces = out + 1;

    float* ws = (float*)d_ws;
    float* s_acc = ws;                               // N*32
    float* v_acc = s_acc + (size_t)N * FDIM;         // N*96
    int nAtomBlocks = (N + 63) / 64;
    float* e_partial = v_acc + (size_t)N * 96;       // nAtomBlocks
    float* accum = e_partial + nAtomBlocks;          // 4
    int* counts = (int*)(accum + 4);                 // N
    int* cursor = counts + N;                        // N
    int2* order_sd = (int2*)(cursor + N);            // E int2

    hipMemsetAsync(d_out, 0, (size_t)out_size * sizeof(float), stream);
    hipMemsetAsync(s_acc, 0, (size_t)N * 128 * sizeof(float), stream);
    hipMemsetAsync(counts, 0, (size_t)N * sizeof(int), stream);
    hipMemsetAsync(accum, 0, 4 * sizeof(float), stream);

    hist_dst<<<2048, 256, 0, stream>>>(eidx, counts, E);
    scan_counts<<<1, 1024, 0, stream>>>(counts, cursor, N);
    scatter_edges<<<2048, 256, 0, stream>>>(eidx, cursor, order_sd, E);

    int nEdgeBlocks = (E + 255) / 256;
    edge_fwd_mfma<<<nEdgeBlocks, 256, 0, stream>>>(pos, types, order_sd,
                                                   Wr1, br1, Wr2, temb,
                                                   s_acc, v_acc, E);
    atom_mlp<<<nAtomBlocks, 256, 0, stream>>>(types, temb, Wself, Wo1, bo1, Wo2,
                                              s_acc, v_acc, e_partial, N);
    reduce_energy<<<1, 256, 0, stream>>>(e_partial, nAtomBlocks, out);
    edge_bwd_mfma<<<nEdgeBlocks, 256, 0, stream>>>(pos, types, order_sd,
                                                   Wr1, br1, Wr2, temb,
                                                   s_acc, v_acc, forces, E);
    reduce_net<<<64, 256, 0, stream>>>(forces, masses, accum, N);
    correct_forces<<<(N + 255) / 256, 256, 0, stream>>>(forces, masses, accum, N);
}

// Round 11
// 664.236 us; speedup vs baseline: 1.0476x; 1.0476x over previous
//
#include <hip/hip_runtime.h>
#include <math.h>

#define FDIM 32
#define NBASIS 8
#define QP 40     // A-stage row pad (f16 units) -> 80B rows, 16B-aligned quads
#define EP 20     // D-stage edge-dim pad (f16 units)
#define SCH 4096  // scan chunk per block (256 thr x 16)

constexpr float RCUT_C = 20.0f;
constexpr float PI_F = 3.14159265358979323846f;
constexpr float EV2KJ_C = 96.4853f;
constexpr float NM2A_C = 10.0f;

typedef _Float16 f16x8 __attribute__((ext_vector_type(8)));
typedef _Float16 f16x4 __attribute__((ext_vector_type(4)));
typedef float f32x4 __attribute__((ext_vector_type(4)));

__device__ __forceinline__ float sigmoidf_(float z) { return 1.0f / (1.0f + __expf(-z)); }

// ---------------- CSR build: histogram, 3-kernel scan, scatter ----------------
__global__ __launch_bounds__(256) void hist_dst(
    const int* __restrict__ eidx, int* __restrict__ counts, int E)
{
    for (int e = blockIdx.x * 256 + threadIdx.x; e < E; e += gridDim.x * 256)
        atomicAdd(&counts[eidx[E + e]], 1);
}

__global__ __launch_bounds__(256) void scan_partial(
    const int* __restrict__ counts, int* __restrict__ bsum, int N)
{
    __shared__ int red[256];
    const int t = threadIdx.x;
    const int st = blockIdx.x * SCH + t * 16;
    int s = 0;
    #pragma unroll
    for (int i = 0; i < 16; i++) { int idx = st + i; if (idx < N) s += counts[idx]; }
    red[t] = s;
    __syncthreads();
    for (int k = 128; k; k >>= 1) {
        if (t < k) red[t] += red[t + k];
        __syncthreads();
    }
    if (t == 0) bsum[blockIdx.x] = red[0];
}

__global__ __launch_bounds__(64) void scan_bsum(int* __restrict__ bsum, int nb)
{
    if (threadIdx.x == 0) {
        int run = 0;
        for (int i = 0; i < nb; i++) { int v = bsum[i]; bsum[i] = run; run += v; }
    }
}

__global__ __launch_bounds__(256) void scan_write(
    const int* __restrict__ counts, const int* __restrict__ bsum,
    int* __restrict__ cursor, int N)
{
    __shared__ int lds[256];
    const int t = threadIdx.x;
    const int st = blockIdx.x * SCH + t * 16;
    int vals[16];
    int s = 0;
    #pragma unroll
    for (int i = 0; i < 16; i++) {
        int idx = st + i;
        int v = (idx < N) ? counts[idx] : 0;
        vals[i] = v; s += v;
    }
    lds[t] = s;
    __syncthreads();
    for (int off = 1; off < 256; off <<= 1) {
        int v = (t >= off) ? lds[t - off] : 0;
        __syncthreads();
        lds[t] += v;
        __syncthreads();
    }
    int run = bsum[blockIdx.x] + lds[t] - s;   // exclusive prefix
    #pragma unroll
    for (int i = 0; i < 16; i++) {
        int idx = st + i;
        if (idx < N) cursor[idx] = run;
        run += vals[i];
    }
}

__global__ __launch_bounds__(256) void scatter_edges(
    const int* __restrict__ eidx, int* __restrict__ cursor,
    int2* __restrict__ order_sd, int E)
{
    for (int e = blockIdx.x * 256 + threadIdx.x; e < E; e += gridDim.x * 256) {
        int dst = eidx[E + e];
        int p = atomicAdd(&cursor[dst], 1);
        order_sd[p] = make_int2(eidx[e], dst);
    }
}

// ---------------- edge forward: dual-MFMA, LDS-aliased (r9 form) ----------------
__global__ __launch_bounds__(256) void edge_fwd_mfma(
    const float* __restrict__ pos, const int* __restrict__ types,
    const int2* __restrict__ order_sd,
    const float* __restrict__ Wr1, const float* __restrict__ br1,
    const float* __restrict__ Wr2, const float* __restrict__ temb,
    float* __restrict__ s_acc, float* __restrict__ v_acc, int E)
{
    __shared__ union UAD {
        _Float16 A[4][16][QP];
        _Float16 D[4][64][EP];
    } u;
    __shared__ _Float16 sQ[4][16][QP];
    __shared__ float sSt[4][16][4];         // env, rhx, rhy, rhz

    const int lane = threadIdx.x & 63;
    const int l32 = threadIdx.x & 31;
    const int hw = (threadIdx.x >> 5) & 1;
    const int w = threadIdx.x >> 6;
    const int base = blockIdx.x * 64 + w * 16;

    const float te0 = temb[l32], te1 = temb[FDIM + l32], te2 = temb[2 * FDIM + l32];

    const int kb = (lane >> 4) * 8, nb = lane & 15;
    f16x8 bz[2];
    #pragma unroll
    for (int t = 0; t < 2; t++)
        #pragma unroll
        for (int j = 0; j < 8; j++) {
            int k = kb + j;
            bz[t][j] = (k < 8) ? (_Float16)Wr1[k * FDIM + t * 16 + nb] : (_Float16)0.0f;
        }
    f16x8 bf[4];
    #pragma unroll
    for (int t = 0; t < 4; t++)
        #pragma unroll
        for (int j = 0; j < 8; j++)
            bf[t][j] = (_Float16)Wr2[(kb + j) * 64 + t * 16 + nb];

    // ---- phase 0: lane-parallel geometry + basis (lanes 0..15) ----
    if (lane < 16) {
        const int p = base + lane;
        int2 sd = (p < E) ? order_sd[p] : make_int2(0, 0);
        float rx = (pos[sd.y * 3 + 0] - pos[sd.x * 3 + 0]) * NM2A_C;
        float ry = (pos[sd.y * 3 + 1] - pos[sd.x * 3 + 1]) * NM2A_C;
        float rz = (pos[sd.y * 3 + 2] - pos[sd.x * 3 + 2]) * NM2A_C;
        float r2 = rx * rx + ry * ry + rz * rz + 1e-12f;
        float r = sqrtf(r2);
        float rinv = 1.0f / r;
        float x = r * (1.0f / RCUT_C);
        float x2 = x * x, x4 = x2 * x2, x6 = x4 * x2, x7 = x6 * x, x8 = x6 * x2;
        float env = (x < 1.0f) ? (1.0f - 28.0f * x6 + 48.0f * x7 - 21.0f * x8) : 0.0f;

        float th = PI_F * x, s1, c1;
        __sincosf(th, &s1, &c1);
        float sp = 0.0f, sn = s1;
        _Float16 av[8];
        #pragma unroll
        for (int n = 0; n < NBASIS; n++) {
            av[n] = (_Float16)(sn * rinv);
            float snx = 2.0f * c1 * sn - sp; sp = sn; sn = snx;
        }
        *(f16x8*)&u.A[w][lane][0] = *(f16x8*)&av[0];
        *(float4*)&u.A[w][lane][8]  = make_float4(0.f, 0.f, 0.f, 0.f);
        *(float4*)&u.A[w][lane][16] = make_float4(0.f, 0.f, 0.f, 0.f);
        *(float4*)&u.A[w][lane][24] = make_float4(0.f, 0.f, 0.f, 0.f);
        sSt[w][lane][0] = env;
        sSt[w][lane][1] = rx * rinv;
        sSt[w][lane][2] = ry * rinv;
        sSt[w][lane][3] = rz * rinv;
    }

    // ---- phase 1: MFMA basis layer -> z, silu -> sQ ----
    {
        f16x8 a1 = *(const f16x8*)&u.A[w][lane & 15][kb];
        const f32x4 z4 = {0.f, 0.f, 0.f, 0.f};
        f32x4 Dz0 = __builtin_amdgcn_mfma_f32_16x16x32_f16(a1, bz[0], z4, 0, 0, 0);
        f32x4 Dz1 = __builtin_amdgcn_mfma_f32_16x16x32_f16(a1, bz[1], z4, 0, 0, 0);
        const int f0 = lane & 15, e0 = (lane >> 4) * 4;
        const float bb0 = br1[f0], bb1 = br1[16 + f0];
        #pragma unroll
        for (int t = 0; t < 2; t++) {
            f32x4 Dz = t ? Dz1 : Dz0;
            float bb = t ? bb1 : bb0;
            #pragma unroll
            for (int r = 0; r < 4; r++) {
                float z = Dz[r] + bb;
                float q = z * sigmoidf_(z);
                sQ[w][e0 + r][t * 16 + f0] = (_Float16)q;
            }
        }
    }

    // ---- phase 2: MFMA W2 -> D ----
    {
        f16x8 aq = *(const f16x8*)&sQ[w][lane & 15][kb];
        const f32x4 z4 = {0.f, 0.f, 0.f, 0.f};
        const int cb = lane & 15, e0 = (lane >> 4) * 4;
        #pragma unroll
        for (int t = 0; t < 4; t++) {
            f32x4 d = __builtin_amdgcn_mfma_f32_16x16x32_f16(aq, bf[t], z4, 0, 0, 0);
            f16x4 dh;
            #pragma unroll
            for (int r = 0; r < 4; r++) dh[r] = (_Float16)d[r];
            *(f16x4*)&u.D[w][t * 16 + cb][e0] = dh;
        }
    }

    // ---- phase 3: epilogue with per-half-wave register run-merge ----
    int runKey = -1;
    float sAcc = 0.f, vXA = 0.f, vYA = 0.f, vZA = 0.f;
    #pragma unroll
    for (int i = 0; i < 8; i++) {
        const int m = hw * 8 + i;
        const int p = base + m;
        if (p >= E) break;
        int2 sd = order_sd[p];
        if (sd.y != runKey) {
            if (runKey >= 0) {
                unsafeAtomicAdd(&s_acc[(size_t)runKey * 32 + l32], sAcc);
                unsafeAtomicAdd(&v_acc[(size_t)runKey * 96 + 0 * 32 + l32], vXA);
                unsafeAtomicAdd(&v_acc[(size_t)runKey * 96 + 1 * 32 + l32], vYA);
                unsafeAtomicAdd(&v_acc[(size_t)runKey * 96 + 2 * 32 + l32], vZA);
            }
            runKey = sd.y;
            sAcc = vXA = vYA = vZA = 0.f;
        }
        float env = sSt[w][m][0], rhx = sSt[w][m][1], rhy = sSt[w][m][2], rhz = sSt[w][m][3];
        float rw0 = (float)u.D[w][l32][m];
        float rw1 = (float)u.D[w][32 + l32][m];
        int tyi = types[sd.x];
        float hs = (tyi == 0) ? te0 : ((tyi == 1) ? te1 : te2);
        sAcc += hs * rw0 * env;
        float hw1 = hs * rw1 * env;
        vXA += hw1 * rhx; vYA += hw1 * rhy; vZA += hw1 * rhz;
    }
    if (runKey >= 0) {
        unsafeAtomicAdd(&s_acc[(size_t)runKey * 32 + l32], sAcc);
        unsafeAtomicAdd(&v_acc[(size_t)runKey * 96 + 0 * 32 + l32], vXA);
        unsafeAtomicAdd(&v_acc[(size_t)runKey * 96 + 1 * 32 + l32], vYA);
        unsafeAtomicAdd(&v_acc[(size_t)runKey * 96 + 2 * 32 + l32], vZA);
    }
}

// -------- atom MLP: 64 atoms/block, weights preloaded once --------
__global__ __launch_bounds__(256) void atom_mlp(
    const int* __restrict__ types, const float* __restrict__ temb,
    const float* __restrict__ Wself, const float* __restrict__ Wo1,
    const float* __restrict__ bo1, const float* __restrict__ Wo2,
    float* __restrict__ s_acc, float* __restrict__ v_acc,
    float* __restrict__ e_partial, int N)
{
    __shared__ float sWs[FDIM * FDIM], sWsT[FDIM * FDIM];
    __shared__ float sWo1[2 * FDIM * FDIM], sWo1T[2 * FDIM * FDIM];
    __shared__ float sb[FDIM], sW2o[FDIM], sTE[96];
    __shared__ float gred[8];
    for (int i = threadIdx.x; i < FDIM * FDIM; i += 256) {
        sWs[i] = Wself[i];
        sWsT[i] = Wself[(i & 31) * FDIM + (i >> 5)];
    }
    for (int i = threadIdx.x; i < 2 * FDIM * FDIM; i += 256) {
        sWo1[i] = Wo1[i];
        sWo1T[i] = Wo1[(i & 63) * FDIM + (i >> 6)];
    }
    for (int i = threadIdx.x; i < FDIM; i += 256) { sb[i] = bo1[i]; sW2o[i] = Wo2[i]; }
    for (int i = threadIdx.x; i < 96; i += 256) sTE[i] = temb[i];
    __syncthreads();

    const int lane = threadIdx.x & 31;
    const int g = threadIdx.x >> 5;
    float eAcc = 0.0f;

    for (int it = 0; it < 8; it++) {
        int a = blockIdx.x * 64 + it * 8 + g;
        const bool valid = (a < N);
        if (!valid) a = 0;

        float sv = s_acc[(size_t)a * FDIM + lane];
        float vx = v_acc[(size_t)a * 96 + 0 * 32 + lane];
        float vy = v_acc[(size_t)a * 96 + 1 * 32 + lane];
        float vz = v_acc[(size_t)a * 96 + 2 * 32 + lane];
        float h = sTE[types[a] * FDIM + lane];
        float vn = sqrtf(vx * vx + vy * vy + vz * vz + 1e-12f);

        float row = h;
        #pragma unroll
        for (int f = 0; f < FDIM; f++) {
            float t = __shfl(sv, f, 32);
            row += t * sWs[f * FDIM + lane];
        }
        float u = sb[lane];
        #pragma unroll
        for (int j = 0; j < FDIM; j++) {
            float rv = __shfl(row, j, 32);
            float vv = __shfl(vn, j, 32);
            u += rv * sWo1[j * FDIM + lane] + vv * sWo1[(j + FDIM) * FDIM + lane];
        }
        float sg = sigmoidf_(u);
        float au = u * sg;
        float pa = valid ? au * sW2o[lane] : 0.0f;
        #pragma unroll
        for (int m = 16; m; m >>= 1) pa += __shfl_xor(pa, m, 32);
        if (lane == 0) eAcc += pa;

        float gu = sW2o[lane] * (sg * (1.0f + u * (1.0f - sg)));
        float gfr = 0.0f, gfv = 0.0f;
        #pragma unroll
        for (int k = 0; k < FDIM; k++) {
            float gv_ = __shfl(gu, k, 32);
            gfr += gv_ * sWo1T[k * 64 + lane];
            gfv += gv_ * sWo1T[k * 64 + 32 + lane];
        }
        float gs = 0.0f;
        #pragma unroll
        for (int k = 0; k < FDIM; k++) {
            float gr = __shfl(gfr, k, 32);
            gs += gr * sWsT[k * FDIM + lane];
        }
        if (valid) {
            s_acc[(size_t)a * FDIM + lane] = gs;
            float sc = gfv / vn;
            v_acc[(size_t)a * 96 + 0 * 32 + lane] = sc * vx;
            v_acc[(size_t)a * 96 + 1 * 32 + lane] = sc * vy;
            v_acc[(size_t)a * 96 + 2 * 32 + lane] = sc * vz;
        }
    }
    if (lane == 0) gred[g] = eAcc;
    __syncthreads();
    if (threadIdx.x == 0) {
        float t = 0.0f;
        #pragma unroll
        for (int i = 0; i < 8; i++) t += gred[i];
        e_partial[blockIdx.x] = t;
    }
}

// ---------------- edge backward: dual-MFMA, LDS-aliased, gm run-cache (r9 form) ----------------
__global__ __launch_bounds__(256) void edge_bwd_mfma(
    const float* __restrict__ pos, const int* __restrict__ types,
    const int2* __restrict__ order_sd,
    const float* __restrict__ Wr1, const float* __restrict__ br1,
    const float* __restrict__ Wr2, const float* __restrict__ temb,
    const float* __restrict__ g_s, const float* __restrict__ g_v,
    float* __restrict__ forces, int E)
{
    __shared__ union UA {
        _Float16 A[4][16][QP];
        _Float16 Dq[4][64][EP];
    } u1;
    __shared__ union UB {
        _Float16 Q[4][16][QP];
        _Float16 Dt[4][64][EP];
    } u2;
    __shared__ _Float16 sT[4][16][QP];
    __shared__ float sSt[4][16][8];       // rinv, env, denv, rhx, rhy, rhz

    const int lane = threadIdx.x & 63;
    const int l32 = threadIdx.x & 31;
    const int hw = (threadIdx.x >> 5) & 1;
    const int w = threadIdx.x >> 6;
    const int base = blockIdx.x * 64 + w * 16;

    const float te0 = temb[l32], te1 = temb[FDIM + l32], te2 = temb[2 * FDIM + l32];

    const int kb = (lane >> 4) * 8, nb = lane & 15;
    f16x8 bz[2], bt[2];
    #pragma unroll
    for (int t = 0; t < 2; t++)
        #pragma unroll
        for (int j = 0; j < 8; j++) {
            int k = kb + j;
            bz[t][j] = (k < 8) ? (_Float16)Wr1[k * FDIM + t * 16 + nb] : (_Float16)0.0f;
            bt[t][j] = (k >= 8 && k < 16) ? (_Float16)Wr1[(k - 8) * FDIM + t * 16 + nb] : (_Float16)0.0f;
        }
    f16x8 bf[4];
    #pragma unroll
    for (int t = 0; t < 4; t++)
        #pragma unroll
        for (int j = 0; j < 8; j++)
            bf[t][j] = (_Float16)Wr2[(kb + j) * 64 + t * 16 + nb];

    // ---- phase 0: lane-parallel geometry + basis/dbasis ----
    if (lane < 16) {
        const int p = base + lane;
        int2 sd = (p < E) ? order_sd[p] : make_int2(0, 0);
        float rx = (pos[sd.y * 3 + 0] - pos[sd.x * 3 + 0]) * NM2A_C;
        float ry = (pos[sd.y * 3 + 1] - pos[sd.x * 3 + 1]) * NM2A_C;
        float rz = (pos[sd.y * 3 + 2] - pos[sd.x * 3 + 2]) * NM2A_C;
        float r2 = rx * rx + ry * ry + rz * rz + 1e-12f;
        float r = sqrtf(r2);
        float rinv = 1.0f / r;
        float x = r * (1.0f / RCUT_C);
        float x2 = x * x, x4 = x2 * x2, x5 = x4 * x, x6 = x4 * x2, x7 = x6 * x, x8 = x6 * x2;
        float env = (x < 1.0f) ? (1.0f - 28.0f * x6 + 48.0f * x7 - 21.0f * x8) : 0.0f;
        float denv = (x < 1.0f) ? (-168.0f * x5 + 336.0f * x6 - 168.0f * x7) * (1.0f / RCUT_C) : 0.0f;

        float th = PI_F * x, s1, c1;
        __sincosf(th, &s1, &c1);
        float sp = 0.0f, sn = s1, cp = 1.0f, cn = c1;
        _Float16 av[16];
        #pragma unroll
        for (int n = 0; n < NBASIS; n++) {
            float basis = sn * rinv;
            float dbdr = (PI_F * (float)(n + 1) * (1.0f / RCUT_C)) * cn * rinv - basis * rinv;
            av[n] = (_Float16)basis;
            av[8 + n] = (_Float16)dbdr;
            float snx = 2.0f * c1 * sn - sp; sp = sn; sn = snx;
            float cnx = 2.0f * c1 * cn - cp; cp = cn; cn = cnx;
        }
        *(f16x8*)&u1.A[w][lane][0] = *(f16x8*)&av[0];
        *(f16x8*)&u1.A[w][lane][8] = *(f16x8*)&av[8];
        *(float4*)&u1.A[w][lane][16] = make_float4(0.f, 0.f, 0.f, 0.f);
        *(float4*)&u1.A[w][lane][24] = make_float4(0.f, 0.f, 0.f, 0.f);
        sSt[w][lane][0] = rinv;
        sSt[w][lane][1] = env;
        sSt[w][lane][2] = denv;
        sSt[w][lane][3] = rx * rinv;
        sSt[w][lane][4] = ry * rinv;
        sSt[w][lane][5] = rz * rinv;
    }

    // ---- phase 1: MFMA basis layer -> z, tacc; silu/tf -> Q/T ----
    {
        f16x8 a1 = *(const f16x8*)&u1.A[w][lane & 15][kb];
        const f32x4 z4 = {0.f, 0.f, 0.f, 0.f};
        f32x4 Dz0 = __builtin_amdgcn_mfma_f32_16x16x32_f16(a1, bz[0], z4, 0, 0, 0);
        f32x4 Dz1 = __builtin_amdgcn_mfma_f32_16x16x32_f16(a1, bz[1], z4, 0, 0, 0);
        f32x4 Dt0 = __builtin_amdgcn_mfma_f32_16x16x32_f16(a1, bt[0], z4, 0, 0, 0);
        f32x4 Dt1 = __builtin_amdgcn_mfma_f32_16x16x32_f16(a1, bt[1], z4, 0, 0, 0);
        const int f0 = lane & 15, e0 = (lane >> 4) * 4;
        const float bb0 = br1[f0], bb1 = br1[16 + f0];
        #pragma unroll
        for (int t = 0; t < 2; t++) {
            f32x4 Dz = t ? Dz1 : Dz0;
            f32x4 Dt = t ? Dt1 : Dt0;
            float bb = t ? bb1 : bb0;
            #pragma unroll
            for (int r = 0; r < 4; r++) {
                float z = Dz[r] + bb;
                float sg = sigmoidf_(z);
                float q = z * sg;
                float tf = (sg * (1.0f + z * (1.0f - sg))) * Dt[r];
                u2.Q[w][e0 + r][t * 16 + f0] = (_Float16)q;
                sT[w][e0 + r][t * 16 + f0] = (_Float16)tf;
            }
        }
    }

    // ---- phase 2: 8 MFMAs (W2 on q and tf) ----
    {
        f16x8 aq = *(const f16x8*)&u2.Q[w][lane & 15][kb];
        f16x8 at = *(const f16x8*)&sT[w][lane & 15][kb];
        const f32x4 z4 = {0.f, 0.f, 0.f, 0.f};
        const int cb = lane & 15, e0 = (lane >> 4) * 4;
        #pragma unroll
        for (int t = 0; t < 4; t++) {
            f32x4 dq = __builtin_amdgcn_mfma_f32_16x16x32_f16(aq, bf[t], z4, 0, 0, 0);
            f32x4 dt = __builtin_amdgcn_mfma_f32_16x16x32_f16(at, bf[t], z4, 0, 0, 0);
            f16x4 hq, ht;
            #pragma unroll
            for (int r = 0; r < 4; r++) { hq[r] = (_Float16)dq[r]; ht[r] = (_Float16)dt[r]; }
            *(f16x4*)&u1.Dq[w][t * 16 + cb][e0] = hq;
            *(f16x4*)&u2.Dt[w][t * 16 + cb][e0] = ht;
        }
    }

    // ---- phase 3: epilogue (gm cached per dst-run) ----
    const float SC = EV2KJ_C * NM2A_C;
    int runKey = -1;
    float fAcc = 0.f;
    float gm0 = 0.f, gm1x = 0.f, gm1y = 0.f, gm1z = 0.f;
    #pragma unroll
    for (int i = 0; i < 8; i++) {
        const int m = hw * 8 + i;
        const int p = base + m;
        if (p >= E) break;
        int2 sd = order_sd[p];
        if (sd.y != runKey) {
            if (runKey >= 0 && l32 < 3)
                unsafeAtomicAdd(&forces[(size_t)runKey * 3 + l32], -SC * fAcc);
            runKey = sd.y;
            fAcc = 0.f;
            gm0  = g_s[(size_t)sd.y * FDIM + l32];
            gm1x = g_v[(size_t)sd.y * 96 + 0 * 32 + l32];
            gm1y = g_v[(size_t)sd.y * 96 + 1 * 32 + l32];
            gm1z = g_v[(size_t)sd.y * 96 + 2 * 32 + l32];
        }
        float rinv = sSt[w][m][0], env = sSt[w][m][1], denv = sSt[w][m][2];
        float rhx = sSt[w][m][3], rhy = sSt[w][m][4], rhz = sSt[w][m][5];
        float rw0 = (float)u1.Dq[w][l32][m];
        float rw1 = (float)u1.Dq[w][32 + l32][m];
        float u0  = (float)u2.Dt[w][l32][m];
        float u1v = (float)u2.Dt[w][32 + l32][m];

        int tyi = types[sd.x];
        float hs = (tyi == 0) ? te0 : ((tyi == 1) ? te1 : te2);

        float gw0 = hs * gm0;
        float gw1 = hs * (gm1x * rhx + gm1y * rhy + gm1z * rhz);
        float hw1 = hs * rw1 * env;
        float grx = hw1 * gm1x, gry = hw1 * gm1y, grz = hw1 * gm1z;
        float genv = gw0 * rw0 + gw1 * rw1;
        float pc = (gw0 * env) * u0 + (gw1 * env) * u1v + genv * denv;
        float pg = pc - (grx * rhx + gry * rhy + grz * rhz) * rinv;

        // channel-packed butterfly: lane%4 -> {Gx,Gy,Gz,beta}
        float a1 = grx + __shfl_xor(grx, 1, 32);
        float b1v = gry + __shfl_xor(gry, 1, 32);
        float c1v = grz + __shfl_xor(grz, 1, 32);
        float d1 = pg + __shfl_xor(pg, 1, 32);
        float e0v = (l32 & 1) ? b1v : a1;
        float e1v = (l32 & 1) ? d1 : c1v;
        e0v += __shfl_xor(e0v, 2, 32);
        e1v += __shfl_xor(e1v, 2, 32);
        float v = (l32 & 2) ? e1v : e0v;
        v += __shfl_xor(v, 4, 32);
        v += __shfl_xor(v, 8, 32);
        v += __shfl_xor(v, 16, 32);
        float beta = __shfl(v, l32 | 3, 32);

        if (l32 < 3) {
            float rh_l = (l32 == 0) ? rhx : ((l32 == 1) ? rhy : rhz);
            float comp = v * rinv + rh_l * beta;
            unsafeAtomicAdd(&forces[(size_t)sd.x * 3 + l32], SC * comp);
            fAcc += comp;
        }
    }
    if (runKey >= 0 && l32 < 3)
        unsafeAtomicAdd(&forces[(size_t)runKey * 3 + l32], -SC * fAcc);
}

// ---------------- reductions & correction ----------------
__global__ __launch_bounds__(256) void reduce_energy(
    const float* __restrict__ e_partial, int n, float* __restrict__ out)
{
    __shared__ float red[256];
    float s = 0.0f;
    for (int i = threadIdx.x; i < n; i += 256) s += e_partial[i];
    red[threadIdx.x] = s;
    __syncthreads();
    for (int k = 128; k; k >>= 1) {
        if (threadIdx.x < k) red[threadIdx.x] += red[threadIdx.x + k];
        __syncthreads();
    }
    if (threadIdx.x == 0) out[0] = red[0] * EV2KJ_C;
}

__global__ __launch_bounds__(256) void reduce_net(
    const float* __restrict__ f, const float* __restrict__ masses,
    float* __restrict__ accum, int N)
{
    float nx = 0, ny = 0, nz = 0, ms = 0;
    for (int i = blockIdx.x * 256 + threadIdx.x; i < N; i += gridDim.x * 256) {
        nx += f[i * 3 + 0]; ny += f[i * 3 + 1]; nz += f[i * 3 + 2]; ms += masses[i];
    }
    #pragma unroll
    for (int m = 32; m; m >>= 1) {
        nx += __shfl_xor(nx, m, 64);
        ny += __shfl_xor(ny, m, 64);
        nz += __shfl_xor(nz, m, 64);
        ms += __shfl_xor(ms, m, 64);
    }
    __shared__ float red[4][4];
    int w = threadIdx.x >> 6;
    if ((threadIdx.x & 63) == 0) { red[w][0] = nx; red[w][1] = ny; red[w][2] = nz; red[w][3] = ms; }
    __syncthreads();
    if (threadIdx.x == 0) {
        float a0 = 0, a1 = 0, a2 = 0, a3 = 0;
        for (int i = 0; i < 4; i++) { a0 += red[i][0]; a1 += red[i][1]; a2 += red[i][2]; a3 += red[i][3]; }
        unsafeAtomicAdd(accum + 0, a0);
        unsafeAtomicAdd(accum + 1, a1);
        unsafeAtomicAdd(accum + 2, a2);
        unsafeAtomicAdd(accum + 3, a3);
    }
}

__global__ __launch_bounds__(256) void correct_forces(
    float* __restrict__ f, const float* __restrict__ masses,
    const float* __restrict__ accum, int N)
{
    int i = blockIdx.x * 256 + threadIdx.x;
    if (i < N) {
        float c = masses[i] / accum[3];
        f[i * 3 + 0] -= c * accum[0];
        f[i * 3 + 1] -= c * accum[1];
        f[i * 3 + 2] -= c * accum[2];
    }
}

extern "C" void kernel_launch(void* const* d_in, const int* in_sizes, int n_in,
                              void* d_out, int out_size, void* d_ws, size_t ws_size,
                              hipStream_t stream)
{
    (void)n_in; (void)ws_size;
    const float* pos    = (const float*)d_in[0];
    const float* masses = (const float*)d_in[1];
    const float* temb   = (const float*)d_in[2];
    const float* Wr1    = (const float*)d_in[3];
    const float* br1    = (const float*)d_in[4];
    const float* Wr2    = (const float*)d_in[5];
    const float* Wself  = (const float*)d_in[6];
    const float* Wo1    = (const float*)d_in[7];
    const float* bo1    = (const float*)d_in[8];
    const float* Wo2    = (const float*)d_in[9];
    const int* types    = (const int*)d_in[10];
    const int* eidx     = (const int*)d_in[11];
    const int N = in_sizes[1];
    const int E = in_sizes[11] / 2;

    float* out = (float*)d_out;
    float* forces = out + 1;

    float* ws = (float*)d_ws;
    float* s_acc = ws;                               // N*32
    float* v_acc = s_acc + (size_t)N * FDIM;         // N*96
    int nAtomBlocks = (N + 63) / 64;
    float* e_partial = v_acc + (size_t)N * 96;       // nAtomBlocks
    float* accum = e_partial + nAtomBlocks;          // 4
    int* counts = (int*)(accum + 4);                 // N
    int* cursor = counts + N;                        // N
    int2* order_sd = (int2*)(cursor + N);            // E int2
    int nScan = (N + SCH - 1) / SCH;
    int* bsum = (int*)(order_sd + E);                // nScan

    hipMemsetAsync(d_out, 0, (size_t)out_size * sizeof(float), stream);
    hipMemsetAsync(s_acc, 0, (size_t)N * 128 * sizeof(float), stream);
    hipMemsetAsync(counts, 0, (size_t)N * sizeof(int), stream);
    hipMemsetAsync(accum, 0, 4 * sizeof(float), stream);

    hist_dst<<<2048, 256, 0, stream>>>(eidx, counts, E);
    scan_partial<<<nScan, 256, 0, stream>>>(counts, bsum, N);
    scan_bsum<<<1, 64, 0, stream>>>(bsum, nScan);
    scan_write<<<nScan, 256, 0, stream>>>(counts, bsum, cursor, N);
    scatter_edges<<<2048, 256, 0, stream>>>(eidx, cursor, order_sd, E);

    int nEdgeBlocks = (E + 63) / 64;
    edge_fwd_mfma<<<nEdgeBlocks, 256, 0, stream>>>(pos, types, order_sd,
                                                   Wr1, br1, Wr2, temb,
                                                   s_acc, v_acc, E);
    atom_mlp<<<nAtomBlocks, 256, 0, stream>>>(types, temb, Wself, Wo1, bo1, Wo2,
                                              s_acc, v_acc, e_partial, N);
    reduce_energy<<<1, 256, 0, stream>>>(e_partial, nAtomBlocks, out);
    edge_bwd_mfma<<<nEdgeBlocks, 256, 0, stream>>>(pos, types, order_sd,
                                                   Wr1, br1, Wr2, temb,
                                                   s_acc, v_acc, forces, E);
    reduce_net<<<64, 256, 0, stream>>>(forces, masses, accum, N);
    correct_forces<<<(N + 255) / 256, 256, 0, stream>>>(forces, masses, accum, N);
}

// Round 12
// 653.670 us; speedup vs baseline: 1.0645x; 1.0162x over previous
//
#include <hip/hip_runtime.h>
#include <math.h>

#define FDIM 32
#define NBASIS 8
#define QP 40     // A-stage row pad (f16 units) -> 80B rows, 16B-aligned quads
#define EP 20     // D-stage edge-dim pad (f16 units)
#define SCH 4096  // scan chunk per block (256 thr x 16)

constexpr float RCUT_C = 20.0f;
constexpr float PI_F = 3.14159265358979323846f;
constexpr float EV2KJ_C = 96.4853f;
constexpr float NM2A_C = 10.0f;

typedef _Float16 f16x8 __attribute__((ext_vector_type(8)));
typedef _Float16 f16x4 __attribute__((ext_vector_type(4)));
typedef float f32x4 __attribute__((ext_vector_type(4)));

__device__ __forceinline__ float sigmoidf_(float z) { return 1.0f / (1.0f + __expf(-z)); }

// ---------------- CSR build: histogram, 3-kernel scan, scatter ----------------
__global__ __launch_bounds__(256) void hist_dst(
    const int* __restrict__ eidx, int* __restrict__ counts, int E)
{
    for (int e = blockIdx.x * 256 + threadIdx.x; e < E; e += gridDim.x * 256)
        atomicAdd(&counts[eidx[E + e]], 1);
}

__global__ __launch_bounds__(256) void scan_partial(
    const int* __restrict__ counts, int* __restrict__ bsum, int N)
{
    __shared__ int red[256];
    const int t = threadIdx.x;
    const int st = blockIdx.x * SCH + t * 16;
    int s = 0;
    #pragma unroll
    for (int i = 0; i < 16; i++) { int idx = st + i; if (idx < N) s += counts[idx]; }
    red[t] = s;
    __syncthreads();
    for (int k = 128; k; k >>= 1) {
        if (t < k) red[t] += red[t + k];
        __syncthreads();
    }
    if (t == 0) bsum[blockIdx.x] = red[0];
}

__global__ __launch_bounds__(64) void scan_bsum(int* __restrict__ bsum, int nb)
{
    if (threadIdx.x == 0) {
        int run = 0;
        for (int i = 0; i < nb; i++) { int v = bsum[i]; bsum[i] = run; run += v; }
    }
}

__global__ __launch_bounds__(256) void scan_write(
    const int* __restrict__ counts, const int* __restrict__ bsum,
    int* __restrict__ cursor, int N)
{
    __shared__ int lds[256];
    const int t = threadIdx.x;
    const int st = blockIdx.x * SCH + t * 16;
    int vals[16];
    int s = 0;
    #pragma unroll
    for (int i = 0; i < 16; i++) {
        int idx = st + i;
        int v = (idx < N) ? counts[idx] : 0;
        vals[i] = v; s += v;
    }
    lds[t] = s;
    __syncthreads();
    for (int off = 1; off < 256; off <<= 1) {
        int v = (t >= off) ? lds[t - off] : 0;
        __syncthreads();
        lds[t] += v;
        __syncthreads();
    }
    int run = bsum[blockIdx.x] + lds[t] - s;   // exclusive prefix
    #pragma unroll
    for (int i = 0; i < 16; i++) {
        int idx = st + i;
        if (idx < N) cursor[idx] = run;
        run += vals[i];
    }
}

__global__ __launch_bounds__(256) void scatter_edges(
    const int* __restrict__ eidx, int* __restrict__ cursor,
    int2* __restrict__ order_sd, int E)
{
    for (int e = blockIdx.x * 256 + threadIdx.x; e < E; e += gridDim.x * 256) {
        int dst = eidx[E + e];
        int p = atomicAdd(&cursor[dst], 1);
        order_sd[p] = make_int2(eidx[e], dst);
    }
}

// ---------------- edge forward: dual-MFMA, LDS-aliased (r9 form) ----------------
__global__ __launch_bounds__(256) void edge_fwd_mfma(
    const float* __restrict__ pos, const int* __restrict__ types,
    const int2* __restrict__ order_sd,
    const float* __restrict__ Wr1, const float* __restrict__ br1,
    const float* __restrict__ Wr2, const float* __restrict__ temb,
    float* __restrict__ s_acc, float* __restrict__ v_acc, int E)
{
    __shared__ union UAD {
        _Float16 A[4][16][QP];
        _Float16 D[4][64][EP];
    } u;
    __shared__ _Float16 sQ[4][16][QP];
    __shared__ float sSt[4][16][4];         // env, rhx, rhy, rhz

    const int lane = threadIdx.x & 63;
    const int l32 = threadIdx.x & 31;
    const int hw = (threadIdx.x >> 5) & 1;
    const int w = threadIdx.x >> 6;
    const int base = blockIdx.x * 64 + w * 16;

    const float te0 = temb[l32], te1 = temb[FDIM + l32], te2 = temb[2 * FDIM + l32];

    const int kb = (lane >> 4) * 8, nb = lane & 15;
    f16x8 bz[2];
    #pragma unroll
    for (int t = 0; t < 2; t++)
        #pragma unroll
        for (int j = 0; j < 8; j++) {
            int k = kb + j;
            bz[t][j] = (k < 8) ? (_Float16)Wr1[k * FDIM + t * 16 + nb] : (_Float16)0.0f;
        }
    f16x8 bf[4];
    #pragma unroll
    for (int t = 0; t < 4; t++)
        #pragma unroll
        for (int j = 0; j < 8; j++)
            bf[t][j] = (_Float16)Wr2[(kb + j) * 64 + t * 16 + nb];

    // ---- phase 0: lane-parallel geometry + basis (lanes 0..15) ----
    if (lane < 16) {
        const int p = base + lane;
        int2 sd = (p < E) ? order_sd[p] : make_int2(0, 0);
        float rx = (pos[sd.y * 3 + 0] - pos[sd.x * 3 + 0]) * NM2A_C;
        float ry = (pos[sd.y * 3 + 1] - pos[sd.x * 3 + 1]) * NM2A_C;
        float rz = (pos[sd.y * 3 + 2] - pos[sd.x * 3 + 2]) * NM2A_C;
        float r2 = rx * rx + ry * ry + rz * rz + 1e-12f;
        float r = sqrtf(r2);
        float rinv = 1.0f / r;
        float x = r * (1.0f / RCUT_C);
        float x2 = x * x, x4 = x2 * x2, x6 = x4 * x2, x7 = x6 * x, x8 = x6 * x2;
        float env = (x < 1.0f) ? (1.0f - 28.0f * x6 + 48.0f * x7 - 21.0f * x8) : 0.0f;

        float th = PI_F * x, s1, c1;
        __sincosf(th, &s1, &c1);
        float sp = 0.0f, sn = s1;
        _Float16 av[8];
        #pragma unroll
        for (int n = 0; n < NBASIS; n++) {
            av[n] = (_Float16)(sn * rinv);
            float snx = 2.0f * c1 * sn - sp; sp = sn; sn = snx;
        }
        *(f16x8*)&u.A[w][lane][0] = *(f16x8*)&av[0];
        *(float4*)&u.A[w][lane][8]  = make_float4(0.f, 0.f, 0.f, 0.f);
        *(float4*)&u.A[w][lane][16] = make_float4(0.f, 0.f, 0.f, 0.f);
        *(float4*)&u.A[w][lane][24] = make_float4(0.f, 0.f, 0.f, 0.f);
        sSt[w][lane][0] = env;
        sSt[w][lane][1] = rx * rinv;
        sSt[w][lane][2] = ry * rinv;
        sSt[w][lane][3] = rz * rinv;
    }

    // ---- phase 1: MFMA basis layer -> z, silu -> sQ ----
    {
        f16x8 a1 = *(const f16x8*)&u.A[w][lane & 15][kb];
        const f32x4 z4 = {0.f, 0.f, 0.f, 0.f};
        f32x4 Dz0 = __builtin_amdgcn_mfma_f32_16x16x32_f16(a1, bz[0], z4, 0, 0, 0);
        f32x4 Dz1 = __builtin_amdgcn_mfma_f32_16x16x32_f16(a1, bz[1], z4, 0, 0, 0);
        const int f0 = lane & 15, e0 = (lane >> 4) * 4;
        const float bb0 = br1[f0], bb1 = br1[16 + f0];
        #pragma unroll
        for (int t = 0; t < 2; t++) {
            f32x4 Dz = t ? Dz1 : Dz0;
            float bb = t ? bb1 : bb0;
            #pragma unroll
            for (int r = 0; r < 4; r++) {
                float z = Dz[r] + bb;
                float q = z * sigmoidf_(z);
                sQ[w][e0 + r][t * 16 + f0] = (_Float16)q;
            }
        }
    }

    // ---- phase 2: MFMA W2 -> D ----
    {
        f16x8 aq = *(const f16x8*)&sQ[w][lane & 15][kb];
        const f32x4 z4 = {0.f, 0.f, 0.f, 0.f};
        const int cb = lane & 15, e0 = (lane >> 4) * 4;
        #pragma unroll
        for (int t = 0; t < 4; t++) {
            f32x4 d = __builtin_amdgcn_mfma_f32_16x16x32_f16(aq, bf[t], z4, 0, 0, 0);
            f16x4 dh;
            #pragma unroll
            for (int r = 0; r < 4; r++) dh[r] = (_Float16)d[r];
            *(f16x4*)&u.D[w][t * 16 + cb][e0] = dh;
        }
    }

    // ---- phase 3: epilogue with per-half-wave register run-merge ----
    int runKey = -1;
    float sAcc = 0.f, vXA = 0.f, vYA = 0.f, vZA = 0.f;
    #pragma unroll
    for (int i = 0; i < 8; i++) {
        const int m = hw * 8 + i;
        const int p = base + m;
        if (p >= E) break;
        int2 sd = order_sd[p];
        if (sd.y != runKey) {
            if (runKey >= 0) {
                unsafeAtomicAdd(&s_acc[(size_t)runKey * 32 + l32], sAcc);
                unsafeAtomicAdd(&v_acc[(size_t)runKey * 96 + 0 * 32 + l32], vXA);
                unsafeAtomicAdd(&v_acc[(size_t)runKey * 96 + 1 * 32 + l32], vYA);
                unsafeAtomicAdd(&v_acc[(size_t)runKey * 96 + 2 * 32 + l32], vZA);
            }
            runKey = sd.y;
            sAcc = vXA = vYA = vZA = 0.f;
        }
        float env = sSt[w][m][0], rhx = sSt[w][m][1], rhy = sSt[w][m][2], rhz = sSt[w][m][3];
        float rw0 = (float)u.D[w][l32][m];
        float rw1 = (float)u.D[w][32 + l32][m];
        int tyi = types[sd.x];
        float hs = (tyi == 0) ? te0 : ((tyi == 1) ? te1 : te2);
        sAcc += hs * rw0 * env;
        float hw1 = hs * rw1 * env;
        vXA += hw1 * rhx; vYA += hw1 * rhy; vZA += hw1 * rhz;
    }
    if (runKey >= 0) {
        unsafeAtomicAdd(&s_acc[(size_t)runKey * 32 + l32], sAcc);
        unsafeAtomicAdd(&v_acc[(size_t)runKey * 96 + 0 * 32 + l32], vXA);
        unsafeAtomicAdd(&v_acc[(size_t)runKey * 96 + 1 * 32 + l32], vYA);
        unsafeAtomicAdd(&v_acc[(size_t)runKey * 96 + 2 * 32 + l32], vZA);
    }
}

// -------- atom MLP: 64 atoms/block, weights preloaded once --------
__global__ __launch_bounds__(256) void atom_mlp(
    const int* __restrict__ types, const float* __restrict__ temb,
    const float* __restrict__ Wself, const float* __restrict__ Wo1,
    const float* __restrict__ bo1, const float* __restrict__ Wo2,
    float* __restrict__ s_acc, float* __restrict__ v_acc,
    float* __restrict__ e_partial, int N)
{
    __shared__ float sWs[FDIM * FDIM], sWsT[FDIM * FDIM];
    __shared__ float sWo1[2 * FDIM * FDIM], sWo1T[2 * FDIM * FDIM];
    __shared__ float sb[FDIM], sW2o[FDIM], sTE[96];
    __shared__ float gred[8];
    for (int i = threadIdx.x; i < FDIM * FDIM; i += 256) {
        sWs[i] = Wself[i];
        sWsT[i] = Wself[(i & 31) * FDIM + (i >> 5)];
    }
    for (int i = threadIdx.x; i < 2 * FDIM * FDIM; i += 256) {
        sWo1[i] = Wo1[i];
        sWo1T[i] = Wo1[(i & 63) * FDIM + (i >> 6)];
    }
    for (int i = threadIdx.x; i < FDIM; i += 256) { sb[i] = bo1[i]; sW2o[i] = Wo2[i]; }
    for (int i = threadIdx.x; i < 96; i += 256) sTE[i] = temb[i];
    __syncthreads();

    const int lane = threadIdx.x & 31;
    const int g = threadIdx.x >> 5;
    float eAcc = 0.0f;

    for (int it = 0; it < 8; it++) {
        int a = blockIdx.x * 64 + it * 8 + g;
        const bool valid = (a < N);
        if (!valid) a = 0;

        float sv = s_acc[(size_t)a * FDIM + lane];
        float vx = v_acc[(size_t)a * 96 + 0 * 32 + lane];
        float vy = v_acc[(size_t)a * 96 + 1 * 32 + lane];
        float vz = v_acc[(size_t)a * 96 + 2 * 32 + lane];
        float h = sTE[types[a] * FDIM + lane];
        float vn = sqrtf(vx * vx + vy * vy + vz * vz + 1e-12f);

        float row = h;
        #pragma unroll
        for (int f = 0; f < FDIM; f++) {
            float t = __shfl(sv, f, 32);
            row += t * sWs[f * FDIM + lane];
        }
        float u = sb[lane];
        #pragma unroll
        for (int j = 0; j < FDIM; j++) {
            float rv = __shfl(row, j, 32);
            float vv = __shfl(vn, j, 32);
            u += rv * sWo1[j * FDIM + lane] + vv * sWo1[(j + FDIM) * FDIM + lane];
        }
        float sg = sigmoidf_(u);
        float au = u * sg;
        float pa = valid ? au * sW2o[lane] : 0.0f;
        #pragma unroll
        for (int m = 16; m; m >>= 1) pa += __shfl_xor(pa, m, 32);
        if (lane == 0) eAcc += pa;

        float gu = sW2o[lane] * (sg * (1.0f + u * (1.0f - sg)));
        float gfr = 0.0f, gfv = 0.0f;
        #pragma unroll
        for (int k = 0; k < FDIM; k++) {
            float gv_ = __shfl(gu, k, 32);
            gfr += gv_ * sWo1T[k * 64 + lane];
            gfv += gv_ * sWo1T[k * 64 + 32 + lane];
        }
        float gs = 0.0f;
        #pragma unroll
        for (int k = 0; k < FDIM; k++) {
            float gr = __shfl(gfr, k, 32);
            gs += gr * sWsT[k * FDIM + lane];
        }
        if (valid) {
            s_acc[(size_t)a * FDIM + lane] = gs;
            float sc = gfv / vn;
            v_acc[(size_t)a * 96 + 0 * 32 + lane] = sc * vx;
            v_acc[(size_t)a * 96 + 1 * 32 + lane] = sc * vy;
            v_acc[(size_t)a * 96 + 2 * 32 + lane] = sc * vz;
        }
    }
    if (lane == 0) gred[g] = eAcc;
    __syncthreads();
    if (threadIdx.x == 0) {
        float t = 0.0f;
        #pragma unroll
        for (int i = 0; i < 8; i++) t += gred[i];
        e_partial[blockIdx.x] = t;
    }
}

// ---------------- edge backward: dual-MFMA, 3-way LDS aliasing, gm run-cache ----------------
// Per-wave liveness: A dies at ph1 A-load, T dies at ph2 at-load, Q dies at ph2 aq-load.
// Region R1 (1280 f16/wave): A at [0,640) as [16][QP], T at [640,1280) as [16][QP],
//                            Dq over the full [0,1280) as [64][EP].
// Region R2 (1280 f16/wave): Q at [0,640) as [16][QP], Dt over full as [64][EP].
// Same-wave program order guarantees read-before-overwrite; no cross-wave sharing.
__global__ __launch_bounds__(256) void edge_bwd_mfma(
    const float* __restrict__ pos, const int* __restrict__ types,
    const int2* __restrict__ order_sd,
    const float* __restrict__ Wr1, const float* __restrict__ br1,
    const float* __restrict__ Wr2, const float* __restrict__ temb,
    const float* __restrict__ g_s, const float* __restrict__ g_v,
    float* __restrict__ forces, int E)
{
    __shared__ _Float16 sR1[4][1280];
    __shared__ _Float16 sR2[4][1280];
    __shared__ float sSt[4][16][8];       // rinv, env, denv, rhx, rhy, rhz

    const int lane = threadIdx.x & 63;
    const int l32 = threadIdx.x & 31;
    const int hw = (threadIdx.x >> 5) & 1;
    const int w = threadIdx.x >> 6;
    const int base = blockIdx.x * 64 + w * 16;

    const float te0 = temb[l32], te1 = temb[FDIM + l32], te2 = temb[2 * FDIM + l32];

    const int kb = (lane >> 4) * 8, nb = lane & 15;
    f16x8 bz[2], bt[2];
    #pragma unroll
    for (int t = 0; t < 2; t++)
        #pragma unroll
        for (int j = 0; j < 8; j++) {
            int k = kb + j;
            bz[t][j] = (k < 8) ? (_Float16)Wr1[k * FDIM + t * 16 + nb] : (_Float16)0.0f;
            bt[t][j] = (k >= 8 && k < 16) ? (_Float16)Wr1[(k - 8) * FDIM + t * 16 + nb] : (_Float16)0.0f;
        }
    f16x8 bf[4];
    #pragma unroll
    for (int t = 0; t < 4; t++)
        #pragma unroll
        for (int j = 0; j < 8; j++)
            bf[t][j] = (_Float16)Wr2[(kb + j) * 64 + t * 16 + nb];

    // ---- phase 0: lane-parallel geometry + basis/dbasis ----
    if (lane < 16) {
        const int p = base + lane;
        int2 sd = (p < E) ? order_sd[p] : make_int2(0, 0);
        float rx = (pos[sd.y * 3 + 0] - pos[sd.x * 3 + 0]) * NM2A_C;
        float ry = (pos[sd.y * 3 + 1] - pos[sd.x * 3 + 1]) * NM2A_C;
        float rz = (pos[sd.y * 3 + 2] - pos[sd.x * 3 + 2]) * NM2A_C;
        float r2 = rx * rx + ry * ry + rz * rz + 1e-12f;
        float r = sqrtf(r2);
        float rinv = 1.0f / r;
        float x = r * (1.0f / RCUT_C);
        float x2 = x * x, x4 = x2 * x2, x5 = x4 * x, x6 = x4 * x2, x7 = x6 * x, x8 = x6 * x2;
        float env = (x < 1.0f) ? (1.0f - 28.0f * x6 + 48.0f * x7 - 21.0f * x8) : 0.0f;
        float denv = (x < 1.0f) ? (-168.0f * x5 + 336.0f * x6 - 168.0f * x7) * (1.0f / RCUT_C) : 0.0f;

        float th = PI_F * x, s1, c1;
        __sincosf(th, &s1, &c1);
        float sp = 0.0f, sn = s1, cp = 1.0f, cn = c1;
        _Float16 av[16];
        #pragma unroll
        for (int n = 0; n < NBASIS; n++) {
            float basis = sn * rinv;
            float dbdr = (PI_F * (float)(n + 1) * (1.0f / RCUT_C)) * cn * rinv - basis * rinv;
            av[n] = (_Float16)basis;
            av[8 + n] = (_Float16)dbdr;
            float snx = 2.0f * c1 * sn - sp; sp = sn; sn = snx;
            float cnx = 2.0f * c1 * cn - cp; cp = cn; cn = cnx;
        }
        *(f16x8*)&sR1[w][lane * QP + 0] = *(f16x8*)&av[0];
        *(f16x8*)&sR1[w][lane * QP + 8] = *(f16x8*)&av[8];
        *(float4*)&sR1[w][lane * QP + 16] = make_float4(0.f, 0.f, 0.f, 0.f);
        *(float4*)&sR1[w][lane * QP + 24] = make_float4(0.f, 0.f, 0.f, 0.f);
        sSt[w][lane][0] = rinv;
        sSt[w][lane][1] = env;
        sSt[w][lane][2] = denv;
        sSt[w][lane][3] = rx * rinv;
        sSt[w][lane][4] = ry * rinv;
        sSt[w][lane][5] = rz * rinv;
    }

    // ---- phase 1: MFMA basis layer -> z, tacc; silu/tf -> Q (R2) / T (R1 upper) ----
    {
        f16x8 a1 = *(const f16x8*)&sR1[w][(lane & 15) * QP + kb];
        const f32x4 z4 = {0.f, 0.f, 0.f, 0.f};
        f32x4 Dz0 = __builtin_amdgcn_mfma_f32_16x16x32_f16(a1, bz[0], z4, 0, 0, 0);
        f32x4 Dz1 = __builtin_amdgcn_mfma_f32_16x16x32_f16(a1, bz[1], z4, 0, 0, 0);
        f32x4 Dt0 = __builtin_amdgcn_mfma_f32_16x16x32_f16(a1, bt[0], z4, 0, 0, 0);
        f32x4 Dt1 = __builtin_amdgcn_mfma_f32_16x16x32_f16(a1, bt[1], z4, 0, 0, 0);
        const int f0 = lane & 15, e0 = (lane >> 4) * 4;
        const float bb0 = br1[f0], bb1 = br1[16 + f0];
        #pragma unroll
        for (int t = 0; t < 2; t++) {
            f32x4 Dz = t ? Dz1 : Dz0;
            f32x4 Dt = t ? Dt1 : Dt0;
            float bb = t ? bb1 : bb0;
            #pragma unroll
            for (int r = 0; r < 4; r++) {
                float z = Dz[r] + bb;
                float sg = sigmoidf_(z);
                float q = z * sg;
                float tf = (sg * (1.0f + z * (1.0f - sg))) * Dt[r];
                sR2[w][(e0 + r) * QP + t * 16 + f0] = (_Float16)q;
                sR1[w][640 + (e0 + r) * QP + t * 16 + f0] = (_Float16)tf;
            }
        }
    }

    // ---- phase 2: 8 MFMAs (W2 on q and tf); Dq overwrites A+T, Dt overwrites Q ----
    {
        f16x8 aq = *(const f16x8*)&sR2[w][(lane & 15) * QP + kb];
        f16x8 at = *(const f16x8*)&sR1[w][640 + (lane & 15) * QP + kb];
        const f32x4 z4 = {0.f, 0.f, 0.f, 0.f};
        const int cb = lane & 15, e0 = (lane >> 4) * 4;
        #pragma unroll
        for (int t = 0; t < 4; t++) {
            f32x4 dq = __builtin_amdgcn_mfma_f32_16x16x32_f16(aq, bf[t], z4, 0, 0, 0);
            f32x4 dt = __builtin_amdgcn_mfma_f32_16x16x32_f16(at, bf[t], z4, 0, 0, 0);
            f16x4 hq, ht;
            #pragma unroll
            for (int r = 0; r < 4; r++) { hq[r] = (_Float16)dq[r]; ht[r] = (_Float16)dt[r]; }
            *(f16x4*)&sR1[w][(t * 16 + cb) * EP + e0] = hq;
            *(f16x4*)&sR2[w][(t * 16 + cb) * EP + e0] = ht;
        }
    }

    // ---- phase 3: epilogue (gm cached per dst-run) ----
    const float SC = EV2KJ_C * NM2A_C;
    int runKey = -1;
    float fAcc = 0.f;
    float gm0 = 0.f, gm1x = 0.f, gm1y = 0.f, gm1z = 0.f;
    #pragma unroll
    for (int i = 0; i < 8; i++) {
        const int m = hw * 8 + i;
        const int p = base + m;
        if (p >= E) break;
        int2 sd = order_sd[p];
        if (sd.y != runKey) {
            if (runKey >= 0 && l32 < 3)
                unsafeAtomicAdd(&forces[(size_t)runKey * 3 + l32], -SC * fAcc);
            runKey = sd.y;
            fAcc = 0.f;
            gm0  = g_s[(size_t)sd.y * FDIM + l32];
            gm1x = g_v[(size_t)sd.y * 96 + 0 * 32 + l32];
            gm1y = g_v[(size_t)sd.y * 96 + 1 * 32 + l32];
            gm1z = g_v[(size_t)sd.y * 96 + 2 * 32 + l32];
        }
        float rinv = sSt[w][m][0], env = sSt[w][m][1], denv = sSt[w][m][2];
        float rhx = sSt[w][m][3], rhy = sSt[w][m][4], rhz = sSt[w][m][5];
        float rw0 = (float)sR1[w][l32 * EP + m];
        float rw1 = (float)sR1[w][(32 + l32) * EP + m];
        float u0  = (float)sR2[w][l32 * EP + m];
        float u1v = (float)sR2[w][(32 + l32) * EP + m];

        int tyi = types[sd.x];
        float hs = (tyi == 0) ? te0 : ((tyi == 1) ? te1 : te2);

        float gw0 = hs * gm0;
        float gw1 = hs * (gm1x * rhx + gm1y * rhy + gm1z * rhz);
        float hw1 = hs * rw1 * env;
        float grx = hw1 * gm1x, gry = hw1 * gm1y, grz = hw1 * gm1z;
        float genv = gw0 * rw0 + gw1 * rw1;
        float pc = (gw0 * env) * u0 + (gw1 * env) * u1v + genv * denv;
        float pg = pc - (grx * rhx + gry * rhy + grz * rhz) * rinv;

        // channel-packed butterfly: lane%4 -> {Gx,Gy,Gz,beta}
        float a1 = grx + __shfl_xor(grx, 1, 32);
        float b1v = gry + __shfl_xor(gry, 1, 32);
        float c1v = grz + __shfl_xor(grz, 1, 32);
        float d1 = pg + __shfl_xor(pg, 1, 32);
        float e0v = (l32 & 1) ? b1v : a1;
        float e1v = (l32 & 1) ? d1 : c1v;
        e0v += __shfl_xor(e0v, 2, 32);
        e1v += __shfl_xor(e1v, 2, 32);
        float v = (l32 & 2) ? e1v : e0v;
        v += __shfl_xor(v, 4, 32);
        v += __shfl_xor(v, 8, 32);
        v += __shfl_xor(v, 16, 32);
        float beta = __shfl(v, l32 | 3, 32);

        if (l32 < 3) {
            float rh_l = (l32 == 0) ? rhx : ((l32 == 1) ? rhy : rhz);
            float comp = v * rinv + rh_l * beta;
            unsafeAtomicAdd(&forces[(size_t)sd.x * 3 + l32], SC * comp);
            fAcc += comp;
        }
    }
    if (runKey >= 0 && l32 < 3)
        unsafeAtomicAdd(&forces[(size_t)runKey * 3 + l32], -SC * fAcc);
}

// ---------------- reductions & correction ----------------
__global__ __launch_bounds__(256) void reduce_energy(
    const float* __restrict__ e_partial, int n, float* __restrict__ out)
{
    __shared__ float red[256];
    float s = 0.0f;
    for (int i = threadIdx.x; i < n; i += 256) s += e_partial[i];
    red[threadIdx.x] = s;
    __syncthreads();
    for (int k = 128; k; k >>= 1) {
        if (threadIdx.x < k) red[threadIdx.x] += red[threadIdx.x + k];
        __syncthreads();
    }
    if (threadIdx.x == 0) out[0] = red[0] * EV2KJ_C;
}

__global__ __launch_bounds__(256) void reduce_net(
    const float* __restrict__ f, const float* __restrict__ masses,
    float* __restrict__ accum, int N)
{
    float nx = 0, ny = 0, nz = 0, ms = 0;
    for (int i = blockIdx.x * 256 + threadIdx.x; i < N; i += gridDim.x * 256) {
        nx += f[i * 3 + 0]; ny += f[i * 3 + 1]; nz += f[i * 3 + 2]; ms += masses[i];
    }
    #pragma unroll
    for (int m = 32; m; m >>= 1) {
        nx += __shfl_xor(nx, m, 64);
        ny += __shfl_xor(ny, m, 64);
        nz += __shfl_xor(nz, m, 64);
        ms += __shfl_xor(ms, m, 64);
    }
    __shared__ float red[4][4];
    int w = threadIdx.x >> 6;
    if ((threadIdx.x & 63) == 0) { red[w][0] = nx; red[w][1] = ny; red[w][2] = nz; red[w][3] = ms; }
    __syncthreads();
    if (threadIdx.x == 0) {
        float a0 = 0, a1 = 0, a2 = 0, a3 = 0;
        for (int i = 0; i < 4; i++) { a0 += red[i][0]; a1 += red[i][1]; a2 += red[i][2]; a3 += red[i][3]; }
        unsafeAtomicAdd(accum + 0, a0);
        unsafeAtomicAdd(accum + 1, a1);
        unsafeAtomicAdd(accum + 2, a2);
        unsafeAtomicAdd(accum + 3, a3);
    }
}

__global__ __launch_bounds__(256) void correct_forces(
    float* __restrict__ f, const float* __restrict__ masses,
    const float* __restrict__ accum, int N)
{
    int i = blockIdx.x * 256 + threadIdx.x;
    if (i < N) {
        float c = masses[i] / accum[3];
        f[i * 3 + 0] -= c * accum[0];
        f[i * 3 + 1] -= c * accum[1];
        f[i * 3 + 2] -= c * accum[2];
    }
}

extern "C" void kernel_launch(void* const* d_in, const int* in_sizes, int n_in,
                              void* d_out, int out_size, void* d_ws, size_t ws_size,
                              hipStream_t stream)
{
    (void)n_in; (void)ws_size;
    const float* pos    = (const float*)d_in[0];
    const float* masses = (const float*)d_in[1];
    const float* temb   = (const float*)d_in[2];
    const float* Wr1    = (const float*)d_in[3];
    const float* br1    = (const float*)d_in[4];
    const float* Wr2    = (const float*)d_in[5];
    const float* Wself  = (const float*)d_in[6];
    const float* Wo1    = (const float*)d_in[7];
    const float* bo1    = (const float*)d_in[8];
    const float* Wo2    = (const float*)d_in[9];
    const int* types    = (const int*)d_in[10];
    const int* eidx     = (const int*)d_in[11];
    const int N = in_sizes[1];
    const int E = in_sizes[11] / 2;

    float* out = (float*)d_out;
    float* forces = out + 1;

    float* ws = (float*)d_ws;
    float* s_acc = ws;                               // N*32
    float* v_acc = s_acc + (size_t)N * FDIM;         // N*96
    int nAtomBlocks = (N + 63) / 64;
    float* e_partial = v_acc + (size_t)N * 96;       // nAtomBlocks
    float* accum = e_partial + nAtomBlocks;          // 4
    int* counts = (int*)(accum + 4);                 // N
    int* cursor = counts + N;                        // N
    int2* order_sd = (int2*)(cursor + N);            // E int2
    int nScan = (N + SCH - 1) / SCH;
    int* bsum = (int*)(order_sd + E);                // nScan

    hipMemsetAsync(d_out, 0, (size_t)out_size * sizeof(float), stream);
    hipMemsetAsync(s_acc, 0, (size_t)N * 128 * sizeof(float), stream);
    hipMemsetAsync(counts, 0, (size_t)N * sizeof(int), stream);
    hipMemsetAsync(accum, 0, 4 * sizeof(float), stream);

    hist_dst<<<2048, 256, 0, stream>>>(eidx, counts, E);
    scan_partial<<<nScan, 256, 0, stream>>>(counts, bsum, N);
    scan_bsum<<<1, 64, 0, stream>>>(bsum, nScan);
    scan_write<<<nScan, 256, 0, stream>>>(counts, bsum, cursor, N);
    scatter_edges<<<2048, 256, 0, stream>>>(eidx, cursor, order_sd, E);

    int nEdgeBlocks = (E + 63) / 64;
    edge_fwd_mfma<<<nEdgeBlocks, 256, 0, stream>>>(pos, types, order_sd,
                                                   Wr1, br1, Wr2, temb,
                                                   s_acc, v_acc, E);
    atom_mlp<<<nAtomBlocks, 256, 0, stream>>>(types, temb, Wself, Wo1, bo1, Wo2,
                                              s_acc, v_acc, e_partial, N);
    reduce_energy<<<1, 256, 0, stream>>>(e_partial, nAtomBlocks, out);
    edge_bwd_mfma<<<nEdgeBlocks, 256, 0, stream>>>(pos, types, order_sd,
                                                   Wr1, br1, Wr2, temb,
                                                   s_acc, v_acc, forces, E);
    reduce_net<<<64, 256, 0, stream>>>(forces, masses, accum, N);
    correct_forces<<<(N + 255) / 256, 256, 0, stream>>>(forces, masses, accum, N);
}

// Round 13
// 640.054 us; speedup vs baseline: 1.0872x; 1.0213x over previous
//
#include <hip/hip_runtime.h>
#include <math.h>

#define FDIM 32
#define NBASIS 8
#define QP 40     // A-stage row pad (f16 units) -> 80B rows, 16B-aligned quads
#define EP 20     // D-stage edge-dim pad (f16 units)
#define SCH 4096  // scan chunk per block (256 thr x 16)

constexpr float RCUT_C = 20.0f;
constexpr float PI_F = 3.14159265358979323846f;
constexpr float EV2KJ_C = 96.4853f;
constexpr float NM2A_C = 10.0f;

typedef _Float16 f16x8 __attribute__((ext_vector_type(8)));
typedef _Float16 f16x4 __attribute__((ext_vector_type(4)));
typedef float f32x4 __attribute__((ext_vector_type(4)));

__device__ __forceinline__ float sigmoidf_(float z) { return 1.0f / (1.0f + __expf(-z)); }

// ---------------- CSR build: histogram, 3-kernel scan, scatter ----------------
__global__ __launch_bounds__(256) void hist_dst(
    const int* __restrict__ eidx, int* __restrict__ counts, int E)
{
    for (int e = blockIdx.x * 256 + threadIdx.x; e < E; e += gridDim.x * 256)
        atomicAdd(&counts[eidx[E + e]], 1);
}

__global__ __launch_bounds__(256) void scan_partial(
    const int* __restrict__ counts, int* __restrict__ bsum, int N)
{
    __shared__ int red[256];
    const int t = threadIdx.x;
    const int st = blockIdx.x * SCH + t * 16;
    int s = 0;
    #pragma unroll
    for (int i = 0; i < 16; i++) { int idx = st + i; if (idx < N) s += counts[idx]; }
    red[t] = s;
    __syncthreads();
    for (int k = 128; k; k >>= 1) {
        if (t < k) red[t] += red[t + k];
        __syncthreads();
    }
    if (t == 0) bsum[blockIdx.x] = red[0];
}

__global__ __launch_bounds__(64) void scan_bsum(int* __restrict__ bsum, int nb)
{
    if (threadIdx.x == 0) {
        int run = 0;
        for (int i = 0; i < nb; i++) { int v = bsum[i]; bsum[i] = run; run += v; }
    }
}

__global__ __launch_bounds__(256) void scan_write(
    const int* __restrict__ counts, const int* __restrict__ bsum,
    int* __restrict__ cursor, int N)
{
    __shared__ int lds[256];
    const int t = threadIdx.x;
    const int st = blockIdx.x * SCH + t * 16;
    int vals[16];
    int s = 0;
    #pragma unroll
    for (int i = 0; i < 16; i++) {
        int idx = st + i;
        int v = (idx < N) ? counts[idx] : 0;
        vals[i] = v; s += v;
    }
    lds[t] = s;
    __syncthreads();
    for (int off = 1; off < 256; off <<= 1) {
        int v = (t >= off) ? lds[t - off] : 0;
        __syncthreads();
        lds[t] += v;
        __syncthreads();
    }
    int run = bsum[blockIdx.x] + lds[t] - s;   // exclusive prefix
    #pragma unroll
    for (int i = 0; i < 16; i++) {
        int idx = st + i;
        if (idx < N) cursor[idx] = run;
        run += vals[i];
    }
}

__global__ __launch_bounds__(256) void scatter_edges(
    const int* __restrict__ eidx, int* __restrict__ cursor,
    int2* __restrict__ order_sd, int E)
{
    for (int e = blockIdx.x * 256 + threadIdx.x; e < E; e += gridDim.x * 256) {
        int dst = eidx[E + e];
        int p = atomicAdd(&cursor[dst], 1);
        order_sd[p] = make_int2(eidx[e], dst);
    }
}

// ---------------- edge forward: dual-tile ILP, dual-MFMA, LDS-aliased ----------------
__global__ __launch_bounds__(256) void edge_fwd_mfma(
    const float* __restrict__ pos, const int* __restrict__ types,
    const int2* __restrict__ order_sd,
    const float* __restrict__ Wr1, const float* __restrict__ br1,
    const float* __restrict__ Wr2, const float* __restrict__ temb,
    float* __restrict__ s_acc, float* __restrict__ v_acc, int E)
{
    union UAD { _Float16 A[16][QP]; _Float16 D[64][EP]; };
    __shared__ __align__(16) UAD uA[4], uB[4];
    __shared__ __align__(16) _Float16 sQa[4][16 * QP], sQb[4][16 * QP];
    __shared__ float sSt[4][32][4];         // env, rhx, rhy, rhz

    const int lane = threadIdx.x & 63;
    const int l32 = threadIdx.x & 31;
    const int hw = (threadIdx.x >> 5) & 1;
    const int w = threadIdx.x >> 6;
    const int gbase = blockIdx.x * 128 + w * 32;

    const float te0 = temb[l32], te1 = temb[FDIM + l32], te2 = temb[2 * FDIM + l32];

    const int kb = (lane >> 4) * 8, nb = lane & 15;
    f16x8 bz[2];
    #pragma unroll
    for (int t = 0; t < 2; t++)
        #pragma unroll
        for (int j = 0; j < 8; j++) {
            int k = kb + j;
            bz[t][j] = (k < 8) ? (_Float16)Wr1[k * FDIM + t * 16 + nb] : (_Float16)0.0f;
        }
    f16x8 bf[4];
    #pragma unroll
    for (int t = 0; t < 4; t++)
        #pragma unroll
        for (int j = 0; j < 8; j++)
            bf[t][j] = (_Float16)Wr2[(kb + j) * 64 + t * 16 + nb];

    // ---- phase 0: lane-parallel geometry + basis (lanes 0..31, one edge each) ----
    if (lane < 32) {
        const int ed = lane;                 // 0..31 -> tile (ed>>4), row (ed&15)
        const int p = gbase + ed;
        int2 sd = (p < E) ? order_sd[p] : make_int2(0, 0);
        float rx = (pos[sd.y * 3 + 0] - pos[sd.x * 3 + 0]) * NM2A_C;
        float ry = (pos[sd.y * 3 + 1] - pos[sd.x * 3 + 1]) * NM2A_C;
        float rz = (pos[sd.y * 3 + 2] - pos[sd.x * 3 + 2]) * NM2A_C;
        float r2 = rx * rx + ry * ry + rz * rz + 1e-12f;
        float r = sqrtf(r2);
        float rinv = 1.0f / r;
        float x = r * (1.0f / RCUT_C);
        float x2 = x * x, x4 = x2 * x2, x6 = x4 * x2, x7 = x6 * x, x8 = x6 * x2;
        float env = (x < 1.0f) ? (1.0f - 28.0f * x6 + 48.0f * x7 - 21.0f * x8) : 0.0f;

        float th = PI_F * x, s1, c1;
        __sincosf(th, &s1, &c1);
        float sp = 0.0f, sn = s1;
        _Float16 av[8];
        #pragma unroll
        for (int n = 0; n < NBASIS; n++) {
            av[n] = (_Float16)(sn * rinv);
            float snx = 2.0f * c1 * sn - sp; sp = sn; sn = snx;
        }
        _Float16* dstA = (ed < 16) ? &uA[w].A[ed & 15][0] : &uB[w].A[ed & 15][0];
        *(f16x8*)&dstA[0] = *(f16x8*)&av[0];
        *(float4*)&dstA[8]  = make_float4(0.f, 0.f, 0.f, 0.f);
        *(float4*)&dstA[16] = make_float4(0.f, 0.f, 0.f, 0.f);
        *(float4*)&dstA[24] = make_float4(0.f, 0.f, 0.f, 0.f);
        sSt[w][ed][0] = env;
        sSt[w][ed][1] = rx * rinv;
        sSt[w][ed][2] = ry * rinv;
        sSt[w][ed][3] = rz * rinv;
    }

    // ---- phase 1: MFMA basis layer -> z, silu -> Q (both tiles) ----
    {
        f16x8 a1a = *(const f16x8*)&uA[w].A[lane & 15][kb];
        f16x8 a1b = *(const f16x8*)&uB[w].A[lane & 15][kb];
        const f32x4 z4 = {0.f, 0.f, 0.f, 0.f};
        f32x4 Dz0a = __builtin_amdgcn_mfma_f32_16x16x32_f16(a1a, bz[0], z4, 0, 0, 0);
        f32x4 Dz1a = __builtin_amdgcn_mfma_f32_16x16x32_f16(a1a, bz[1], z4, 0, 0, 0);
        f32x4 Dz0b = __builtin_amdgcn_mfma_f32_16x16x32_f16(a1b, bz[0], z4, 0, 0, 0);
        f32x4 Dz1b = __builtin_amdgcn_mfma_f32_16x16x32_f16(a1b, bz[1], z4, 0, 0, 0);
        const int f0 = lane & 15, e0 = (lane >> 4) * 4;
        const float bb0 = br1[f0], bb1 = br1[16 + f0];
        #pragma unroll
        for (int t = 0; t < 2; t++) {
            f32x4 Dza = t ? Dz1a : Dz0a;
            f32x4 Dzb = t ? Dz1b : Dz0b;
            float bb = t ? bb1 : bb0;
            #pragma unroll
            for (int r = 0; r < 4; r++) {
                float za = Dza[r] + bb;
                float zb = Dzb[r] + bb;
                sQa[w][(e0 + r) * QP + t * 16 + f0] = (_Float16)(za * sigmoidf_(za));
                sQb[w][(e0 + r) * QP + t * 16 + f0] = (_Float16)(zb * sigmoidf_(zb));
            }
        }
    }

    // ---- phase 2: MFMA W2 -> D (both tiles) ----
    {
        f16x8 aqa = *(const f16x8*)&sQa[w][(lane & 15) * QP + kb];
        f16x8 aqb = *(const f16x8*)&sQb[w][(lane & 15) * QP + kb];
        const f32x4 z4 = {0.f, 0.f, 0.f, 0.f};
        const int cb = lane & 15, e0 = (lane >> 4) * 4;
        #pragma unroll
        for (int t = 0; t < 4; t++) {
            f32x4 da = __builtin_amdgcn_mfma_f32_16x16x32_f16(aqa, bf[t], z4, 0, 0, 0);
            f32x4 db = __builtin_amdgcn_mfma_f32_16x16x32_f16(aqb, bf[t], z4, 0, 0, 0);
            f16x4 ha, hb;
            #pragma unroll
            for (int r = 0; r < 4; r++) { ha[r] = (_Float16)da[r]; hb[r] = (_Float16)db[r]; }
            *(f16x4*)&uA[w].D[t * 16 + cb][e0] = ha;
            *(f16x4*)&uB[w].D[t * 16 + cb][e0] = hb;
        }
    }

    // ---- phase 3: epilogue, run-merge carried across both tiles ----
    int runKey = -1;
    float sAcc = 0.f, vXA = 0.f, vYA = 0.f, vZA = 0.f;
    #pragma unroll
    for (int t = 0; t < 2; t++) {
        const UAD* uu = t ? &uB[w] : &uA[w];
        #pragma unroll
        for (int i = 0; i < 8; i++) {
            const int m = t * 16 + hw * 8 + i;
            const int p = gbase + m;
            if (p >= E) break;
            int2 sd = order_sd[p];
            if (sd.y != runKey) {
                if (runKey >= 0) {
                    unsafeAtomicAdd(&s_acc[(size_t)runKey * 32 + l32], sAcc);
                    unsafeAtomicAdd(&v_acc[(size_t)runKey * 96 + 0 * 32 + l32], vXA);
                    unsafeAtomicAdd(&v_acc[(size_t)runKey * 96 + 1 * 32 + l32], vYA);
                    unsafeAtomicAdd(&v_acc[(size_t)runKey * 96 + 2 * 32 + l32], vZA);
                }
                runKey = sd.y;
                sAcc = vXA = vYA = vZA = 0.f;
            }
            float env = sSt[w][m][0], rhx = sSt[w][m][1], rhy = sSt[w][m][2], rhz = sSt[w][m][3];
            float rw0 = (float)uu->D[l32][m & 15];
            float rw1 = (float)uu->D[32 + l32][m & 15];
            int tyi = types[sd.x];
            float hs = (tyi == 0) ? te0 : ((tyi == 1) ? te1 : te2);
            sAcc += hs * rw0 * env;
            float hw1 = hs * rw1 * env;
            vXA += hw1 * rhx; vYA += hw1 * rhy; vZA += hw1 * rhz;
        }
    }
    if (runKey >= 0) {
        unsafeAtomicAdd(&s_acc[(size_t)runKey * 32 + l32], sAcc);
        unsafeAtomicAdd(&v_acc[(size_t)runKey * 96 + 0 * 32 + l32], vXA);
        unsafeAtomicAdd(&v_acc[(size_t)runKey * 96 + 1 * 32 + l32], vYA);
        unsafeAtomicAdd(&v_acc[(size_t)runKey * 96 + 2 * 32 + l32], vZA);
    }
}

// -------- atom MLP: 64 atoms/block, weights preloaded once --------
__global__ __launch_bounds__(256) void atom_mlp(
    const int* __restrict__ types, const float* __restrict__ temb,
    const float* __restrict__ Wself, const float* __restrict__ Wo1,
    const float* __restrict__ bo1, const float* __restrict__ Wo2,
    float* __restrict__ s_acc, float* __restrict__ v_acc,
    float* __restrict__ e_partial, int N)
{
    __shared__ float sWs[FDIM * FDIM], sWsT[FDIM * FDIM];
    __shared__ float sWo1[2 * FDIM * FDIM], sWo1T[2 * FDIM * FDIM];
    __shared__ float sb[FDIM], sW2o[FDIM], sTE[96];
    __shared__ float gred[8];
    for (int i = threadIdx.x; i < FDIM * FDIM; i += 256) {
        sWs[i] = Wself[i];
        sWsT[i] = Wself[(i & 31) * FDIM + (i >> 5)];
    }
    for (int i = threadIdx.x; i < 2 * FDIM * FDIM; i += 256) {
        sWo1[i] = Wo1[i];
        sWo1T[i] = Wo1[(i & 63) * FDIM + (i >> 6)];
    }
    for (int i = threadIdx.x; i < FDIM; i += 256) { sb[i] = bo1[i]; sW2o[i] = Wo2[i]; }
    for (int i = threadIdx.x; i < 96; i += 256) sTE[i] = temb[i];
    __syncthreads();

    const int lane = threadIdx.x & 31;
    const int g = threadIdx.x >> 5;
    float eAcc = 0.0f;

    for (int it = 0; it < 8; it++) {
        int a = blockIdx.x * 64 + it * 8 + g;
        const bool valid = (a < N);
        if (!valid) a = 0;

        float sv = s_acc[(size_t)a * FDIM + lane];
        float vx = v_acc[(size_t)a * 96 + 0 * 32 + lane];
        float vy = v_acc[(size_t)a * 96 + 1 * 32 + lane];
        float vz = v_acc[(size_t)a * 96 + 2 * 32 + lane];
        float h = sTE[types[a] * FDIM + lane];
        float vn = sqrtf(vx * vx + vy * vy + vz * vz + 1e-12f);

        float row = h;
        #pragma unroll
        for (int f = 0; f < FDIM; f++) {
            float t = __shfl(sv, f, 32);
            row += t * sWs[f * FDIM + lane];
        }
        float u = sb[lane];
        #pragma unroll
        for (int j = 0; j < FDIM; j++) {
            float rv = __shfl(row, j, 32);
            float vv = __shfl(vn, j, 32);
            u += rv * sWo1[j * FDIM + lane] + vv * sWo1[(j + FDIM) * FDIM + lane];
        }
        float sg = sigmoidf_(u);
        float au = u * sg;
        float pa = valid ? au * sW2o[lane] : 0.0f;
        #pragma unroll
        for (int m = 16; m; m >>= 1) pa += __shfl_xor(pa, m, 32);
        if (lane == 0) eAcc += pa;

        float gu = sW2o[lane] * (sg * (1.0f + u * (1.0f - sg)));
        float gfr = 0.0f, gfv = 0.0f;
        #pragma unroll
        for (int k = 0; k < FDIM; k++) {
            float gv_ = __shfl(gu, k, 32);
            gfr += gv_ * sWo1T[k * 64 + lane];
            gfv += gv_ * sWo1T[k * 64 + 32 + lane];
        }
        float gs = 0.0f;
        #pragma unroll
        for (int k = 0; k < FDIM; k++) {
            float gr = __shfl(gfr, k, 32);
            gs += gr * sWsT[k * FDIM + lane];
        }
        if (valid) {
            s_acc[(size_t)a * FDIM + lane] = gs;
            float sc = gfv / vn;
            v_acc[(size_t)a * 96 + 0 * 32 + lane] = sc * vx;
            v_acc[(size_t)a * 96 + 1 * 32 + lane] = sc * vy;
            v_acc[(size_t)a * 96 + 2 * 32 + lane] = sc * vz;
        }
    }
    if (lane == 0) gred[g] = eAcc;
    __syncthreads();
    if (threadIdx.x == 0) {
        float t = 0.0f;
        #pragma unroll
        for (int i = 0; i < 8; i++) t += gred[i];
        e_partial[blockIdx.x] = t;
    }
}

// ---------------- edge backward: dual-tile ILP, 3-way LDS aliasing, gm run-cache ----------------
// Per-tile regions as in r12: R1 = A(640) | T(640) -> Dq(1280); R2 = Q(640) -> Dt(1280).
// Two tiles (a,b) per wave give two independent dependency chains for ILP.
__global__ __launch_bounds__(256) void edge_bwd_mfma(
    const float* __restrict__ pos, const int* __restrict__ types,
    const int2* __restrict__ order_sd,
    const float* __restrict__ Wr1, const float* __restrict__ br1,
    const float* __restrict__ Wr2, const float* __restrict__ temb,
    const float* __restrict__ g_s, const float* __restrict__ g_v,
    float* __restrict__ forces, int E)
{
    __shared__ __align__(16) _Float16 sR1a[4][1280], sR2a[4][1280];
    __shared__ __align__(16) _Float16 sR1b[4][1280], sR2b[4][1280];
    __shared__ float sSt[4][32][8];       // rinv, env, denv, rhx, rhy, rhz

    const int lane = threadIdx.x & 63;
    const int l32 = threadIdx.x & 31;
    const int hw = (threadIdx.x >> 5) & 1;
    const int w = threadIdx.x >> 6;
    const int gbase = blockIdx.x * 128 + w * 32;

    const float te0 = temb[l32], te1 = temb[FDIM + l32], te2 = temb[2 * FDIM + l32];

    const int kb = (lane >> 4) * 8, nb = lane & 15;
    f16x8 bz[2], bt[2];
    #pragma unroll
    for (int t = 0; t < 2; t++)
        #pragma unroll
        for (int j = 0; j < 8; j++) {
            int k = kb + j;
            bz[t][j] = (k < 8) ? (_Float16)Wr1[k * FDIM + t * 16 + nb] : (_Float16)0.0f;
            bt[t][j] = (k >= 8 && k < 16) ? (_Float16)Wr1[(k - 8) * FDIM + t * 16 + nb] : (_Float16)0.0f;
        }
    f16x8 bf[4];
    #pragma unroll
    for (int t = 0; t < 4; t++)
        #pragma unroll
        for (int j = 0; j < 8; j++)
            bf[t][j] = (_Float16)Wr2[(kb + j) * 64 + t * 16 + nb];

    // ---- phase 0: lane-parallel geometry + basis/dbasis (lanes 0..31) ----
    if (lane < 32) {
        const int ed = lane;
        const int p = gbase + ed;
        int2 sd = (p < E) ? order_sd[p] : make_int2(0, 0);
        float rx = (pos[sd.y * 3 + 0] - pos[sd.x * 3 + 0]) * NM2A_C;
        float ry = (pos[sd.y * 3 + 1] - pos[sd.x * 3 + 1]) * NM2A_C;
        float rz = (pos[sd.y * 3 + 2] - pos[sd.x * 3 + 2]) * NM2A_C;
        float r2 = rx * rx + ry * ry + rz * rz + 1e-12f;
        float r = sqrtf(r2);
        float rinv = 1.0f / r;
        float x = r * (1.0f / RCUT_C);
        float x2 = x * x, x4 = x2 * x2, x5 = x4 * x, x6 = x4 * x2, x7 = x6 * x, x8 = x6 * x2;
        float env = (x < 1.0f) ? (1.0f - 28.0f * x6 + 48.0f * x7 - 21.0f * x8) : 0.0f;
        float denv = (x < 1.0f) ? (-168.0f * x5 + 336.0f * x6 - 168.0f * x7) * (1.0f / RCUT_C) : 0.0f;

        float th = PI_F * x, s1, c1;
        __sincosf(th, &s1, &c1);
        float sp = 0.0f, sn = s1, cp = 1.0f, cn = c1;
        _Float16 av[16];
        #pragma unroll
        for (int n = 0; n < NBASIS; n++) {
            float basis = sn * rinv;
            float dbdr = (PI_F * (float)(n + 1) * (1.0f / RCUT_C)) * cn * rinv - basis * rinv;
            av[n] = (_Float16)basis;
            av[8 + n] = (_Float16)dbdr;
            float snx = 2.0f * c1 * sn - sp; sp = sn; sn = snx;
            float cnx = 2.0f * c1 * cn - cp; cp = cn; cn = cnx;
        }
        _Float16* dstA = (ed < 16) ? &sR1a[w][(ed & 15) * QP] : &sR1b[w][(ed & 15) * QP];
        *(f16x8*)&dstA[0] = *(f16x8*)&av[0];
        *(f16x8*)&dstA[8] = *(f16x8*)&av[8];
        *(float4*)&dstA[16] = make_float4(0.f, 0.f, 0.f, 0.f);
        *(float4*)&dstA[24] = make_float4(0.f, 0.f, 0.f, 0.f);
        sSt[w][ed][0] = rinv;
        sSt[w][ed][1] = env;
        sSt[w][ed][2] = denv;
        sSt[w][ed][3] = rx * rinv;
        sSt[w][ed][4] = ry * rinv;
        sSt[w][ed][5] = rz * rinv;
    }

    // ---- phase 1: MFMA basis layer (both tiles) -> z, tacc; silu/tf -> Q/T ----
    {
        f16x8 a1a = *(const f16x8*)&sR1a[w][(lane & 15) * QP + kb];
        f16x8 a1b = *(const f16x8*)&sR1b[w][(lane & 15) * QP + kb];
        const f32x4 z4 = {0.f, 0.f, 0.f, 0.f};
        f32x4 Dz0a = __builtin_amdgcn_mfma_f32_16x16x32_f16(a1a, bz[0], z4, 0, 0, 0);
        f32x4 Dz1a = __builtin_amdgcn_mfma_f32_16x16x32_f16(a1a, bz[1], z4, 0, 0, 0);
        f32x4 Dt0a = __builtin_amdgcn_mfma_f32_16x16x32_f16(a1a, bt[0], z4, 0, 0, 0);
        f32x4 Dt1a = __builtin_amdgcn_mfma_f32_16x16x32_f16(a1a, bt[1], z4, 0, 0, 0);
        f32x4 Dz0b = __builtin_amdgcn_mfma_f32_16x16x32_f16(a1b, bz[0], z4, 0, 0, 0);
        f32x4 Dz1b = __builtin_amdgcn_mfma_f32_16x16x32_f16(a1b, bz[1], z4, 0, 0, 0);
        f32x4 Dt0b = __builtin_amdgcn_mfma_f32_16x16x32_f16(a1b, bt[0], z4, 0, 0, 0);
        f32x4 Dt1b = __builtin_amdgcn_mfma_f32_16x16x32_f16(a1b, bt[1], z4, 0, 0, 0);
        const int f0 = lane & 15, e0 = (lane >> 4) * 4;
        const float bb0 = br1[f0], bb1 = br1[16 + f0];
        #pragma unroll
        for (int t = 0; t < 2; t++) {
            f32x4 Dza = t ? Dz1a : Dz0a;
            f32x4 Dta = t ? Dt1a : Dt0a;
            f32x4 Dzb = t ? Dz1b : Dz0b;
            f32x4 Dtb = t ? Dt1b : Dt0b;
            float bb = t ? bb1 : bb0;
            #pragma unroll
            for (int r = 0; r < 4; r++) {
                float za = Dza[r] + bb;
                float sga = sigmoidf_(za);
                sR2a[w][(e0 + r) * QP + t * 16 + f0] = (_Float16)(za * sga);
                sR1a[w][640 + (e0 + r) * QP + t * 16 + f0] =
                    (_Float16)((sga * (1.0f + za * (1.0f - sga))) * Dta[r]);
                float zb = Dzb[r] + bb;
                float sgb = sigmoidf_(zb);
                sR2b[w][(e0 + r) * QP + t * 16 + f0] = (_Float16)(zb * sgb);
                sR1b[w][640 + (e0 + r) * QP + t * 16 + f0] =
                    (_Float16)((sgb * (1.0f + zb * (1.0f - sgb))) * Dtb[r]);
            }
        }
    }

    // ---- phase 2: 16 MFMAs (W2 on q and tf, both tiles); D overwrites stages ----
    {
        f16x8 aqa = *(const f16x8*)&sR2a[w][(lane & 15) * QP + kb];
        f16x8 ata = *(const f16x8*)&sR1a[w][640 + (lane & 15) * QP + kb];
        f16x8 aqb = *(const f16x8*)&sR2b[w][(lane & 15) * QP + kb];
        f16x8 atb = *(const f16x8*)&sR1b[w][640 + (lane & 15) * QP + kb];
        const f32x4 z4 = {0.f, 0.f, 0.f, 0.f};
        const int cb = lane & 15, e0 = (lane >> 4) * 4;
        #pragma unroll
        for (int t = 0; t < 4; t++) {
            f32x4 dqa = __builtin_amdgcn_mfma_f32_16x16x32_f16(aqa, bf[t], z4, 0, 0, 0);
            f32x4 dta = __builtin_amdgcn_mfma_f32_16x16x32_f16(ata, bf[t], z4, 0, 0, 0);
            f32x4 dqb = __builtin_amdgcn_mfma_f32_16x16x32_f16(aqb, bf[t], z4, 0, 0, 0);
            f32x4 dtb = __builtin_amdgcn_mfma_f32_16x16x32_f16(atb, bf[t], z4, 0, 0, 0);
            f16x4 hqa, hta, hqb, htb;
            #pragma unroll
            for (int r = 0; r < 4; r++) {
                hqa[r] = (_Float16)dqa[r]; hta[r] = (_Float16)dta[r];
                hqb[r] = (_Float16)dqb[r]; htb[r] = (_Float16)dtb[r];
            }
            *(f16x4*)&sR1a[w][(t * 16 + cb) * EP + e0] = hqa;
            *(f16x4*)&sR2a[w][(t * 16 + cb) * EP + e0] = hta;
            *(f16x4*)&sR1b[w][(t * 16 + cb) * EP + e0] = hqb;
            *(f16x4*)&sR2b[w][(t * 16 + cb) * EP + e0] = htb;
        }
    }

    // ---- phase 3: epilogue (gm cached per dst-run, carried across tiles) ----
    const float SC = EV2KJ_C * NM2A_C;
    int runKey = -1;
    float fAcc = 0.f;
    float gm0 = 0.f, gm1x = 0.f, gm1y = 0.f, gm1z = 0.f;
    #pragma unroll
    for (int t = 0; t < 2; t++) {
        const _Float16* Dq = t ? &sR1b[w][0] : &sR1a[w][0];
        const _Float16* Dt = t ? &sR2b[w][0] : &sR2a[w][0];
        #pragma unroll
        for (int i = 0; i < 8; i++) {
            const int m = t * 16 + hw * 8 + i;
            const int p = gbase + m;
            if (p >= E) break;
            int2 sd = order_sd[p];
            if (sd.y != runKey) {
                if (runKey >= 0 && l32 < 3)
                    unsafeAtomicAdd(&forces[(size_t)runKey * 3 + l32], -SC * fAcc);
                runKey = sd.y;
                fAcc = 0.f;
                gm0  = g_s[(size_t)sd.y * FDIM + l32];
                gm1x = g_v[(size_t)sd.y * 96 + 0 * 32 + l32];
                gm1y = g_v[(size_t)sd.y * 96 + 1 * 32 + l32];
                gm1z = g_v[(size_t)sd.y * 96 + 2 * 32 + l32];
            }
            float rinv = sSt[w][m][0], env = sSt[w][m][1], denv = sSt[w][m][2];
            float rhx = sSt[w][m][3], rhy = sSt[w][m][4], rhz = sSt[w][m][5];
            const int me = m & 15;
            float rw0 = (float)Dq[l32 * EP + me];
            float rw1 = (float)Dq[(32 + l32) * EP + me];
            float u0  = (float)Dt[l32 * EP + me];
            float u1v = (float)Dt[(32 + l32) * EP + me];

            int tyi = types[sd.x];
            float hs = (tyi == 0) ? te0 : ((tyi == 1) ? te1 : te2);

            float gw0 = hs * gm0;
            float gw1 = hs * (gm1x * rhx + gm1y * rhy + gm1z * rhz);
            float hw1 = hs * rw1 * env;
            float grx = hw1 * gm1x, gry = hw1 * gm1y, grz = hw1 * gm1z;
            float genv = gw0 * rw0 + gw1 * rw1;
            float pc = (gw0 * env) * u0 + (gw1 * env) * u1v + genv * denv;
            float pg = pc - (grx * rhx + gry * rhy + grz * rhz) * rinv;

            // channel-packed butterfly: lane%4 -> {Gx,Gy,Gz,beta}
            float a1 = grx + __shfl_xor(grx, 1, 32);
            float b1v = gry + __shfl_xor(gry, 1, 32);
            float c1v = grz + __shfl_xor(grz, 1, 32);
            float d1 = pg + __shfl_xor(pg, 1, 32);
            float e0v = (l32 & 1) ? b1v : a1;
            float e1v = (l32 & 1) ? d1 : c1v;
            e0v += __shfl_xor(e0v, 2, 32);
            e1v += __shfl_xor(e1v, 2, 32);
            float v = (l32 & 2) ? e1v : e0v;
            v += __shfl_xor(v, 4, 32);
            v += __shfl_xor(v, 8, 32);
            v += __shfl_xor(v, 16, 32);
            float beta = __shfl(v, l32 | 3, 32);

            if (l32 < 3) {
                float rh_l = (l32 == 0) ? rhx : ((l32 == 1) ? rhy : rhz);
                float comp = v * rinv + rh_l * beta;
                unsafeAtomicAdd(&forces[(size_t)sd.x * 3 + l32], SC * comp);
                fAcc += comp;
            }
        }
    }
    if (runKey >= 0 && l32 < 3)
        unsafeAtomicAdd(&forces[(size_t)runKey * 3 + l32], -SC * fAcc);
}

// ---------------- reductions & correction ----------------
__global__ __launch_bounds__(256) void reduce_energy(
    const float* __restrict__ e_partial, int n, float* __restrict__ out)
{
    __shared__ float red[256];
    float s = 0.0f;
    for (int i = threadIdx.x; i < n; i += 256) s += e_partial[i];
    red[threadIdx.x] = s;
    __syncthreads();
    for (int k = 128; k; k >>= 1) {
        if (threadIdx.x < k) red[threadIdx.x] += red[threadIdx.x + k];
        __syncthreads();
    }
    if (threadIdx.x == 0) out[0] = red[0] * EV2KJ_C;
}

__global__ __launch_bounds__(256) void reduce_net(
    const float* __restrict__ f, const float* __restrict__ masses,
    float* __restrict__ accum, int N)
{
    float nx = 0, ny = 0, nz = 0, ms = 0;
    for (int i = blockIdx.x * 256 + threadIdx.x; i < N; i += gridDim.x * 256) {
        nx += f[i * 3 + 0]; ny += f[i * 3 + 1]; nz += f[i * 3 + 2]; ms += masses[i];
    }
    #pragma unroll
    for (int m = 32; m; m >>= 1) {
        nx += __shfl_xor(nx, m, 64);
        ny += __shfl_xor(ny, m, 64);
        nz += __shfl_xor(nz, m, 64);
        ms += __shfl_xor(ms, m, 64);
    }
    __shared__ float red[4][4];
    int w = threadIdx.x >> 6;
    if ((threadIdx.x & 63) == 0) { red[w][0] = nx; red[w][1] = ny; red[w][2] = nz; red[w][3] = ms; }
    __syncthreads();
    if (threadIdx.x == 0) {
        float a0 = 0, a1 = 0, a2 = 0, a3 = 0;
        for (int i = 0; i < 4; i++) { a0 += red[i][0]; a1 += red[i][1]; a2 += red[i][2]; a3 += red[i][3]; }
        unsafeAtomicAdd(accum + 0, a0);
        unsafeAtomicAdd(accum + 1, a1);
        unsafeAtomicAdd(accum + 2, a2);
        unsafeAtomicAdd(accum + 3, a3);
    }
}

__global__ __launch_bounds__(256) void correct_forces(
    float* __restrict__ f, const float* __restrict__ masses,
    const float* __restrict__ accum, int N)
{
    int i = blockIdx.x * 256 + threadIdx.x;
    if (i < N) {
        float c = masses[i] / accum[3];
        f[i * 3 + 0] -= c * accum[0];
        f[i * 3 + 1] -= c * accum[1];
        f[i * 3 + 2] -= c * accum[2];
    }
}

extern "C" void kernel_launch(void* const* d_in, const int* in_sizes, int n_in,
                              void* d_out, int out_size, void* d_ws, size_t ws_size,
                              hipStream_t stream)
{
    (void)n_in; (void)ws_size;
    const float* pos    = (const float*)d_in[0];
    const float* masses = (const float*)d_in[1];
    const float* temb   = (const float*)d_in[2];
    const float* Wr1    = (const float*)d_in[3];
    const float* br1    = (const float*)d_in[4];
    const float* Wr2    = (const float*)d_in[5];
    const float* Wself  = (const float*)d_in[6];
    const float* Wo1    = (const float*)d_in[7];
    const float* bo1    = (const float*)d_in[8];
    const float* Wo2    = (const float*)d_in[9];
    const int* types    = (const int*)d_in[10];
    const int* eidx     = (const int*)d_in[11];
    const int N = in_sizes[1];
    const int E = in_sizes[11] / 2;

    float* out = (float*)d_out;
    float* forces = out + 1;

    float* ws = (float*)d_ws;
    float* s_acc = ws;                               // N*32
    float* v_acc = s_acc + (size_t)N * FDIM;         // N*96
    int nAtomBlocks = (N + 63) / 64;
    float* e_partial = v_acc + (size_t)N * 96;       // nAtomBlocks
    float* accum = e_partial + nAtomBlocks;          // 4
    int* counts = (int*)(accum + 4);                 // N
    int* cursor = counts + N;                        // N
    int2* order_sd = (int2*)(cursor + N);            // E int2
    int nScan = (N + SCH - 1) / SCH;
    int* bsum = (int*)(order_sd + E);                // nScan

    hipMemsetAsync(d_out, 0, (size_t)out_size * sizeof(float), stream);
    hipMemsetAsync(s_acc, 0, (size_t)N * 128 * sizeof(float), stream);
    hipMemsetAsync(counts, 0, (size_t)N * sizeof(int), stream);
    hipMemsetAsync(accum, 0, 4 * sizeof(float), stream);

    hist_dst<<<2048, 256, 0, stream>>>(eidx, counts, E);
    scan_partial<<<nScan, 256, 0, stream>>>(counts, bsum, N);
    scan_bsum<<<1, 64, 0, stream>>>(bsum, nScan);
    scan_write<<<nScan, 256, 0, stream>>>(counts, bsum, cursor, N);
    scatter_edges<<<2048, 256, 0, stream>>>(eidx, cursor, order_sd, E);

    int nEdgeBlocks = (E + 127) / 128;
    edge_fwd_mfma<<<nEdgeBlocks, 256, 0, stream>>>(pos, types, order_sd,
                                                   Wr1, br1, Wr2, temb,
                                                   s_acc, v_acc, E);
    atom_mlp<<<nAtomBlocks, 256, 0, stream>>>(types, temb, Wself, Wo1, bo1, Wo2,
                                              s_acc, v_acc, e_partial, N);
    reduce_energy<<<1, 256, 0, stream>>>(e_partial, nAtomBlocks, out);
    edge_bwd_mfma<<<nEdgeBlocks, 256, 0, stream>>>(pos, types, order_sd,
                                                   Wr1, br1, Wr2, temb,
                                                   s_acc, v_acc, forces, E);
    reduce_net<<<64, 256, 0, stream>>>(forces, masses, accum, N);
    correct_forces<<<(N + 255) / 256, 256, 0, stream>>>(forces, masses, accum, N);
}

// Round 14
// 598.436 us; speedup vs baseline: 1.1628x; 1.0695x over previous
//
#include <hip/hip_runtime.h>
#include <math.h>

#define FDIM 32
#define NBASIS 8
#define QP 40     // A-stage row pad (f16 units) -> 80B rows, 16B-aligned quads
#define EP 20     // fwd D-stage edge-dim pad (f16 units)
#define SCH 4096  // scan chunk per block (256 thr x 16)

constexpr float RCUT_C = 20.0f;
constexpr float PI_F = 3.14159265358979323846f;
constexpr float EV2KJ_C = 96.4853f;
constexpr float NM2A_C = 10.0f;

typedef _Float16 f16x8 __attribute__((ext_vector_type(8)));
typedef _Float16 f16x4 __attribute__((ext_vector_type(4)));
typedef float f32x4 __attribute__((ext_vector_type(4)));

__device__ __forceinline__ float sigmoidf_(float z) { return 1.0f / (1.0f + __expf(-z)); }

__device__ __forceinline__ unsigned int pk2_(float a, float b) {
    unsigned short lo = __builtin_bit_cast(unsigned short, (_Float16)a);
    unsigned short hi = __builtin_bit_cast(unsigned short, (_Float16)b);
    return (unsigned int)lo | ((unsigned int)hi << 16);
}
__device__ __forceinline__ float lo16_(unsigned int v) {
    return (float)__builtin_bit_cast(_Float16, (unsigned short)(v & 0xffffu));
}
__device__ __forceinline__ float hi16_(unsigned int v) {
    return (float)__builtin_bit_cast(_Float16, (unsigned short)(v >> 16));
}

// ---------------- CSR build: histogram, 3-kernel scan, scatter ----------------
__global__ __launch_bounds__(256) void hist_dst(
    const int* __restrict__ eidx, int* __restrict__ counts, int E)
{
    for (int e = blockIdx.x * 256 + threadIdx.x; e < E; e += gridDim.x * 256)
        atomicAdd(&counts[eidx[E + e]], 1);
}

__global__ __launch_bounds__(256) void scan_partial(
    const int* __restrict__ counts, int* __restrict__ bsum, int N)
{
    __shared__ int red[256];
    const int t = threadIdx.x;
    const int st = blockIdx.x * SCH + t * 16;
    int s = 0;
    #pragma unroll
    for (int i = 0; i < 16; i++) { int idx = st + i; if (idx < N) s += counts[idx]; }
    red[t] = s;
    __syncthreads();
    for (int k = 128; k; k >>= 1) {
        if (t < k) red[t] += red[t + k];
        __syncthreads();
    }
    if (t == 0) bsum[blockIdx.x] = red[0];
}

__global__ __launch_bounds__(64) void scan_bsum(int* __restrict__ bsum, int nb)
{
    if (threadIdx.x == 0) {
        int run = 0;
        for (int i = 0; i < nb; i++) { int v = bsum[i]; bsum[i] = run; run += v; }
    }
}

__global__ __launch_bounds__(256) void scan_write(
    const int* __restrict__ counts, const int* __restrict__ bsum,
    int* __restrict__ cursor, int N)
{
    __shared__ int lds[256];
    const int t = threadIdx.x;
    const int st = blockIdx.x * SCH + t * 16;
    int vals[16];
    int s = 0;
    #pragma unroll
    for (int i = 0; i < 16; i++) {
        int idx = st + i;
        int v = (idx < N) ? counts[idx] : 0;
        vals[i] = v; s += v;
    }
    lds[t] = s;
    __syncthreads();
    for (int off = 1; off < 256; off <<= 1) {
        int v = (t >= off) ? lds[t - off] : 0;
        __syncthreads();
        lds[t] += v;
        __syncthreads();
    }
    int run = bsum[blockIdx.x] + lds[t] - s;   // exclusive prefix
    #pragma unroll
    for (int i = 0; i < 16; i++) {
        int idx = st + i;
        if (idx < N) cursor[idx] = run;
        run += vals[i];
    }
}

__global__ __launch_bounds__(256) void scatter_edges(
    const int* __restrict__ eidx, int* __restrict__ cursor,
    int2* __restrict__ order_sd, int E)
{
    for (int e = blockIdx.x * 256 + threadIdx.x; e < E; e += gridDim.x * 256) {
        int dst = eidx[E + e];
        int p = atomicAdd(&cursor[dst], 1);
        order_sd[p] = make_int2(eidx[e], dst);
    }
}

// ---------------- edge forward: dual-tile, dual-MFMA, LDS-aliased (r13 form) ----------------
__global__ __launch_bounds__(256) void edge_fwd_mfma(
    const float* __restrict__ pos, const int* __restrict__ types,
    const int2* __restrict__ order_sd,
    const float* __restrict__ Wr1, const float* __restrict__ br1,
    const float* __restrict__ Wr2, const float* __restrict__ temb,
    float* __restrict__ s_acc, float* __restrict__ v_acc, int E)
{
    union UAD { _Float16 A[16][QP]; _Float16 D[64][EP]; };
    __shared__ __align__(16) UAD uA[4], uB[4];
    __shared__ __align__(16) _Float16 sQa[4][16 * QP], sQb[4][16 * QP];
    __shared__ float sSt[4][32][4];         // env, rhx, rhy, rhz

    const int lane = threadIdx.x & 63;
    const int l32 = threadIdx.x & 31;
    const int hw = (threadIdx.x >> 5) & 1;
    const int w = threadIdx.x >> 6;
    const int gbase = blockIdx.x * 128 + w * 32;

    const float te0 = temb[l32], te1 = temb[FDIM + l32], te2 = temb[2 * FDIM + l32];

    const int kb = (lane >> 4) * 8, nb = lane & 15;
    f16x8 bz[2];
    #pragma unroll
    for (int t = 0; t < 2; t++)
        #pragma unroll
        for (int j = 0; j < 8; j++) {
            int k = kb + j;
            bz[t][j] = (k < 8) ? (_Float16)Wr1[k * FDIM + t * 16 + nb] : (_Float16)0.0f;
        }
    f16x8 bf[4];
    #pragma unroll
    for (int t = 0; t < 4; t++)
        #pragma unroll
        for (int j = 0; j < 8; j++)
            bf[t][j] = (_Float16)Wr2[(kb + j) * 64 + t * 16 + nb];

    // ---- phase 0: lane-parallel geometry + basis (lanes 0..31, one edge each) ----
    if (lane < 32) {
        const int ed = lane;
        const int p = gbase + ed;
        int2 sd = (p < E) ? order_sd[p] : make_int2(0, 0);
        float rx = (pos[sd.y * 3 + 0] - pos[sd.x * 3 + 0]) * NM2A_C;
        float ry = (pos[sd.y * 3 + 1] - pos[sd.x * 3 + 1]) * NM2A_C;
        float rz = (pos[sd.y * 3 + 2] - pos[sd.x * 3 + 2]) * NM2A_C;
        float r2 = rx * rx + ry * ry + rz * rz + 1e-12f;
        float r = sqrtf(r2);
        float rinv = 1.0f / r;
        float x = r * (1.0f / RCUT_C);
        float x2 = x * x, x4 = x2 * x2, x6 = x4 * x2, x7 = x6 * x, x8 = x6 * x2;
        float env = (x < 1.0f) ? (1.0f - 28.0f * x6 + 48.0f * x7 - 21.0f * x8) : 0.0f;

        float th = PI_F * x, s1, c1;
        __sincosf(th, &s1, &c1);
        float sp = 0.0f, sn = s1;
        _Float16 av[8];
        #pragma unroll
        for (int n = 0; n < NBASIS; n++) {
            av[n] = (_Float16)(sn * rinv);
            float snx = 2.0f * c1 * sn - sp; sp = sn; sn = snx;
        }
        _Float16* dstA = (ed < 16) ? &uA[w].A[ed & 15][0] : &uB[w].A[ed & 15][0];
        *(f16x8*)&dstA[0] = *(f16x8*)&av[0];
        *(float4*)&dstA[8]  = make_float4(0.f, 0.f, 0.f, 0.f);
        *(float4*)&dstA[16] = make_float4(0.f, 0.f, 0.f, 0.f);
        *(float4*)&dstA[24] = make_float4(0.f, 0.f, 0.f, 0.f);
        sSt[w][ed][0] = env;
        sSt[w][ed][1] = rx * rinv;
        sSt[w][ed][2] = ry * rinv;
        sSt[w][ed][3] = rz * rinv;
    }

    // ---- phase 1: MFMA basis layer -> z, silu -> Q (both tiles) ----
    {
        f16x8 a1a = *(const f16x8*)&uA[w].A[lane & 15][kb];
        f16x8 a1b = *(const f16x8*)&uB[w].A[lane & 15][kb];
        const f32x4 z4 = {0.f, 0.f, 0.f, 0.f};
        f32x4 Dz0a = __builtin_amdgcn_mfma_f32_16x16x32_f16(a1a, bz[0], z4, 0, 0, 0);
        f32x4 Dz1a = __builtin_amdgcn_mfma_f32_16x16x32_f16(a1a, bz[1], z4, 0, 0, 0);
        f32x4 Dz0b = __builtin_amdgcn_mfma_f32_16x16x32_f16(a1b, bz[0], z4, 0, 0, 0);
        f32x4 Dz1b = __builtin_amdgcn_mfma_f32_16x16x32_f16(a1b, bz[1], z4, 0, 0, 0);
        const int f0 = lane & 15, e0 = (lane >> 4) * 4;
        const float bb0 = br1[f0], bb1 = br1[16 + f0];
        #pragma unroll
        for (int t = 0; t < 2; t++) {
            f32x4 Dza = t ? Dz1a : Dz0a;
            f32x4 Dzb = t ? Dz1b : Dz0b;
            float bb = t ? bb1 : bb0;
            #pragma unroll
            for (int r = 0; r < 4; r++) {
                float za = Dza[r] + bb;
                float zb = Dzb[r] + bb;
                sQa[w][(e0 + r) * QP + t * 16 + f0] = (_Float16)(za * sigmoidf_(za));
                sQb[w][(e0 + r) * QP + t * 16 + f0] = (_Float16)(zb * sigmoidf_(zb));
            }
        }
    }

    // ---- phase 2: MFMA W2 -> D (both tiles) ----
    {
        f16x8 aqa = *(const f16x8*)&sQa[w][(lane & 15) * QP + kb];
        f16x8 aqb = *(const f16x8*)&sQb[w][(lane & 15) * QP + kb];
        const f32x4 z4 = {0.f, 0.f, 0.f, 0.f};
        const int cb = lane & 15, e0 = (lane >> 4) * 4;
        #pragma unroll
        for (int t = 0; t < 4; t++) {
            f32x4 da = __builtin_amdgcn_mfma_f32_16x16x32_f16(aqa, bf[t], z4, 0, 0, 0);
            f32x4 db = __builtin_amdgcn_mfma_f32_16x16x32_f16(aqb, bf[t], z4, 0, 0, 0);
            f16x4 ha, hb;
            #pragma unroll
            for (int r = 0; r < 4; r++) { ha[r] = (_Float16)da[r]; hb[r] = (_Float16)db[r]; }
            *(f16x4*)&uA[w].D[t * 16 + cb][e0] = ha;
            *(f16x4*)&uB[w].D[t * 16 + cb][e0] = hb;
        }
    }

    // ---- phase 3: epilogue, run-merge carried across both tiles ----
    int runKey = -1;
    float sAcc = 0.f, vXA = 0.f, vYA = 0.f, vZA = 0.f;
    #pragma unroll
    for (int t = 0; t < 2; t++) {
        const UAD* uu = t ? &uB[w] : &uA[w];
        #pragma unroll
        for (int i = 0; i < 8; i++) {
            const int m = t * 16 + hw * 8 + i;
            const int p = gbase + m;
            if (p >= E) break;
            int2 sd = order_sd[p];
            if (sd.y != runKey) {
                if (runKey >= 0) {
                    unsafeAtomicAdd(&s_acc[(size_t)runKey * 32 + l32], sAcc);
                    unsafeAtomicAdd(&v_acc[(size_t)runKey * 96 + 0 * 32 + l32], vXA);
                    unsafeAtomicAdd(&v_acc[(size_t)runKey * 96 + 1 * 32 + l32], vYA);
                    unsafeAtomicAdd(&v_acc[(size_t)runKey * 96 + 2 * 32 + l32], vZA);
                }
                runKey = sd.y;
                sAcc = vXA = vYA = vZA = 0.f;
            }
            float env = sSt[w][m][0], rhx = sSt[w][m][1], rhy = sSt[w][m][2], rhz = sSt[w][m][3];
            float rw0 = (float)uu->D[l32][m & 15];
            float rw1 = (float)uu->D[32 + l32][m & 15];
            int tyi = types[sd.x];
            float hs = (tyi == 0) ? te0 : ((tyi == 1) ? te1 : te2);
            sAcc += hs * rw0 * env;
            float hw1 = hs * rw1 * env;
            vXA += hw1 * rhx; vYA += hw1 * rhy; vZA += hw1 * rhz;
        }
    }
    if (runKey >= 0) {
        unsafeAtomicAdd(&s_acc[(size_t)runKey * 32 + l32], sAcc);
        unsafeAtomicAdd(&v_acc[(size_t)runKey * 96 + 0 * 32 + l32], vXA);
        unsafeAtomicAdd(&v_acc[(size_t)runKey * 96 + 1 * 32 + l32], vYA);
        unsafeAtomicAdd(&v_acc[(size_t)runKey * 96 + 2 * 32 + l32], vZA);
    }
}

// -------- atom MLP: 64 atoms/block; g_v written FEATURE-MAJOR [a*96 + f*3 + c] --------
__global__ __launch_bounds__(256) void atom_mlp(
    const int* __restrict__ types, const float* __restrict__ temb,
    const float* __restrict__ Wself, const float* __restrict__ Wo1,
    const float* __restrict__ bo1, const float* __restrict__ Wo2,
    float* __restrict__ s_acc, float* __restrict__ v_acc,
    float* __restrict__ e_partial, int N)
{
    __shared__ float sWs[FDIM * FDIM], sWsT[FDIM * FDIM];
    __shared__ float sWo1[2 * FDIM * FDIM], sWo1T[2 * FDIM * FDIM];
    __shared__ float sb[FDIM], sW2o[FDIM], sTE[96];
    __shared__ float gred[8];
    for (int i = threadIdx.x; i < FDIM * FDIM; i += 256) {
        sWs[i] = Wself[i];
        sWsT[i] = Wself[(i & 31) * FDIM + (i >> 5)];
    }
    for (int i = threadIdx.x; i < 2 * FDIM * FDIM; i += 256) {
        sWo1[i] = Wo1[i];
        sWo1T[i] = Wo1[(i & 63) * FDIM + (i >> 6)];
    }
    for (int i = threadIdx.x; i < FDIM; i += 256) { sb[i] = bo1[i]; sW2o[i] = Wo2[i]; }
    for (int i = threadIdx.x; i < 96; i += 256) sTE[i] = temb[i];
    __syncthreads();

    const int lane = threadIdx.x & 31;
    const int g = threadIdx.x >> 5;
    float eAcc = 0.0f;

    for (int it = 0; it < 8; it++) {
        int a = blockIdx.x * 64 + it * 8 + g;
        const bool valid = (a < N);
        if (!valid) a = 0;

        float sv = s_acc[(size_t)a * FDIM + lane];
        float vx = v_acc[(size_t)a * 96 + 0 * 32 + lane];
        float vy = v_acc[(size_t)a * 96 + 1 * 32 + lane];
        float vz = v_acc[(size_t)a * 96 + 2 * 32 + lane];
        float h = sTE[types[a] * FDIM + lane];
        float vn = sqrtf(vx * vx + vy * vy + vz * vz + 1e-12f);

        float row = h;
        #pragma unroll
        for (int f = 0; f < FDIM; f++) {
            float t = __shfl(sv, f, 32);
            row += t * sWs[f * FDIM + lane];
        }
        float u = sb[lane];
        #pragma unroll
        for (int j = 0; j < FDIM; j++) {
            float rv = __shfl(row, j, 32);
            float vv = __shfl(vn, j, 32);
            u += rv * sWo1[j * FDIM + lane] + vv * sWo1[(j + FDIM) * FDIM + lane];
        }
        float sg = sigmoidf_(u);
        float au = u * sg;
        float pa = valid ? au * sW2o[lane] : 0.0f;
        #pragma unroll
        for (int m = 16; m; m >>= 1) pa += __shfl_xor(pa, m, 32);
        if (lane == 0) eAcc += pa;

        float gu = sW2o[lane] * (sg * (1.0f + u * (1.0f - sg)));
        float gfr = 0.0f, gfv = 0.0f;
        #pragma unroll
        for (int k = 0; k < FDIM; k++) {
            float gv_ = __shfl(gu, k, 32);
            gfr += gv_ * sWo1T[k * 64 + lane];
            gfv += gv_ * sWo1T[k * 64 + 32 + lane];
        }
        float gs = 0.0f;
        #pragma unroll
        for (int k = 0; k < FDIM; k++) {
            float gr = __shfl(gfr, k, 32);
            gs += gr * sWsT[k * FDIM + lane];
        }
        if (valid) {
            s_acc[(size_t)a * FDIM + lane] = gs;
            float sc = gfv / vn;
            // feature-major write for bwd's per-edge-lane gather
            v_acc[(size_t)a * 96 + lane * 3 + 0] = sc * vx;
            v_acc[(size_t)a * 96 + lane * 3 + 1] = sc * vy;
            v_acc[(size_t)a * 96 + lane * 3 + 2] = sc * vz;
        }
    }
    if (lane == 0) gred[g] = eAcc;
    __syncthreads();
    if (threadIdx.x == 0) {
        float t = 0.0f;
        #pragma unroll
        for (int i = 0; i < 8; i++) t += gred[i];
        e_partial[blockIdx.x] = t;
    }
}

// ---------------- edge backward: transposed (edge-per-lane) epilogue ----------------
// Per wave: 32 edges = 2 MFMA tiles. LDS regions (f16 units):
//  R1[2560]: A_a[0,640) A_b[640,1280) T_a[1280,1920) T_b[1920,2560)
//            -> after phase2: Dq packed f16x2 [tile*512 + f*16 + e] (uint units, [0,1024))
//  R2[2048]: Q_a[0,640) Q_b[640,1280) -> Dt packed likewise [0,1024) uints.
// hs (type_embed) is folded into D in phase 2; epilogue lane e loops f with
// private accumulators (no cross-lane reduction); dst scatter via segmented lane scan.
__global__ __launch_bounds__(256) void edge_bwd_mfma(
    const float* __restrict__ pos, const int* __restrict__ types,
    const int2* __restrict__ order_sd,
    const float* __restrict__ Wr1, const float* __restrict__ br1,
    const float* __restrict__ Wr2, const float* __restrict__ temb,
    const float* __restrict__ g_s, const float* __restrict__ g_v,
    float* __restrict__ forces, int E)
{
    __shared__ __align__(16) _Float16 sR1[4][2560];
    __shared__ __align__(16) _Float16 sR2[4][2048];
    __shared__ int   sTy[4][32];
    __shared__ float sTemb[96];

    const int lane = threadIdx.x & 63;
    const int l32 = threadIdx.x & 31;
    const int w = threadIdx.x >> 6;
    const int gbase = blockIdx.x * 128 + w * 32;

    for (int i = threadIdx.x; i < 96; i += 256) sTemb[i] = temb[i];
    __syncthreads();

    const int kb = (lane >> 4) * 8, nb = lane & 15;
    f16x8 bz[2], bt[2];
    #pragma unroll
    for (int t = 0; t < 2; t++)
        #pragma unroll
        for (int j = 0; j < 8; j++) {
            int k = kb + j;
            bz[t][j] = (k < 8) ? (_Float16)Wr1[k * FDIM + t * 16 + nb] : (_Float16)0.0f;
            bt[t][j] = (k >= 8 && k < 16) ? (_Float16)Wr1[(k - 8) * FDIM + t * 16 + nb] : (_Float16)0.0f;
        }
    f16x8 bf[4];
    #pragma unroll
    for (int t = 0; t < 4; t++)
        #pragma unroll
        for (int j = 0; j < 8; j++)
            bf[t][j] = (_Float16)Wr2[(kb + j) * 64 + t * 16 + nb];

    // ---- phase 0: lanes 0..31, one edge each; geometry kept in registers ----
    float rinv = 1.f, env = 0.f, denv = 0.f, rhx = 0.f, rhy = 0.f, rhz = 0.f;
    int srcI = 0, dstI = 0, key = -2 - l32;
    bool valid = false;
    if (lane < 32) {
        const int p = gbase + l32;
        valid = (p < E);
        int2 sd = valid ? order_sd[p] : make_int2(0, 0);
        srcI = sd.x; dstI = sd.y;
        if (valid) key = sd.y;
        float rx = (pos[sd.y * 3 + 0] - pos[sd.x * 3 + 0]) * NM2A_C;
        float ry = (pos[sd.y * 3 + 1] - pos[sd.x * 3 + 1]) * NM2A_C;
        float rz = (pos[sd.y * 3 + 2] - pos[sd.x * 3 + 2]) * NM2A_C;
        float r2 = rx * rx + ry * ry + rz * rz + 1e-12f;
        float r = sqrtf(r2);
        rinv = 1.0f / r;
        float x = r * (1.0f / RCUT_C);
        float x2 = x * x, x4 = x2 * x2, x5 = x4 * x, x6 = x4 * x2, x7 = x6 * x, x8 = x6 * x2;
        env = (x < 1.0f) ? (1.0f - 28.0f * x6 + 48.0f * x7 - 21.0f * x8) : 0.0f;
        denv = (x < 1.0f) ? (-168.0f * x5 + 336.0f * x6 - 168.0f * x7) * (1.0f / RCUT_C) : 0.0f;
        rhx = rx * rinv; rhy = ry * rinv; rhz = rz * rinv;

        float th = PI_F * x, s1, c1;
        __sincosf(th, &s1, &c1);
        float sp = 0.0f, sn = s1, cp = 1.0f, cn = c1;
        _Float16 av[16];
        #pragma unroll
        for (int n = 0; n < NBASIS; n++) {
            float basis = sn * rinv;
            float dbdr = (PI_F * (float)(n + 1) * (1.0f / RCUT_C)) * cn * rinv - basis * rinv;
            av[n] = (_Float16)basis;
            av[8 + n] = (_Float16)dbdr;
            float snx = 2.0f * c1 * sn - sp; sp = sn; sn = snx;
            float cnx = 2.0f * c1 * cn - cp; cp = cn; cn = cnx;
        }
        _Float16* dstA = &sR1[w][(l32 < 16 ? 0 : 640) + (l32 & 15) * QP];
        *(f16x8*)&dstA[0] = *(f16x8*)&av[0];
        *(f16x8*)&dstA[8] = *(f16x8*)&av[8];
        *(float4*)&dstA[16] = make_float4(0.f, 0.f, 0.f, 0.f);
        *(float4*)&dstA[24] = make_float4(0.f, 0.f, 0.f, 0.f);
        sTy[w][l32] = types[sd.x];
    }

    // ---- phase 1: MFMA basis layer (both tiles) -> z, tacc; silu/tf -> Q/T ----
    {
        const int me = lane & 15;
        f16x8 a1a = *(const f16x8*)&sR1[w][me * QP + kb];
        f16x8 a1b = *(const f16x8*)&sR1[w][640 + me * QP + kb];
        const f32x4 z4 = {0.f, 0.f, 0.f, 0.f};
        f32x4 Dz0a = __builtin_amdgcn_mfma_f32_16x16x32_f16(a1a, bz[0], z4, 0, 0, 0);
        f32x4 Dz1a = __builtin_amdgcn_mfma_f32_16x16x32_f16(a1a, bz[1], z4, 0, 0, 0);
        f32x4 Dt0a = __builtin_amdgcn_mfma_f32_16x16x32_f16(a1a, bt[0], z4, 0, 0, 0);
        f32x4 Dt1a = __builtin_amdgcn_mfma_f32_16x16x32_f16(a1a, bt[1], z4, 0, 0, 0);
        f32x4 Dz0b = __builtin_amdgcn_mfma_f32_16x16x32_f16(a1b, bz[0], z4, 0, 0, 0);
        f32x4 Dz1b = __builtin_amdgcn_mfma_f32_16x16x32_f16(a1b, bz[1], z4, 0, 0, 0);
        f32x4 Dt0b = __builtin_amdgcn_mfma_f32_16x16x32_f16(a1b, bt[0], z4, 0, 0, 0);
        f32x4 Dt1b = __builtin_amdgcn_mfma_f32_16x16x32_f16(a1b, bt[1], z4, 0, 0, 0);
        const int f0 = lane & 15, e0 = (lane >> 4) * 4;
        const float bb0 = br1[f0], bb1 = br1[16 + f0];
        #pragma unroll
        for (int t = 0; t < 2; t++) {
            f32x4 Dza = t ? Dz1a : Dz0a;
            f32x4 Dta = t ? Dt1a : Dt0a;
            f32x4 Dzb = t ? Dz1b : Dz0b;
            f32x4 Dtb = t ? Dt1b : Dt0b;
            float bb = t ? bb1 : bb0;
            #pragma unroll
            for (int r = 0; r < 4; r++) {
                float za = Dza[r] + bb;
                float sga = sigmoidf_(za);
                sR2[w][(e0 + r) * QP + t * 16 + f0] = (_Float16)(za * sga);
                sR1[w][1280 + (e0 + r) * QP + t * 16 + f0] =
                    (_Float16)((sga * (1.0f + za * (1.0f - sga))) * Dta[r]);
                float zb = Dzb[r] + bb;
                float sgb = sigmoidf_(zb);
                sR2[w][640 + (e0 + r) * QP + t * 16 + f0] = (_Float16)(zb * sgb);
                sR1[w][1920 + (e0 + r) * QP + t * 16 + f0] =
                    (_Float16)((sgb * (1.0f + zb * (1.0f - sgb))) * Dtb[r]);
            }
        }
    }

    // ---- phase 2: 16 MFMAs; fold hs; pack (x, x+32) channel pairs as f16x2 ----
    {
        const int me = lane & 15;
        f16x8 aqa = *(const f16x8*)&sR2[w][me * QP + kb];
        f16x8 ata = *(const f16x8*)&sR1[w][1280 + me * QP + kb];
        f16x8 aqb = *(const f16x8*)&sR2[w][640 + me * QP + kb];
        f16x8 atb = *(const f16x8*)&sR1[w][1920 + me * QP + kb];
        const int cb = lane & 15, e0 = (lane >> 4) * 4;
        float hsv[2][2][4];   // [tile][fpair][r]
        #pragma unroll
        for (int tl = 0; tl < 2; tl++)
            #pragma unroll
            for (int r = 0; r < 4; r++) {
                int ty = sTy[w][tl * 16 + e0 + r];
                hsv[tl][0][r] = sTemb[ty * 32 + cb];
                hsv[tl][1][r] = sTemb[ty * 32 + 16 + cb];
            }
        const f32x4 z4 = {0.f, 0.f, 0.f, 0.f};
        unsigned int* DqU = (unsigned int*)&sR1[w][0];
        unsigned int* DtU = (unsigned int*)&sR2[w][0];
        #pragma unroll
        for (int fp = 0; fp < 2; fp++) {
            f32x4 qa0 = __builtin_amdgcn_mfma_f32_16x16x32_f16(aqa, bf[fp],     z4, 0, 0, 0);
            f32x4 qa1 = __builtin_amdgcn_mfma_f32_16x16x32_f16(aqa, bf[fp + 2], z4, 0, 0, 0);
            f32x4 qb0 = __builtin_amdgcn_mfma_f32_16x16x32_f16(aqb, bf[fp],     z4, 0, 0, 0);
            f32x4 qb1 = __builtin_amdgcn_mfma_f32_16x16x32_f16(aqb, bf[fp + 2], z4, 0, 0, 0);
            f32x4 ta0 = __builtin_amdgcn_mfma_f32_16x16x32_f16(ata, bf[fp],     z4, 0, 0, 0);
            f32x4 ta1 = __builtin_amdgcn_mfma_f32_16x16x32_f16(ata, bf[fp + 2], z4, 0, 0, 0);
            f32x4 tb0 = __builtin_amdgcn_mfma_f32_16x16x32_f16(atb, bf[fp],     z4, 0, 0, 0);
            f32x4 tb1 = __builtin_amdgcn_mfma_f32_16x16x32_f16(atb, bf[fp + 2], z4, 0, 0, 0);
            unsigned int pqa[4], pqb[4], pta[4], ptb[4];
            #pragma unroll
            for (int r = 0; r < 4; r++) {
                float ha = hsv[0][fp][r], hb = hsv[1][fp][r];
                pqa[r] = pk2_(qa0[r] * ha, qa1[r] * ha);
                pqb[r] = pk2_(qb0[r] * hb, qb1[r] * hb);
                pta[r] = pk2_(ta0[r] * ha, ta1[r] * ha);
                ptb[r] = pk2_(tb0[r] * hb, tb1[r] * hb);
            }
            const int f = fp * 16 + cb;
            *(uint4*)&DqU[f * 16 + e0]       = make_uint4(pqa[0], pqa[1], pqa[2], pqa[3]);
            *(uint4*)&DqU[512 + f * 16 + e0] = make_uint4(pqb[0], pqb[1], pqb[2], pqb[3]);
            *(uint4*)&DtU[f * 16 + e0]       = make_uint4(pta[0], pta[1], pta[2], pta[3]);
            *(uint4*)&DtU[512 + f * 16 + e0] = make_uint4(ptb[0], ptb[1], ptb[2], ptb[3]);
        }
    }

    // ---- phase 3: transposed epilogue (lanes 0..31; lane = edge) ----
    if (lane < 32) {
        const unsigned int* DqU = (const unsigned int*)&sR1[w][0];
        const unsigned int* DtU = (const unsigned int*)&sR2[w][0];
        const int tb = (l32 >> 4) * 512;
        const int me = l32 & 15;
        const size_t gsb = (size_t)dstI * 32;
        const size_t gvb = (size_t)dstI * 96;
        float Aa = 0.f, Bb = 0.f, Cc = 0.f, Pp = 0.f;
        float Ap = 0.f, Bp = 0.f, Cp = 0.f, Qq = 0.f;
        #pragma unroll 8
        for (int f = 0; f < 32; f++) {
            unsigned int qp = DqU[tb + f * 16 + me];
            unsigned int tp = DtU[tb + f * 16 + me];
            float rw0 = lo16_(qp), rw1 = hi16_(qp);
            float u0 = lo16_(tp), u1 = hi16_(tp);
            float gm0 = g_s[gsb + f];
            float g1x = g_v[gvb + f * 3 + 0];
            float g1y = g_v[gvb + f * 3 + 1];
            float g1z = g_v[gvb + f * 3 + 2];
            Pp += rw0 * gm0; Qq += u0 * gm0;
            Aa += rw1 * g1x; Bb += rw1 * g1y; Cc += rw1 * g1z;
            Ap += u1 * g1x;  Bp += u1 * g1y;  Cp += u1 * g1z;
        }
        float Gx = env * Aa, Gy = env * Bb, Gz = env * Cc;
        float genv = Pp + rhx * Aa + rhy * Bb + rhz * Cc;
        float pc = env * (Qq + rhx * Ap + rhy * Bp + rhz * Cp) + genv * denv;
        float dotg = Gx * rhx + Gy * rhy + Gz * rhz;
        float cx = pc * rhx + (Gx - dotg * rhx) * rinv;
        float cy = pc * rhy + (Gy - dotg * rhy) * rinv;
        float cz = pc * rhz + (Gz - dotg * rhz) * rinv;

        const float SC = EV2KJ_C * NM2A_C;
        if (valid) {
            unsafeAtomicAdd(&forces[(size_t)srcI * 3 + 0], SC * cx);
            unsafeAtomicAdd(&forces[(size_t)srcI * 3 + 1], SC * cy);
            unsafeAtomicAdd(&forces[(size_t)srcI * 3 + 2], SC * cz);
        }
        // segmented inclusive scan over contiguous dst runs
        #pragma unroll
        for (int d = 1; d < 32; d <<= 1) {
            float ux = __shfl_up(cx, d, 32);
            float uy = __shfl_up(cy, d, 32);
            float uz = __shfl_up(cz, d, 32);
            int uk = __shfl_up(key, d, 32);
            if (l32 >= d && uk == key) { cx += ux; cy += uy; cz += uz; }
        }
        int nk = __shfl_down(key, 1, 32);
        bool leader = (l32 == 31) || (nk != key);
        if (valid && leader) {
            unsafeAtomicAdd(&forces[(size_t)dstI * 3 + 0], -SC * cx);
            unsafeAtomicAdd(&forces[(size_t)dstI * 3 + 1], -SC * cy);
            unsafeAtomicAdd(&forces[(size_t)dstI * 3 + 2], -SC * cz);
        }
    }
}

// ---------------- reductions & correction ----------------
__global__ __launch_bounds__(256) void reduce_energy(
    const float* __restrict__ e_partial, int n, float* __restrict__ out)
{
    __shared__ float red[256];
    float s = 0.0f;
    for (int i = threadIdx.x; i < n; i += 256) s += e_partial[i];
    red[threadIdx.x] = s;
    __syncthreads();
    for (int k = 128; k; k >>= 1) {
        if (threadIdx.x < k) red[threadIdx.x] += red[threadIdx.x + k];
        __syncthreads();
    }
    if (threadIdx.x == 0) out[0] = red[0] * EV2KJ_C;
}

__global__ __launch_bounds__(256) void reduce_net(
    const float* __restrict__ f, const float* __restrict__ masses,
    float* __restrict__ accum, int N)
{
    float nx = 0, ny = 0, nz = 0, ms = 0;
    for (int i = blockIdx.x * 256 + threadIdx.x; i < N; i += gridDim.x * 256) {
        nx += f[i * 3 + 0]; ny += f[i * 3 + 1]; nz += f[i * 3 + 2]; ms += masses[i];
    }
    #pragma unroll
    for (int m = 32; m; m >>= 1) {
        nx += __shfl_xor(nx, m, 64);
        ny += __shfl_xor(ny, m, 64);
        nz += __shfl_xor(nz, m, 64);
        ms += __shfl_xor(ms, m, 64);
    }
    __shared__ float red[4][4];
    int w = threadIdx.x >> 6;
    if ((threadIdx.x & 63) == 0) { red[w][0] = nx; red[w][1] = ny; red[w][2] = nz; red[w][3] = ms; }
    __syncthreads();
    if (threadIdx.x == 0) {
        float a0 = 0, a1 = 0, a2 = 0, a3 = 0;
        for (int i = 0; i < 4; i++) { a0 += red[i][0]; a1 += red[i][1]; a2 += red[i][2]; a3 += red[i][3]; }
        unsafeAtomicAdd(accum + 0, a0);
        unsafeAtomicAdd(accum + 1, a1);
        unsafeAtomicAdd(accum + 2, a2);
        unsafeAtomicAdd(accum + 3, a3);
    }
}

__global__ __launch_bounds__(256) void correct_forces(
    float* __restrict__ f, const float* __restrict__ masses,
    const float* __restrict__ accum, int N)
{
    int i = blockIdx.x * 256 + threadIdx.x;
    if (i < N) {
        float c = masses[i] / accum[3];
        f[i * 3 + 0] -= c * accum[0];
        f[i * 3 + 1] -= c * accum[1];
        f[i * 3 + 2] -= c * accum[2];
    }
}

extern "C" void kernel_launch(void* const* d_in, const int* in_sizes, int n_in,
                              void* d_out, int out_size, void* d_ws, size_t ws_size,
                              hipStream_t stream)
{
    (void)n_in; (void)ws_size;
    const float* pos    = (const float*)d_in[0];
    const float* masses = (const float*)d_in[1];
    const float* temb   = (const float*)d_in[2];
    const float* Wr1    = (const float*)d_in[3];
    const float* br1    = (const float*)d_in[4];
    const float* Wr2    = (const float*)d_in[5];
    const float* Wself  = (const float*)d_in[6];
    const float* Wo1    = (const float*)d_in[7];
    const float* bo1    = (const float*)d_in[8];
    const float* Wo2    = (const float*)d_in[9];
    const int* types    = (const int*)d_in[10];
    const int* eidx     = (const int*)d_in[11];
    const int N = in_sizes[1];
    const int E = in_sizes[11] / 2;

    float* out = (float*)d_out;
    float* forces = out + 1;

    float* ws = (float*)d_ws;
    float* s_acc = ws;                               // N*32
    float* v_acc = s_acc + (size_t)N * FDIM;         // N*96
    int nAtomBlocks = (N + 63) / 64;
    float* e_partial = v_acc + (size_t)N * 96;       // nAtomBlocks
    float* accum = e_partial + nAtomBlocks;          // 4
    int* counts = (int*)(accum + 4);                 // N
    int* cursor = counts + N;                        // N
    int2* order_sd = (int2*)(cursor + N);            // E int2
    int nScan = (N + SCH - 1) / SCH;
    int* bsum = (int*)(order_sd + E);                // nScan

    hipMemsetAsync(d_out, 0, (size_t)out_size * sizeof(float), stream);
    hipMemsetAsync(s_acc, 0, (size_t)N * 128 * sizeof(float), stream);
    hipMemsetAsync(counts, 0, (size_t)N * sizeof(int), stream);
    hipMemsetAsync(accum, 0, 4 * sizeof(float), stream);

    hist_dst<<<2048, 256, 0, stream>>>(eidx, counts, E);
    scan_partial<<<nScan, 256, 0, stream>>>(counts, bsum, N);
    scan_bsum<<<1, 64, 0, stream>>>(bsum, nScan);
    scan_write<<<nScan, 256, 0, stream>>>(counts, bsum, cursor, N);
    scatter_edges<<<2048, 256, 0, stream>>>(eidx, cursor, order_sd, E);

    int nEdgeBlocks = (E + 127) / 128;
    edge_fwd_mfma<<<nEdgeBlocks, 256, 0, stream>>>(pos, types, order_sd,
                                                   Wr1, br1, Wr2, temb,
                                                   s_acc, v_acc, E);
    atom_mlp<<<nAtomBlocks, 256, 0, stream>>>(types, temb, Wself, Wo1, bo1, Wo2,
                                              s_acc, v_acc, e_partial, N);
    reduce_energy<<<1, 256, 0, stream>>>(e_partial, nAtomBlocks, out);
    edge_bwd_mfma<<<nEdgeBlocks, 256, 0, stream>>>(pos, types, order_sd,
                                                   Wr1, br1, Wr2, temb,
                                                   s_acc, v_acc, forces, E);
    reduce_net<<<64, 256, 0, stream>>>(forces, masses, accum, N);
    correct_forces<<<(N + 255) / 256, 256, 0, stream>>>(forces, masses, accum, N);
}

// Round 15
// 559.103 us; speedup vs baseline: 1.2446x; 1.0703x over previous
//
#include <hip/hip_runtime.h>
#include <math.h>

#define FDIM 32
#define NBASIS 8
#define QP 40     // A-stage row pad (f16 units) -> 80B rows, 16B-aligned quads
#define SCH 4096  // scan chunk per block (256 thr x 16)

constexpr float RCUT_C = 20.0f;
constexpr float PI_F = 3.14159265358979323846f;
constexpr float EV2KJ_C = 96.4853f;
constexpr float NM2A_C = 10.0f;

typedef _Float16 f16x8 __attribute__((ext_vector_type(8)));
typedef _Float16 f16x4 __attribute__((ext_vector_type(4)));
typedef float f32x4 __attribute__((ext_vector_type(4)));

__device__ __forceinline__ float sigmoidf_(float z) { return 1.0f / (1.0f + __expf(-z)); }

__device__ __forceinline__ unsigned int pk2_(float a, float b) {
    unsigned short lo = __builtin_bit_cast(unsigned short, (_Float16)a);
    unsigned short hi = __builtin_bit_cast(unsigned short, (_Float16)b);
    return (unsigned int)lo | ((unsigned int)hi << 16);
}
__device__ __forceinline__ float lo16_(unsigned int v) {
    return (float)__builtin_bit_cast(_Float16, (unsigned short)(v & 0xffffu));
}
__device__ __forceinline__ float hi16_(unsigned int v) {
    return (float)__builtin_bit_cast(_Float16, (unsigned short)(v >> 16));
}

// ---------------- CSR build: histogram, 3-kernel scan, scatter ----------------
__global__ __launch_bounds__(256) void hist_dst(
    const int* __restrict__ eidx, int* __restrict__ counts, int E)
{
    for (int e = blockIdx.x * 256 + threadIdx.x; e < E; e += gridDim.x * 256)
        atomicAdd(&counts[eidx[E + e]], 1);
}

__global__ __launch_bounds__(256) void scan_partial(
    const int* __restrict__ counts, int* __restrict__ bsum, int N)
{
    __shared__ int red[256];
    const int t = threadIdx.x;
    const int st = blockIdx.x * SCH + t * 16;
    int s = 0;
    #pragma unroll
    for (int i = 0; i < 16; i++) { int idx = st + i; if (idx < N) s += counts[idx]; }
    red[t] = s;
    __syncthreads();
    for (int k = 128; k; k >>= 1) {
        if (t < k) red[t] += red[t + k];
        __syncthreads();
    }
    if (t == 0) bsum[blockIdx.x] = red[0];
}

__global__ __launch_bounds__(64) void scan_bsum(int* __restrict__ bsum, int nb)
{
    if (threadIdx.x == 0) {
        int run = 0;
        for (int i = 0; i < nb; i++) { int v = bsum[i]; bsum[i] = run; run += v; }
    }
}

__global__ __launch_bounds__(256) void scan_write(
    const int* __restrict__ counts, const int* __restrict__ bsum,
    int* __restrict__ cursor, int N)
{
    __shared__ int lds[256];
    const int t = threadIdx.x;
    const int st = blockIdx.x * SCH + t * 16;
    int vals[16];
    int s = 0;
    #pragma unroll
    for (int i = 0; i < 16; i++) {
        int idx = st + i;
        int v = (idx < N) ? counts[idx] : 0;
        vals[i] = v; s += v;
    }
    lds[t] = s;
    __syncthreads();
    for (int off = 1; off < 256; off <<= 1) {
        int v = (t >= off) ? lds[t - off] : 0;
        __syncthreads();
        lds[t] += v;
        __syncthreads();
    }
    int run = bsum[blockIdx.x] + lds[t] - s;   // exclusive prefix
    #pragma unroll
    for (int i = 0; i < 16; i++) {
        int idx = st + i;
        if (idx < N) cursor[idx] = run;
        run += vals[i];
    }
}

__global__ __launch_bounds__(256) void scatter_edges(
    const int* __restrict__ eidx, int* __restrict__ cursor,
    int2* __restrict__ order_sd, int E)
{
    for (int e = blockIdx.x * 256 + threadIdx.x; e < E; e += gridDim.x * 256) {
        int dst = eidx[E + e];
        int p = atomicAdd(&cursor[dst], 1);
        order_sd[p] = make_int2(eidx[e], dst);
    }
}

// ---------------- edge forward: hs*env folded into packed D ----------------
// LDS per wave (f16 units): sR[2560] = A_a[0,640) A_b[640,1280) Q_a[1280,1920) Q_b[1920,2560)
// After phase-2 loads, D (uint[1024], [edge*32 + chpair]) overlays sR[0,2048).
__global__ __launch_bounds__(256) void edge_fwd_mfma(
    const float* __restrict__ pos, const int* __restrict__ types,
    const int2* __restrict__ order_sd,
    const float* __restrict__ Wr1, const float* __restrict__ br1,
    const float* __restrict__ Wr2, const float* __restrict__ temb,
    float* __restrict__ s_acc, float* __restrict__ v_acc, int E)
{
    __shared__ __align__(16) _Float16 sR[4][2560];
    __shared__ float sSt[4][32][4];         // env, rhx, rhy, rhz
    __shared__ int sTy[4][32];
    __shared__ float sTemb[96];

    const int lane = threadIdx.x & 63;
    const int l32 = threadIdx.x & 31;
    const int hw = (threadIdx.x >> 5) & 1;
    const int w = threadIdx.x >> 6;
    const int gbase = blockIdx.x * 128 + w * 32;

    for (int i = threadIdx.x; i < 96; i += 256) sTemb[i] = temb[i];
    __syncthreads();

    const int kb = (lane >> 4) * 8, nb = lane & 15;
    f16x8 bz[2];
    #pragma unroll
    for (int t = 0; t < 2; t++)
        #pragma unroll
        for (int j = 0; j < 8; j++) {
            int k = kb + j;
            bz[t][j] = (k < 8) ? (_Float16)Wr1[k * FDIM + t * 16 + nb] : (_Float16)0.0f;
        }
    f16x8 bf[4];
    #pragma unroll
    for (int t = 0; t < 4; t++)
        #pragma unroll
        for (int j = 0; j < 8; j++)
            bf[t][j] = (_Float16)Wr2[(kb + j) * 64 + t * 16 + nb];

    // ---- phase 0: lane-parallel geometry + basis (lanes 0..31) ----
    if (lane < 32) {
        const int ed = l32;
        const int p = gbase + ed;
        int2 sd = (p < E) ? order_sd[p] : make_int2(0, 0);
        float rx = (pos[sd.y * 3 + 0] - pos[sd.x * 3 + 0]) * NM2A_C;
        float ry = (pos[sd.y * 3 + 1] - pos[sd.x * 3 + 1]) * NM2A_C;
        float rz = (pos[sd.y * 3 + 2] - pos[sd.x * 3 + 2]) * NM2A_C;
        float r2 = rx * rx + ry * ry + rz * rz + 1e-12f;
        float r = sqrtf(r2);
        float rinv = 1.0f / r;
        float x = r * (1.0f / RCUT_C);
        float x2 = x * x, x4 = x2 * x2, x6 = x4 * x2, x7 = x6 * x, x8 = x6 * x2;
        float env = (x < 1.0f) ? (1.0f - 28.0f * x6 + 48.0f * x7 - 21.0f * x8) : 0.0f;

        float th = PI_F * x, s1, c1;
        __sincosf(th, &s1, &c1);
        float sp = 0.0f, sn = s1;
        _Float16 av[8];
        #pragma unroll
        for (int n = 0; n < NBASIS; n++) {
            av[n] = (_Float16)(sn * rinv);
            float snx = 2.0f * c1 * sn - sp; sp = sn; sn = snx;
        }
        _Float16* dstA = &sR[w][(ed < 16 ? 0 : 640) + (ed & 15) * QP];
        *(f16x8*)&dstA[0] = *(f16x8*)&av[0];
        *(float4*)&dstA[8]  = make_float4(0.f, 0.f, 0.f, 0.f);
        *(float4*)&dstA[16] = make_float4(0.f, 0.f, 0.f, 0.f);
        *(float4*)&dstA[24] = make_float4(0.f, 0.f, 0.f, 0.f);
        sSt[w][ed][0] = env;
        sSt[w][ed][1] = rx * rinv;
        sSt[w][ed][2] = ry * rinv;
        sSt[w][ed][3] = rz * rinv;
        sTy[w][ed] = types[sd.x];
    }

    // ---- phase 1: MFMA basis layer -> z, silu -> Q (both tiles) ----
    {
        const int me = lane & 15;
        f16x8 a1a = *(const f16x8*)&sR[w][me * QP + kb];
        f16x8 a1b = *(const f16x8*)&sR[w][640 + me * QP + kb];
        const f32x4 z4 = {0.f, 0.f, 0.f, 0.f};
        f32x4 Dz0a = __builtin_amdgcn_mfma_f32_16x16x32_f16(a1a, bz[0], z4, 0, 0, 0);
        f32x4 Dz1a = __builtin_amdgcn_mfma_f32_16x16x32_f16(a1a, bz[1], z4, 0, 0, 0);
        f32x4 Dz0b = __builtin_amdgcn_mfma_f32_16x16x32_f16(a1b, bz[0], z4, 0, 0, 0);
        f32x4 Dz1b = __builtin_amdgcn_mfma_f32_16x16x32_f16(a1b, bz[1], z4, 0, 0, 0);
        const int f0 = lane & 15, e0 = (lane >> 4) * 4;
        const float bb0 = br1[f0], bb1 = br1[16 + f0];
        #pragma unroll
        for (int t = 0; t < 2; t++) {
            f32x4 Dza = t ? Dz1a : Dz0a;
            f32x4 Dzb = t ? Dz1b : Dz0b;
            float bb = t ? bb1 : bb0;
            #pragma unroll
            for (int r = 0; r < 4; r++) {
                float za = Dza[r] + bb;
                float zb = Dzb[r] + bb;
                sR[w][1280 + (e0 + r) * QP + t * 16 + f0] = (_Float16)(za * sigmoidf_(za));
                sR[w][1920 + (e0 + r) * QP + t * 16 + f0] = (_Float16)(zb * sigmoidf_(zb));
            }
        }
    }

    // ---- phase 2: MFMA W2; fold hs*env; pack (ch, ch+32) pairs; D[edge*32+ch] ----
    {
        const int me = lane & 15;
        f16x8 aqa = *(const f16x8*)&sR[w][1280 + me * QP + kb];
        f16x8 aqb = *(const f16x8*)&sR[w][1920 + me * QP + kb];
        const int cb = lane & 15, e0 = (lane >> 4) * 4;
        float hev[2][2][4];   // [tile][fpair][r] = hs(ch)*env
        #pragma unroll
        for (int tl = 0; tl < 2; tl++)
            #pragma unroll
            for (int fp = 0; fp < 2; fp++)
                #pragma unroll
                for (int r = 0; r < 4; r++) {
                    int ed = tl * 16 + e0 + r;
                    hev[tl][fp][r] = sTemb[sTy[w][ed] * 32 + fp * 16 + cb] * sSt[w][ed][0];
                }
        const f32x4 z4 = {0.f, 0.f, 0.f, 0.f};
        unsigned int* DU = (unsigned int*)&sR[w][0];
        #pragma unroll
        for (int fp = 0; fp < 2; fp++) {
            f32x4 a0 = __builtin_amdgcn_mfma_f32_16x16x32_f16(aqa, bf[fp],     z4, 0, 0, 0);
            f32x4 a1 = __builtin_amdgcn_mfma_f32_16x16x32_f16(aqa, bf[fp + 2], z4, 0, 0, 0);
            f32x4 b0 = __builtin_amdgcn_mfma_f32_16x16x32_f16(aqb, bf[fp],     z4, 0, 0, 0);
            f32x4 b1 = __builtin_amdgcn_mfma_f32_16x16x32_f16(aqb, bf[fp + 2], z4, 0, 0, 0);
            #pragma unroll
            for (int r = 0; r < 4; r++) {
                float ha = hev[0][fp][r], hb = hev[1][fp][r];
                DU[(e0 + r) * 32 + fp * 16 + cb]        = pk2_(a0[r] * ha, a1[r] * ha);
                DU[(16 + e0 + r) * 32 + fp * 16 + cb]   = pk2_(b0[r] * hb, b1[r] * hb);
            }
        }
    }

    // ---- phase 3: epilogue, run-merge carried across both tiles ----
    const unsigned int* DU = (const unsigned int*)&sR[w][0];
    int runKey = -1;
    float sAcc = 0.f, vXA = 0.f, vYA = 0.f, vZA = 0.f;
    #pragma unroll
    for (int t = 0; t < 2; t++) {
        #pragma unroll
        for (int i = 0; i < 8; i++) {
            const int m = t * 16 + hw * 8 + i;
            const int p = gbase + m;
            if (p >= E) break;
            int2 sd = order_sd[p];
            if (sd.y != runKey) {
                if (runKey >= 0) {
                    unsafeAtomicAdd(&s_acc[(size_t)runKey * 32 + l32], sAcc);
                    unsafeAtomicAdd(&v_acc[(size_t)runKey * 96 + 0 * 32 + l32], vXA);
                    unsafeAtomicAdd(&v_acc[(size_t)runKey * 96 + 1 * 32 + l32], vYA);
                    unsafeAtomicAdd(&v_acc[(size_t)runKey * 96 + 2 * 32 + l32], vZA);
                }
                runKey = sd.y;
                sAcc = vXA = vYA = vZA = 0.f;
            }
            unsigned int qp = DU[m * 32 + l32];
            float s0 = lo16_(qp);       // hs*env*rw0
            float h1 = hi16_(qp);       // hs*env*rw1
            sAcc += s0;
            vXA += h1 * sSt[w][m][1];
            vYA += h1 * sSt[w][m][2];
            vZA += h1 * sSt[w][m][3];
        }
    }
    if (runKey >= 0) {
        unsafeAtomicAdd(&s_acc[(size_t)runKey * 32 + l32], sAcc);
        unsafeAtomicAdd(&v_acc[(size_t)runKey * 96 + 0 * 32 + l32], vXA);
        unsafeAtomicAdd(&v_acc[(size_t)runKey * 96 + 1 * 32 + l32], vYA);
        unsafeAtomicAdd(&v_acc[(size_t)runKey * 96 + 2 * 32 + l32], vZA);
    }
}

// -------- atom MLP: 64 atoms/block; writes packed g_all[a*128 + f*4] = {gs,gvx,gvy,gvz} --------
__global__ __launch_bounds__(256) void atom_mlp(
    const int* __restrict__ types, const float* __restrict__ temb,
    const float* __restrict__ Wself, const float* __restrict__ Wo1,
    const float* __restrict__ bo1, const float* __restrict__ Wo2,
    const float* __restrict__ s_acc, const float* __restrict__ v_acc,
    float* __restrict__ g_all, float* __restrict__ e_partial, int N)
{
    __shared__ float sWs[FDIM * FDIM], sWsT[FDIM * FDIM];
    __shared__ float sWo1[2 * FDIM * FDIM], sWo1T[2 * FDIM * FDIM];
    __shared__ float sb[FDIM], sW2o[FDIM], sTE[96];
    __shared__ float gred[8];
    for (int i = threadIdx.x; i < FDIM * FDIM; i += 256) {
        sWs[i] = Wself[i];
        sWsT[i] = Wself[(i & 31) * FDIM + (i >> 5)];
    }
    for (int i = threadIdx.x; i < 2 * FDIM * FDIM; i += 256) {
        sWo1[i] = Wo1[i];
        sWo1T[i] = Wo1[(i & 63) * FDIM + (i >> 6)];
    }
    for (int i = threadIdx.x; i < FDIM; i += 256) { sb[i] = bo1[i]; sW2o[i] = Wo2[i]; }
    for (int i = threadIdx.x; i < 96; i += 256) sTE[i] = temb[i];
    __syncthreads();

    const int lane = threadIdx.x & 31;
    const int g = threadIdx.x >> 5;
    float eAcc = 0.0f;

    for (int it = 0; it < 8; it++) {
        int a = blockIdx.x * 64 + it * 8 + g;
        const bool valid = (a < N);
        if (!valid) a = 0;

        float sv = s_acc[(size_t)a * FDIM + lane];
        float vx = v_acc[(size_t)a * 96 + 0 * 32 + lane];
        float vy = v_acc[(size_t)a * 96 + 1 * 32 + lane];
        float vz = v_acc[(size_t)a * 96 + 2 * 32 + lane];
        float h = sTE[types[a] * FDIM + lane];
        float vn = sqrtf(vx * vx + vy * vy + vz * vz + 1e-12f);

        float row = h;
        #pragma unroll
        for (int f = 0; f < FDIM; f++) {
            float t = __shfl(sv, f, 32);
            row += t * sWs[f * FDIM + lane];
        }
        float u = sb[lane];
        #pragma unroll
        for (int j = 0; j < FDIM; j++) {
            float rv = __shfl(row, j, 32);
            float vv = __shfl(vn, j, 32);
            u += rv * sWo1[j * FDIM + lane] + vv * sWo1[(j + FDIM) * FDIM + lane];
        }
        float sg = sigmoidf_(u);
        float au = u * sg;
        float pa = valid ? au * sW2o[lane] : 0.0f;
        #pragma unroll
        for (int m = 16; m; m >>= 1) pa += __shfl_xor(pa, m, 32);
        if (lane == 0) eAcc += pa;

        float gu = sW2o[lane] * (sg * (1.0f + u * (1.0f - sg)));
        float gfr = 0.0f, gfv = 0.0f;
        #pragma unroll
        for (int k = 0; k < FDIM; k++) {
            float gv_ = __shfl(gu, k, 32);
            gfr += gv_ * sWo1T[k * 64 + lane];
            gfv += gv_ * sWo1T[k * 64 + 32 + lane];
        }
        float gs = 0.0f;
        #pragma unroll
        for (int k = 0; k < FDIM; k++) {
            float gr = __shfl(gfr, k, 32);
            gs += gr * sWsT[k * FDIM + lane];
        }
        if (valid) {
            float sc = gfv / vn;
            *(float4*)&g_all[(size_t)a * 128 + lane * 4] =
                make_float4(gs, sc * vx, sc * vy, sc * vz);
        }
    }
    if (lane == 0) gred[g] = eAcc;
    __syncthreads();
    if (threadIdx.x == 0) {
        float t = 0.0f;
        #pragma unroll
        for (int i = 0; i < 8; i++) t += gred[i];
        e_partial[blockIdx.x] = t;
    }
}

// ---------------- edge backward: transposed epilogue + packed float4 gradient loads ----------------
__global__ __launch_bounds__(256) void edge_bwd_mfma(
    const float* __restrict__ pos, const int* __restrict__ types,
    const int2* __restrict__ order_sd,
    const float* __restrict__ Wr1, const float* __restrict__ br1,
    const float* __restrict__ Wr2, const float* __restrict__ temb,
    const float* __restrict__ g_all,
    float* __restrict__ forces, int E)
{
    __shared__ __align__(16) _Float16 sR1[4][2560];
    __shared__ __align__(16) _Float16 sR2[4][2048];
    __shared__ int   sTy[4][32];
    __shared__ float sTemb[96];

    const int lane = threadIdx.x & 63;
    const int l32 = threadIdx.x & 31;
    const int w = threadIdx.x >> 6;
    const int gbase = blockIdx.x * 128 + w * 32;

    for (int i = threadIdx.x; i < 96; i += 256) sTemb[i] = temb[i];
    __syncthreads();

    const int kb = (lane >> 4) * 8, nb = lane & 15;
    f16x8 bz[2], bt[2];
    #pragma unroll
    for (int t = 0; t < 2; t++)
        #pragma unroll
        for (int j = 0; j < 8; j++) {
            int k = kb + j;
            bz[t][j] = (k < 8) ? (_Float16)Wr1[k * FDIM + t * 16 + nb] : (_Float16)0.0f;
            bt[t][j] = (k >= 8 && k < 16) ? (_Float16)Wr1[(k - 8) * FDIM + t * 16 + nb] : (_Float16)0.0f;
        }
    f16x8 bf[4];
    #pragma unroll
    for (int t = 0; t < 4; t++)
        #pragma unroll
        for (int j = 0; j < 8; j++)
            bf[t][j] = (_Float16)Wr2[(kb + j) * 64 + t * 16 + nb];

    // ---- phase 0: lanes 0..31, one edge each; geometry kept in registers ----
    float rinv = 1.f, env = 0.f, denv = 0.f, rhx = 0.f, rhy = 0.f, rhz = 0.f;
    int srcI = 0, dstI = 0, key = -2 - l32;
    bool valid = false;
    if (lane < 32) {
        const int p = gbase + l32;
        valid = (p < E);
        int2 sd = valid ? order_sd[p] : make_int2(0, 0);
        srcI = sd.x; dstI = sd.y;
        if (valid) key = sd.y;
        float rx = (pos[sd.y * 3 + 0] - pos[sd.x * 3 + 0]) * NM2A_C;
        float ry = (pos[sd.y * 3 + 1] - pos[sd.x * 3 + 1]) * NM2A_C;
        float rz = (pos[sd.y * 3 + 2] - pos[sd.x * 3 + 2]) * NM2A_C;
        float r2 = rx * rx + ry * ry + rz * rz + 1e-12f;
        float r = sqrtf(r2);
        rinv = 1.0f / r;
        float x = r * (1.0f / RCUT_C);
        float x2 = x * x, x4 = x2 * x2, x5 = x4 * x, x6 = x4 * x2, x7 = x6 * x, x8 = x6 * x2;
        env = (x < 1.0f) ? (1.0f - 28.0f * x6 + 48.0f * x7 - 21.0f * x8) : 0.0f;
        denv = (x < 1.0f) ? (-168.0f * x5 + 336.0f * x6 - 168.0f * x7) * (1.0f / RCUT_C) : 0.0f;
        rhx = rx * rinv; rhy = ry * rinv; rhz = rz * rinv;

        float th = PI_F * x, s1, c1;
        __sincosf(th, &s1, &c1);
        float sp = 0.0f, sn = s1, cp = 1.0f, cn = c1;
        _Float16 av[16];
        #pragma unroll
        for (int n = 0; n < NBASIS; n++) {
            float basis = sn * rinv;
            float dbdr = (PI_F * (float)(n + 1) * (1.0f / RCUT_C)) * cn * rinv - basis * rinv;
            av[n] = (_Float16)basis;
            av[8 + n] = (_Float16)dbdr;
            float snx = 2.0f * c1 * sn - sp; sp = sn; sn = snx;
            float cnx = 2.0f * c1 * cn - cp; cp = cn; cn = cnx;
        }
        _Float16* dstA = &sR1[w][(l32 < 16 ? 0 : 640) + (l32 & 15) * QP];
        *(f16x8*)&dstA[0] = *(f16x8*)&av[0];
        *(f16x8*)&dstA[8] = *(f16x8*)&av[8];
        *(float4*)&dstA[16] = make_float4(0.f, 0.f, 0.f, 0.f);
        *(float4*)&dstA[24] = make_float4(0.f, 0.f, 0.f, 0.f);
        sTy[w][l32] = types[sd.x];
    }

    // ---- phase 1: MFMA basis layer (both tiles) -> z, tacc; silu/tf -> Q/T ----
    {
        const int me = lane & 15;
        f16x8 a1a = *(const f16x8*)&sR1[w][me * QP + kb];
        f16x8 a1b = *(const f16x8*)&sR1[w][640 + me * QP + kb];
        const f32x4 z4 = {0.f, 0.f, 0.f, 0.f};
        f32x4 Dz0a = __builtin_amdgcn_mfma_f32_16x16x32_f16(a1a, bz[0], z4, 0, 0, 0);
        f32x4 Dz1a = __builtin_amdgcn_mfma_f32_16x16x32_f16(a1a, bz[1], z4, 0, 0, 0);
        f32x4 Dt0a = __builtin_amdgcn_mfma_f32_16x16x32_f16(a1a, bt[0], z4, 0, 0, 0);
        f32x4 Dt1a = __builtin_amdgcn_mfma_f32_16x16x32_f16(a1a, bt[1], z4, 0, 0, 0);
        f32x4 Dz0b = __builtin_amdgcn_mfma_f32_16x16x32_f16(a1b, bz[0], z4, 0, 0, 0);
        f32x4 Dz1b = __builtin_amdgcn_mfma_f32_16x16x32_f16(a1b, bz[1], z4, 0, 0, 0);
        f32x4 Dt0b = __builtin_amdgcn_mfma_f32_16x16x32_f16(a1b, bt[0], z4, 0, 0, 0);
        f32x4 Dt1b = __builtin_amdgcn_mfma_f32_16x16x32_f16(a1b, bt[1], z4, 0, 0, 0);
        const int f0 = lane & 15, e0 = (lane >> 4) * 4;
        const float bb0 = br1[f0], bb1 = br1[16 + f0];
        #pragma unroll
        for (int t = 0; t < 2; t++) {
            f32x4 Dza = t ? Dz1a : Dz0a;
            f32x4 Dta = t ? Dt1a : Dt0a;
            f32x4 Dzb = t ? Dz1b : Dz0b;
            f32x4 Dtb = t ? Dt1b : Dt0b;
            float bb = t ? bb1 : bb0;
            #pragma unroll
            for (int r = 0; r < 4; r++) {
                float za = Dza[r] + bb;
                float sga = sigmoidf_(za);
                sR2[w][(e0 + r) * QP + t * 16 + f0] = (_Float16)(za * sga);
                sR1[w][1280 + (e0 + r) * QP + t * 16 + f0] =
                    (_Float16)((sga * (1.0f + za * (1.0f - sga))) * Dta[r]);
                float zb = Dzb[r] + bb;
                float sgb = sigmoidf_(zb);
                sR2[w][640 + (e0 + r) * QP + t * 16 + f0] = (_Float16)(zb * sgb);
                sR1[w][1920 + (e0 + r) * QP + t * 16 + f0] =
                    (_Float16)((sgb * (1.0f + zb * (1.0f - sgb))) * Dtb[r]);
            }
        }
    }

    // ---- phase 2: 16 MFMAs; fold hs; pack (x, x+32) channel pairs as f16x2 ----
    {
        const int me = lane & 15;
        f16x8 aqa = *(const f16x8*)&sR2[w][me * QP + kb];
        f16x8 ata = *(const f16x8*)&sR1[w][1280 + me * QP + kb];
        f16x8 aqb = *(const f16x8*)&sR2[w][640 + me * QP + kb];
        f16x8 atb = *(const f16x8*)&sR1[w][1920 + me * QP + kb];
        const int cb = lane & 15, e0 = (lane >> 4) * 4;
        float hsv[2][2][4];   // [tile][fpair][r]
        #pragma unroll
        for (int tl = 0; tl < 2; tl++)
            #pragma unroll
            for (int r = 0; r < 4; r++) {
                int ty = sTy[w][tl * 16 + e0 + r];
                hsv[tl][0][r] = sTemb[ty * 32 + cb];
                hsv[tl][1][r] = sTemb[ty * 32 + 16 + cb];
            }
        const f32x4 z4 = {0.f, 0.f, 0.f, 0.f};
        unsigned int* DqU = (unsigned int*)&sR1[w][0];
        unsigned int* DtU = (unsigned int*)&sR2[w][0];
        #pragma unroll
        for (int fp = 0; fp < 2; fp++) {
            f32x4 qa0 = __builtin_amdgcn_mfma_f32_16x16x32_f16(aqa, bf[fp],     z4, 0, 0, 0);
            f32x4 qa1 = __builtin_amdgcn_mfma_f32_16x16x32_f16(aqa, bf[fp + 2], z4, 0, 0, 0);
            f32x4 qb0 = __builtin_amdgcn_mfma_f32_16x16x32_f16(aqb, bf[fp],     z4, 0, 0, 0);
            f32x4 qb1 = __builtin_amdgcn_mfma_f32_16x16x32_f16(aqb, bf[fp + 2], z4, 0, 0, 0);
            f32x4 ta0 = __builtin_amdgcn_mfma_f32_16x16x32_f16(ata, bf[fp],     z4, 0, 0, 0);
            f32x4 ta1 = __builtin_amdgcn_mfma_f32_16x16x32_f16(ata, bf[fp + 2], z4, 0, 0, 0);
            f32x4 tb0 = __builtin_amdgcn_mfma_f32_16x16x32_f16(atb, bf[fp],     z4, 0, 0, 0);
            f32x4 tb1 = __builtin_amdgcn_mfma_f32_16x16x32_f16(atb, bf[fp + 2], z4, 0, 0, 0);
            unsigned int pqa[4], pqb[4], pta[4], ptb[4];
            #pragma unroll
            for (int r = 0; r < 4; r++) {
                float ha = hsv[0][fp][r], hb = hsv[1][fp][r];
                pqa[r] = pk2_(qa0[r] * ha, qa1[r] * ha);
                pqb[r] = pk2_(qb0[r] * hb, qb1[r] * hb);
                pta[r] = pk2_(ta0[r] * ha, ta1[r] * ha);
                ptb[r] = pk2_(tb0[r] * hb, tb1[r] * hb);
            }
            const int f = fp * 16 + cb;
            *(uint4*)&DqU[f * 16 + e0]       = make_uint4(pqa[0], pqa[1], pqa[2], pqa[3]);
            *(uint4*)&DqU[512 + f * 16 + e0] = make_uint4(pqb[0], pqb[1], pqb[2], pqb[3]);
            *(uint4*)&DtU[f * 16 + e0]       = make_uint4(pta[0], pta[1], pta[2], pta[3]);
            *(uint4*)&DtU[512 + f * 16 + e0] = make_uint4(ptb[0], ptb[1], ptb[2], ptb[3]);
        }
    }

    // ---- phase 3: transposed epilogue (lanes 0..31; lane = edge) ----
    if (lane < 32) {
        const unsigned int* DqU = (const unsigned int*)&sR1[w][0];
        const unsigned int* DtU = (const unsigned int*)&sR2[w][0];
        const int tb = (l32 >> 4) * 512;
        const int me = l32 & 15;
        const float* gb = g_all + (size_t)dstI * 128;
        float Aa = 0.f, Bb = 0.f, Cc = 0.f, Pp = 0.f;
        float Ap = 0.f, Bp = 0.f, Cp = 0.f, Qq = 0.f;
        #pragma unroll 8
        for (int f = 0; f < 32; f++) {
            unsigned int qp = DqU[tb + f * 16 + me];
            unsigned int tp = DtU[tb + f * 16 + me];
            float rw0 = lo16_(qp), rw1 = hi16_(qp);
            float u0 = lo16_(tp), u1 = hi16_(tp);
            float4 g4 = *(const float4*)(gb + f * 4);
            Pp += rw0 * g4.x; Qq += u0 * g4.x;
            Aa += rw1 * g4.y; Bb += rw1 * g4.z; Cc += rw1 * g4.w;
            Ap += u1 * g4.y;  Bp += u1 * g4.z;  Cp += u1 * g4.w;
        }
        float Gx = env * Aa, Gy = env * Bb, Gz = env * Cc;
        float genv = Pp + rhx * Aa + rhy * Bb + rhz * Cc;
        float pc = env * (Qq + rhx * Ap + rhy * Bp + rhz * Cp) + genv * denv;
        float dotg = Gx * rhx + Gy * rhy + Gz * rhz;
        float cx = pc * rhx + (Gx - dotg * rhx) * rinv;
        float cy = pc * rhy + (Gy - dotg * rhy) * rinv;
        float cz = pc * rhz + (Gz - dotg * rhz) * rinv;

        const float SC = EV2KJ_C * NM2A_C;
        if (valid) {
            unsafeAtomicAdd(&forces[(size_t)srcI * 3 + 0], SC * cx);
            unsafeAtomicAdd(&forces[(size_t)srcI * 3 + 1], SC * cy);
            unsafeAtomicAdd(&forces[(size_t)srcI * 3 + 2], SC * cz);
        }
        // segmented inclusive scan over contiguous dst runs
        #pragma unroll
        for (int d = 1; d < 32; d <<= 1) {
            float ux = __shfl_up(cx, d, 32);
            float uy = __shfl_up(cy, d, 32);
            float uz = __shfl_up(cz, d, 32);
            int uk = __shfl_up(key, d, 32);
            if (l32 >= d && uk == key) { cx += ux; cy += uy; cz += uz; }
        }
        int nk = __shfl_down(key, 1, 32);
        bool leader = (l32 == 31) || (nk != key);
        if (valid && leader) {
            unsafeAtomicAdd(&forces[(size_t)dstI * 3 + 0], -SC * cx);
            unsafeAtomicAdd(&forces[(size_t)dstI * 3 + 1], -SC * cy);
            unsafeAtomicAdd(&forces[(size_t)dstI * 3 + 2], -SC * cz);
        }
    }
}

// ---------------- reductions & correction ----------------
__global__ __launch_bounds__(256) void reduce_energy(
    const float* __restrict__ e_partial, int n, float* __restrict__ out)
{
    __shared__ float red[256];
    float s = 0.0f;
    for (int i = threadIdx.x; i < n; i += 256) s += e_partial[i];
    red[threadIdx.x] = s;
    __syncthreads();
    for (int k = 128; k; k >>= 1) {
        if (threadIdx.x < k) red[threadIdx.x] += red[threadIdx.x + k];
        __syncthreads();
    }
    if (threadIdx.x == 0) out[0] = red[0] * EV2KJ_C;
}

__global__ __launch_bounds__(256) void reduce_net(
    const float* __restrict__ f, const float* __restrict__ masses,
    float* __restrict__ accum, int N)
{
    float nx = 0, ny = 0, nz = 0, ms = 0;
    for (int i = blockIdx.x * 256 + threadIdx.x; i < N; i += gridDim.x * 256) {
        nx += f[i * 3 + 0]; ny += f[i * 3 + 1]; nz += f[i * 3 + 2]; ms += masses[i];
    }
    #pragma unroll
    for (int m = 32; m; m >>= 1) {
        nx += __shfl_xor(nx, m, 64);
        ny += __shfl_xor(ny, m, 64);
        nz += __shfl_xor(nz, m, 64);
        ms += __shfl_xor(ms, m, 64);
    }
    __shared__ float red[4][4];
    int w = threadIdx.x >> 6;
    if ((threadIdx.x & 63) == 0) { red[w][0] = nx; red[w][1] = ny; red[w][2] = nz; red[w][3] = ms; }
    __syncthreads();
    if (threadIdx.x == 0) {
        float a0 = 0, a1 = 0, a2 = 0, a3 = 0;
        for (int i = 0; i < 4; i++) { a0 += red[i][0]; a1 += red[i][1]; a2 += red[i][2]; a3 += red[i][3]; }
        unsafeAtomicAdd(accum + 0, a0);
        unsafeAtomicAdd(accum + 1, a1);
        unsafeAtomicAdd(accum + 2, a2);
        unsafeAtomicAdd(accum + 3, a3);
    }
}

__global__ __launch_bounds__(256) void correct_forces(
    float* __restrict__ f, const float* __restrict__ masses,
    const float* __restrict__ accum, int N)
{
    int i = blockIdx.x * 256 + threadIdx.x;
    if (i < N) {
        float c = masses[i] / accum[3];
        f[i * 3 + 0] -= c * accum[0];
        f[i * 3 + 1] -= c * accum[1];
        f[i * 3 + 2] -= c * accum[2];
    }
}

extern "C" void kernel_launch(void* const* d_in, const int* in_sizes, int n_in,
                              void* d_out, int out_size, void* d_ws, size_t ws_size,
                              hipStream_t stream)
{
    (void)n_in; (void)ws_size;
    const float* pos    = (const float*)d_in[0];
    const float* masses = (const float*)d_in[1];
    const float* temb   = (const float*)d_in[2];
    const float* Wr1    = (const float*)d_in[3];
    const float* br1    = (const float*)d_in[4];
    const float* Wr2    = (const float*)d_in[5];
    const float* Wself  = (const float*)d_in[6];
    const float* Wo1    = (const float*)d_in[7];
    const float* bo1    = (const float*)d_in[8];
    const float* Wo2    = (const float*)d_in[9];
    const int* types    = (const int*)d_in[10];
    const int* eidx     = (const int*)d_in[11];
    const int N = in_sizes[1];
    const int E = in_sizes[11] / 2;

    float* out = (float*)d_out;
    float* forces = out + 1;

    float* ws = (float*)d_ws;
    float* s_acc = ws;                               // N*32
    float* v_acc = s_acc + (size_t)N * FDIM;         // N*96
    float* g_all = v_acc + (size_t)N * 96;           // N*128 (packed gradients)
    int nAtomBlocks = (N + 63) / 64;
    float* e_partial = g_all + (size_t)N * 128;      // nAtomBlocks
    float* accum = e_partial + nAtomBlocks;          // 4
    int* counts = (int*)(accum + 4);                 // N
    int* cursor = counts + N;                        // N
    int2* order_sd = (int2*)(cursor + N);            // E int2
    int nScan = (N + SCH - 1) / SCH;
    int* bsum = (int*)(order_sd + E);                // nScan

    hipMemsetAsync(d_out, 0, (size_t)out_size * sizeof(float), stream);
    hipMemsetAsync(s_acc, 0, (size_t)N * 128 * sizeof(float), stream);
    hipMemsetAsync(counts, 0, (size_t)N * sizeof(int), stream);
    hipMemsetAsync(accum, 0, 4 * sizeof(float), stream);

    hist_dst<<<2048, 256, 0, stream>>>(eidx, counts, E);
    scan_partial<<<nScan, 256, 0, stream>>>(counts, bsum, N);
    scan_bsum<<<1, 64, 0, stream>>>(bsum, nScan);
    scan_write<<<nScan, 256, 0, stream>>>(counts, bsum, cursor, N);
    scatter_edges<<<2048, 256, 0, stream>>>(eidx, cursor, order_sd, E);

    int nEdgeBlocks = (E + 127) / 128;
    edge_fwd_mfma<<<nEdgeBlocks, 256, 0, stream>>>(pos, types, order_sd,
                                                   Wr1, br1, Wr2, temb,
                                                   s_acc, v_acc, E);
    atom_mlp<<<nAtomBlocks, 256, 0, stream>>>(types, temb, Wself, Wo1, bo1, Wo2,
                                              s_acc, v_acc, g_all, e_partial, N);
    reduce_energy<<<1, 256, 0, stream>>>(e_partial, nAtomBlocks, out);
    edge_bwd_mfma<<<nEdgeBlocks, 256, 0, stream>>>(pos, types, order_sd,
                                                   Wr1, br1, Wr2, temb,
                                                   g_all, forces, E);
    reduce_net<<<64, 256, 0, stream>>>(forces, masses, accum, N);
    correct_forces<<<(N + 255) / 256, 256, 0, stream>>>(forces, masses, accum, N);
}

// Round 16
// 552.761 us; speedup vs baseline: 1.2588x; 1.0115x over previous
//
#include <hip/hip_runtime.h>
#include <math.h>

#define FDIM 32
#define NBASIS 8
#define QP 40     // A-stage row pad (f16 units) -> 80B rows, 16B-aligned quads
#define SCH 4096  // scan chunk per block (256 thr x 16)

constexpr float RCUT_C = 20.0f;
constexpr float PI_F = 3.14159265358979323846f;
constexpr float EV2KJ_C = 96.4853f;
constexpr float NM2A_C = 10.0f;

typedef _Float16 f16x8 __attribute__((ext_vector_type(8)));
typedef _Float16 f16x4 __attribute__((ext_vector_type(4)));
typedef float f32x4 __attribute__((ext_vector_type(4)));

__device__ __forceinline__ float sigmoidf_(float z) { return 1.0f / (1.0f + __expf(-z)); }

__device__ __forceinline__ unsigned int pk2_(float a, float b) {
    unsigned short lo = __builtin_bit_cast(unsigned short, (_Float16)a);
    unsigned short hi = __builtin_bit_cast(unsigned short, (_Float16)b);
    return (unsigned int)lo | ((unsigned int)hi << 16);
}
__device__ __forceinline__ float lo16_(unsigned int v) {
    return (float)__builtin_bit_cast(_Float16, (unsigned short)(v & 0xffffu));
}
__device__ __forceinline__ float hi16_(unsigned int v) {
    return (float)__builtin_bit_cast(_Float16, (unsigned short)(v >> 16));
}

// ---------------- CSR build: histogram, 3-kernel scan, scatter ----------------
__global__ __launch_bounds__(256) void hist_dst(
    const int* __restrict__ eidx, int* __restrict__ counts, int E)
{
    for (int e = blockIdx.x * 256 + threadIdx.x; e < E; e += gridDim.x * 256)
        atomicAdd(&counts[eidx[E + e]], 1);
}

__global__ __launch_bounds__(256) void scan_partial(
    const int* __restrict__ counts, int* __restrict__ bsum, int N)
{
    __shared__ int red[256];
    const int t = threadIdx.x;
    const int st = blockIdx.x * SCH + t * 16;
    int s = 0;
    #pragma unroll
    for (int i = 0; i < 16; i++) { int idx = st + i; if (idx < N) s += counts[idx]; }
    red[t] = s;
    __syncthreads();
    for (int k = 128; k; k >>= 1) {
        if (t < k) red[t] += red[t + k];
        __syncthreads();
    }
    if (t == 0) bsum[blockIdx.x] = red[0];
}

__global__ __launch_bounds__(64) void scan_bsum(int* __restrict__ bsum, int nb)
{
    if (threadIdx.x == 0) {
        int run = 0;
        for (int i = 0; i < nb; i++) { int v = bsum[i]; bsum[i] = run; run += v; }
    }
}

__global__ __launch_bounds__(256) void scan_write(
    const int* __restrict__ counts, const int* __restrict__ bsum,
    int* __restrict__ cursor, int N)
{
    __shared__ int lds[256];
    const int t = threadIdx.x;
    const int st = blockIdx.x * SCH + t * 16;
    int vals[16];
    int s = 0;
    #pragma unroll
    for (int i = 0; i < 16; i++) {
        int idx = st + i;
        int v = (idx < N) ? counts[idx] : 0;
        vals[i] = v; s += v;
    }
    lds[t] = s;
    __syncthreads();
    for (int off = 1; off < 256; off <<= 1) {
        int v = (t >= off) ? lds[t - off] : 0;
        __syncthreads();
        lds[t] += v;
        __syncthreads();
    }
    int run = bsum[blockIdx.x] + lds[t] - s;   // exclusive prefix
    #pragma unroll
    for (int i = 0; i < 16; i++) {
        int idx = st + i;
        if (idx < N) cursor[idx] = run;
        run += vals[i];
    }
}

__global__ __launch_bounds__(256) void scatter_edges(
    const int* __restrict__ eidx, int* __restrict__ cursor,
    int2* __restrict__ order_sd, int E)
{
    for (int e = blockIdx.x * 256 + threadIdx.x; e < E; e += gridDim.x * 256) {
        int dst = eidx[E + e];
        int p = atomicAdd(&cursor[dst], 1);
        order_sd[p] = make_int2(eidx[e], dst);
    }
}

// ---------------- edge forward: hs*env folded into packed D; LDS-stashed keys ----------------
__global__ __launch_bounds__(256) void edge_fwd_mfma(
    const float* __restrict__ pos, const int* __restrict__ types,
    const int2* __restrict__ order_sd,
    const float* __restrict__ Wr1, const float* __restrict__ br1,
    const float* __restrict__ Wr2, const float* __restrict__ temb,
    float* __restrict__ s_acc, float* __restrict__ v_acc, int E)
{
    __shared__ __align__(16) _Float16 sR[4][2560];
    __shared__ float sSt[4][32][4];         // env, rhx, rhy, rhz
    __shared__ int sTy[4][32];
    __shared__ int sKey[4][32];
    __shared__ float sTemb[96];

    const int lane = threadIdx.x & 63;
    const int l32 = threadIdx.x & 31;
    const int hw = (threadIdx.x >> 5) & 1;
    const int w = threadIdx.x >> 6;
    const int gbase = blockIdx.x * 128 + w * 32;

    for (int i = threadIdx.x; i < 96; i += 256) sTemb[i] = temb[i];
    __syncthreads();

    const int kb = (lane >> 4) * 8, nb = lane & 15;
    f16x8 bz[2];
    #pragma unroll
    for (int t = 0; t < 2; t++)
        #pragma unroll
        for (int j = 0; j < 8; j++) {
            int k = kb + j;
            bz[t][j] = (k < 8) ? (_Float16)Wr1[k * FDIM + t * 16 + nb] : (_Float16)0.0f;
        }
    f16x8 bf[4];
    #pragma unroll
    for (int t = 0; t < 4; t++)
        #pragma unroll
        for (int j = 0; j < 8; j++)
            bf[t][j] = (_Float16)Wr2[(kb + j) * 64 + t * 16 + nb];

    // ---- phase 0: lane-parallel geometry + basis (lanes 0..31) ----
    if (lane < 32) {
        const int ed = l32;
        const int p = gbase + ed;
        const bool vld = (p < E);
        int2 sd = vld ? order_sd[p] : make_int2(0, 0);
        float rx = (pos[sd.y * 3 + 0] - pos[sd.x * 3 + 0]) * NM2A_C;
        float ry = (pos[sd.y * 3 + 1] - pos[sd.x * 3 + 1]) * NM2A_C;
        float rz = (pos[sd.y * 3 + 2] - pos[sd.x * 3 + 2]) * NM2A_C;
        float r2 = rx * rx + ry * ry + rz * rz + 1e-12f;
        float r = sqrtf(r2);
        float rinv = 1.0f / r;
        float x = r * (1.0f / RCUT_C);
        float x2 = x * x, x4 = x2 * x2, x6 = x4 * x2, x7 = x6 * x, x8 = x6 * x2;
        float env = (x < 1.0f) ? (1.0f - 28.0f * x6 + 48.0f * x7 - 21.0f * x8) : 0.0f;

        float th = PI_F * x, s1, c1;
        __sincosf(th, &s1, &c1);
        float sp = 0.0f, sn = s1;
        _Float16 av[8];
        #pragma unroll
        for (int n = 0; n < NBASIS; n++) {
            av[n] = (_Float16)(sn * rinv);
            float snx = 2.0f * c1 * sn - sp; sp = sn; sn = snx;
        }
        _Float16* dstA = &sR[w][(ed < 16 ? 0 : 640) + (ed & 15) * QP];
        *(f16x8*)&dstA[0] = *(f16x8*)&av[0];
        *(float4*)&dstA[8]  = make_float4(0.f, 0.f, 0.f, 0.f);
        *(float4*)&dstA[16] = make_float4(0.f, 0.f, 0.f, 0.f);
        *(float4*)&dstA[24] = make_float4(0.f, 0.f, 0.f, 0.f);
        sSt[w][ed][0] = env;
        sSt[w][ed][1] = rx * rinv;
        sSt[w][ed][2] = ry * rinv;
        sSt[w][ed][3] = rz * rinv;
        sTy[w][ed] = types[sd.x];
        sKey[w][ed] = vld ? sd.y : -1;
    }

    // ---- phase 1: MFMA basis layer -> z, silu -> Q (both tiles) ----
    {
        const int me = lane & 15;
        f16x8 a1a = *(const f16x8*)&sR[w][me * QP + kb];
        f16x8 a1b = *(const f16x8*)&sR[w][640 + me * QP + kb];
        const f32x4 z4 = {0.f, 0.f, 0.f, 0.f};
        f32x4 Dz0a = __builtin_amdgcn_mfma_f32_16x16x32_f16(a1a, bz[0], z4, 0, 0, 0);
        f32x4 Dz1a = __builtin_amdgcn_mfma_f32_16x16x32_f16(a1a, bz[1], z4, 0, 0, 0);
        f32x4 Dz0b = __builtin_amdgcn_mfma_f32_16x16x32_f16(a1b, bz[0], z4, 0, 0, 0);
        f32x4 Dz1b = __builtin_amdgcn_mfma_f32_16x16x32_f16(a1b, bz[1], z4, 0, 0, 0);
        const int f0 = lane & 15, e0 = (lane >> 4) * 4;
        const float bb0 = br1[f0], bb1 = br1[16 + f0];
        #pragma unroll
        for (int t = 0; t < 2; t++) {
            f32x4 Dza = t ? Dz1a : Dz0a;
            f32x4 Dzb = t ? Dz1b : Dz0b;
            float bb = t ? bb1 : bb0;
            #pragma unroll
            for (int r = 0; r < 4; r++) {
                float za = Dza[r] + bb;
                float zb = Dzb[r] + bb;
                sR[w][1280 + (e0 + r) * QP + t * 16 + f0] = (_Float16)(za * sigmoidf_(za));
                sR[w][1920 + (e0 + r) * QP + t * 16 + f0] = (_Float16)(zb * sigmoidf_(zb));
            }
        }
    }

    // ---- phase 2: MFMA W2; fold hs*env; pack (ch, ch+32) pairs; D[edge*32+ch] ----
    {
        const int me = lane & 15;
        f16x8 aqa = *(const f16x8*)&sR[w][1280 + me * QP + kb];
        f16x8 aqb = *(const f16x8*)&sR[w][1920 + me * QP + kb];
        const int cb = lane & 15, e0 = (lane >> 4) * 4;
        float hev[2][2][4];   // [tile][fpair][r] = hs(ch)*env
        #pragma unroll
        for (int tl = 0; tl < 2; tl++)
            #pragma unroll
            for (int fp = 0; fp < 2; fp++)
                #pragma unroll
                for (int r = 0; r < 4; r++) {
                    int ed = tl * 16 + e0 + r;
                    hev[tl][fp][r] = sTemb[sTy[w][ed] * 32 + fp * 16 + cb] * sSt[w][ed][0];
                }
        const f32x4 z4 = {0.f, 0.f, 0.f, 0.f};
        unsigned int* DU = (unsigned int*)&sR[w][0];
        #pragma unroll
        for (int fp = 0; fp < 2; fp++) {
            f32x4 a0 = __builtin_amdgcn_mfma_f32_16x16x32_f16(aqa, bf[fp],     z4, 0, 0, 0);
            f32x4 a1 = __builtin_amdgcn_mfma_f32_16x16x32_f16(aqa, bf[fp + 2], z4, 0, 0, 0);
            f32x4 b0 = __builtin_amdgcn_mfma_f32_16x16x32_f16(aqb, bf[fp],     z4, 0, 0, 0);
            f32x4 b1 = __builtin_amdgcn_mfma_f32_16x16x32_f16(aqb, bf[fp + 2], z4, 0, 0, 0);
            #pragma unroll
            for (int r = 0; r < 4; r++) {
                float ha = hev[0][fp][r], hb = hev[1][fp][r];
                DU[(e0 + r) * 32 + fp * 16 + cb]        = pk2_(a0[r] * ha, a1[r] * ha);
                DU[(16 + e0 + r) * 32 + fp * 16 + cb]   = pk2_(b0[r] * hb, b1[r] * hb);
            }
        }
    }

    // ---- phase 3: epilogue, run-merge carried across both tiles (keys from LDS) ----
    const unsigned int* DU = (const unsigned int*)&sR[w][0];
    int runKey = -1;
    float sAcc = 0.f, vXA = 0.f, vYA = 0.f, vZA = 0.f;
    #pragma unroll
    for (int t = 0; t < 2; t++) {
        #pragma unroll
        for (int i = 0; i < 8; i++) {
            const int m = t * 16 + hw * 8 + i;
            const int p = gbase + m;
            if (p >= E) break;
            int k = sKey[w][m];
            if (k != runKey) {
                if (runKey >= 0) {
                    unsafeAtomicAdd(&s_acc[(size_t)runKey * 32 + l32], sAcc);
                    unsafeAtomicAdd(&v_acc[(size_t)runKey * 96 + 0 * 32 + l32], vXA);
                    unsafeAtomicAdd(&v_acc[(size_t)runKey * 96 + 1 * 32 + l32], vYA);
                    unsafeAtomicAdd(&v_acc[(size_t)runKey * 96 + 2 * 32 + l32], vZA);
                }
                runKey = k;
                sAcc = vXA = vYA = vZA = 0.f;
            }
            unsigned int qp = DU[m * 32 + l32];
            float s0 = lo16_(qp);       // hs*env*rw0
            float h1 = hi16_(qp);       // hs*env*rw1
            sAcc += s0;
            vXA += h1 * sSt[w][m][1];
            vYA += h1 * sSt[w][m][2];
            vZA += h1 * sSt[w][m][3];
        }
    }
    if (runKey >= 0) {
        unsafeAtomicAdd(&s_acc[(size_t)runKey * 32 + l32], sAcc);
        unsafeAtomicAdd(&v_acc[(size_t)runKey * 96 + 0 * 32 + l32], vXA);
        unsafeAtomicAdd(&v_acc[(size_t)runKey * 96 + 1 * 32 + l32], vYA);
        unsafeAtomicAdd(&v_acc[(size_t)runKey * 96 + 2 * 32 + l32], vZA);
    }
}

// -------- atom MLP: 64 atoms/block; writes packed g_all[a*128 + f*4] = {gs,gvx,gvy,gvz} --------
__global__ __launch_bounds__(256) void atom_mlp(
    const int* __restrict__ types, const float* __restrict__ temb,
    const float* __restrict__ Wself, const float* __restrict__ Wo1,
    const float* __restrict__ bo1, const float* __restrict__ Wo2,
    const float* __restrict__ s_acc, const float* __restrict__ v_acc,
    float* __restrict__ g_all, float* __restrict__ e_partial, int N)
{
    __shared__ float sWs[FDIM * FDIM], sWsT[FDIM * FDIM];
    __shared__ float sWo1[2 * FDIM * FDIM], sWo1T[2 * FDIM * FDIM];
    __shared__ float sb[FDIM], sW2o[FDIM], sTE[96];
    __shared__ float gred[8];
    for (int i = threadIdx.x; i < FDIM * FDIM; i += 256) {
        sWs[i] = Wself[i];
        sWsT[i] = Wself[(i & 31) * FDIM + (i >> 5)];
    }
    for (int i = threadIdx.x; i < 2 * FDIM * FDIM; i += 256) {
        sWo1[i] = Wo1[i];
        sWo1T[i] = Wo1[(i & 63) * FDIM + (i >> 6)];
    }
    for (int i = threadIdx.x; i < FDIM; i += 256) { sb[i] = bo1[i]; sW2o[i] = Wo2[i]; }
    for (int i = threadIdx.x; i < 96; i += 256) sTE[i] = temb[i];
    __syncthreads();

    const int lane = threadIdx.x & 31;
    const int g = threadIdx.x >> 5;
    float eAcc = 0.0f;

    for (int it = 0; it < 8; it++) {
        int a = blockIdx.x * 64 + it * 8 + g;
        const bool valid = (a < N);
        if (!valid) a = 0;

        float sv = s_acc[(size_t)a * FDIM + lane];
        float vx = v_acc[(size_t)a * 96 + 0 * 32 + lane];
        float vy = v_acc[(size_t)a * 96 + 1 * 32 + lane];
        float vz = v_acc[(size_t)a * 96 + 2 * 32 + lane];
        float h = sTE[types[a] * FDIM + lane];
        float vn = sqrtf(vx * vx + vy * vy + vz * vz + 1e-12f);

        float row = h;
        #pragma unroll
        for (int f = 0; f < FDIM; f++) {
            float t = __shfl(sv, f, 32);
            row += t * sWs[f * FDIM + lane];
        }
        float u = sb[lane];
        #pragma unroll
        for (int j = 0; j < FDIM; j++) {
            float rv = __shfl(row, j, 32);
            float vv = __shfl(vn, j, 32);
            u += rv * sWo1[j * FDIM + lane] + vv * sWo1[(j + FDIM) * FDIM + lane];
        }
        float sg = sigmoidf_(u);
        float au = u * sg;
        float pa = valid ? au * sW2o[lane] : 0.0f;
        #pragma unroll
        for (int m = 16; m; m >>= 1) pa += __shfl_xor(pa, m, 32);
        if (lane == 0) eAcc += pa;

        float gu = sW2o[lane] * (sg * (1.0f + u * (1.0f - sg)));
        float gfr = 0.0f, gfv = 0.0f;
        #pragma unroll
        for (int k = 0; k < FDIM; k++) {
            float gv_ = __shfl(gu, k, 32);
            gfr += gv_ * sWo1T[k * 64 + lane];
            gfv += gv_ * sWo1T[k * 64 + 32 + lane];
        }
        float gs = 0.0f;
        #pragma unroll
        for (int k = 0; k < FDIM; k++) {
            float gr = __shfl(gfr, k, 32);
            gs += gr * sWsT[k * FDIM + lane];
        }
        if (valid) {
            float sc = gfv / vn;
            *(float4*)&g_all[(size_t)a * 128 + lane * 4] =
                make_float4(gs, sc * vx, sc * vy, sc * vz);
        }
    }
    if (lane == 0) gred[g] = eAcc;
    __syncthreads();
    if (threadIdx.x == 0) {
        float t = 0.0f;
        #pragma unroll
        for (int i = 0; i < 8; i++) t += gred[i];
        e_partial[blockIdx.x] = t;
    }
}

// ---------------- edge backward: transposed epilogue split across half-waves ----------------
__global__ __launch_bounds__(256) void edge_bwd_mfma(
    const float* __restrict__ pos, const int* __restrict__ types,
    const int2* __restrict__ order_sd,
    const float* __restrict__ Wr1, const float* __restrict__ br1,
    const float* __restrict__ Wr2, const float* __restrict__ temb,
    const float* __restrict__ g_all,
    float* __restrict__ forces, int E)
{
    __shared__ __align__(16) _Float16 sR1[4][2560];
    __shared__ __align__(16) _Float16 sR2[4][2048];
    __shared__ int   sTy[4][32];
    __shared__ float sTemb[96];

    const int lane = threadIdx.x & 63;
    const int l32 = threadIdx.x & 31;
    const int w = threadIdx.x >> 6;
    const int gbase = blockIdx.x * 128 + w * 32;

    for (int i = threadIdx.x; i < 96; i += 256) sTemb[i] = temb[i];
    __syncthreads();

    const int kb = (lane >> 4) * 8, nb = lane & 15;
    f16x8 bz[2], bt[2];
    #pragma unroll
    for (int t = 0; t < 2; t++)
        #pragma unroll
        for (int j = 0; j < 8; j++) {
            int k = kb + j;
            bz[t][j] = (k < 8) ? (_Float16)Wr1[k * FDIM + t * 16 + nb] : (_Float16)0.0f;
            bt[t][j] = (k >= 8 && k < 16) ? (_Float16)Wr1[(k - 8) * FDIM + t * 16 + nb] : (_Float16)0.0f;
        }
    f16x8 bf[4];
    #pragma unroll
    for (int t = 0; t < 4; t++)
        #pragma unroll
        for (int j = 0; j < 8; j++)
            bf[t][j] = (_Float16)Wr2[(kb + j) * 64 + t * 16 + nb];

    // ---- phase 0: edge descriptors for ALL lanes (halves mirror edges 0..31) ----
    const int p_e = gbase + l32;
    const bool valid = (p_e < E);
    int2 sd = valid ? order_sd[p_e] : make_int2(0, 0);
    const int srcI = sd.x, dstI = sd.y;
    const int key = valid ? sd.y : (-2 - l32);

    float rinv = 1.f, env = 0.f, denv = 0.f, rhx = 0.f, rhy = 0.f, rhz = 0.f;
    if (lane < 32) {
        float rx = (pos[sd.y * 3 + 0] - pos[sd.x * 3 + 0]) * NM2A_C;
        float ry = (pos[sd.y * 3 + 1] - pos[sd.x * 3 + 1]) * NM2A_C;
        float rz = (pos[sd.y * 3 + 2] - pos[sd.x * 3 + 2]) * NM2A_C;
        float r2 = rx * rx + ry * ry + rz * rz + 1e-12f;
        float r = sqrtf(r2);
        rinv = 1.0f / r;
        float x = r * (1.0f / RCUT_C);
        float x2 = x * x, x4 = x2 * x2, x5 = x4 * x, x6 = x4 * x2, x7 = x6 * x, x8 = x6 * x2;
        env = (x < 1.0f) ? (1.0f - 28.0f * x6 + 48.0f * x7 - 21.0f * x8) : 0.0f;
        denv = (x < 1.0f) ? (-168.0f * x5 + 336.0f * x6 - 168.0f * x7) * (1.0f / RCUT_C) : 0.0f;
        rhx = rx * rinv; rhy = ry * rinv; rhz = rz * rinv;

        float th = PI_F * x, s1, c1;
        __sincosf(th, &s1, &c1);
        float sp = 0.0f, sn = s1, cp = 1.0f, cn = c1;
        _Float16 av[16];
        #pragma unroll
        for (int n = 0; n < NBASIS; n++) {
            float basis = sn * rinv;
            float dbdr = (PI_F * (float)(n + 1) * (1.0f / RCUT_C)) * cn * rinv - basis * rinv;
            av[n] = (_Float16)basis;
            av[8 + n] = (_Float16)dbdr;
            float snx = 2.0f * c1 * sn - sp; sp = sn; sn = snx;
            float cnx = 2.0f * c1 * cn - cp; cp = cn; cn = cnx;
        }
        _Float16* dstA = &sR1[w][(l32 < 16 ? 0 : 640) + (l32 & 15) * QP];
        *(f16x8*)&dstA[0] = *(f16x8*)&av[0];
        *(f16x8*)&dstA[8] = *(f16x8*)&av[8];
        *(float4*)&dstA[16] = make_float4(0.f, 0.f, 0.f, 0.f);
        *(float4*)&dstA[24] = make_float4(0.f, 0.f, 0.f, 0.f);
        sTy[w][l32] = types[sd.x];
    }

    // ---- phase 1: MFMA basis layer (both tiles) -> z, tacc; silu/tf -> Q/T ----
    {
        const int me = lane & 15;
        f16x8 a1a = *(const f16x8*)&sR1[w][me * QP + kb];
        f16x8 a1b = *(const f16x8*)&sR1[w][640 + me * QP + kb];
        const f32x4 z4 = {0.f, 0.f, 0.f, 0.f};
        f32x4 Dz0a = __builtin_amdgcn_mfma_f32_16x16x32_f16(a1a, bz[0], z4, 0, 0, 0);
        f32x4 Dz1a = __builtin_amdgcn_mfma_f32_16x16x32_f16(a1a, bz[1], z4, 0, 0, 0);
        f32x4 Dt0a = __builtin_amdgcn_mfma_f32_16x16x32_f16(a1a, bt[0], z4, 0, 0, 0);
        f32x4 Dt1a = __builtin_amdgcn_mfma_f32_16x16x32_f16(a1a, bt[1], z4, 0, 0, 0);
        f32x4 Dz0b = __builtin_amdgcn_mfma_f32_16x16x32_f16(a1b, bz[0], z4, 0, 0, 0);
        f32x4 Dz1b = __builtin_amdgcn_mfma_f32_16x16x32_f16(a1b, bz[1], z4, 0, 0, 0);
        f32x4 Dt0b = __builtin_amdgcn_mfma_f32_16x16x32_f16(a1b, bt[0], z4, 0, 0, 0);
        f32x4 Dt1b = __builtin_amdgcn_mfma_f32_16x16x32_f16(a1b, bt[1], z4, 0, 0, 0);
        const int f0 = lane & 15, e0 = (lane >> 4) * 4;
        const float bb0 = br1[f0], bb1 = br1[16 + f0];
        #pragma unroll
        for (int t = 0; t < 2; t++) {
            f32x4 Dza = t ? Dz1a : Dz0a;
            f32x4 Dta = t ? Dt1a : Dt0a;
            f32x4 Dzb = t ? Dz1b : Dz0b;
            f32x4 Dtb = t ? Dt1b : Dt0b;
            float bb = t ? bb1 : bb0;
            #pragma unroll
            for (int r = 0; r < 4; r++) {
                float za = Dza[r] + bb;
                float sga = sigmoidf_(za);
                sR2[w][(e0 + r) * QP + t * 16 + f0] = (_Float16)(za * sga);
                sR1[w][1280 + (e0 + r) * QP + t * 16 + f0] =
                    (_Float16)((sga * (1.0f + za * (1.0f - sga))) * Dta[r]);
                float zb = Dzb[r] + bb;
                float sgb = sigmoidf_(zb);
                sR2[w][640 + (e0 + r) * QP + t * 16 + f0] = (_Float16)(zb * sgb);
                sR1[w][1920 + (e0 + r) * QP + t * 16 + f0] =
                    (_Float16)((sgb * (1.0f + zb * (1.0f - sgb))) * Dtb[r]);
            }
        }
    }

    // ---- phase 2: 16 MFMAs; fold hs; pack (x, x+32) channel pairs as f16x2 ----
    {
        const int me = lane & 15;
        f16x8 aqa = *(const f16x8*)&sR2[w][me * QP + kb];
        f16x8 ata = *(const f16x8*)&sR1[w][1280 + me * QP + kb];
        f16x8 aqb = *(const f16x8*)&sR2[w][640 + me * QP + kb];
        f16x8 atb = *(const f16x8*)&sR1[w][1920 + me * QP + kb];
        const int cb = lane & 15, e0 = (lane >> 4) * 4;
        float hsv[2][2][4];   // [tile][fpair][r]
        #pragma unroll
        for (int tl = 0; tl < 2; tl++)
            #pragma unroll
            for (int r = 0; r < 4; r++) {
                int ty = sTy[w][tl * 16 + e0 + r];
                hsv[tl][0][r] = sTemb[ty * 32 + cb];
                hsv[tl][1][r] = sTemb[ty * 32 + 16 + cb];
            }
        const f32x4 z4 = {0.f, 0.f, 0.f, 0.f};
        unsigned int* DqU = (unsigned int*)&sR1[w][0];
        unsigned int* DtU = (unsigned int*)&sR2[w][0];
        #pragma unroll
        for (int fp = 0; fp < 2; fp++) {
            f32x4 qa0 = __builtin_amdgcn_mfma_f32_16x16x32_f16(aqa, bf[fp],     z4, 0, 0, 0);
            f32x4 qa1 = __builtin_amdgcn_mfma_f32_16x16x32_f16(aqa, bf[fp + 2], z4, 0, 0, 0);
            f32x4 qb0 = __builtin_amdgcn_mfma_f32_16x16x32_f16(aqb, bf[fp],     z4, 0, 0, 0);
            f32x4 qb1 = __builtin_amdgcn_mfma_f32_16x16x32_f16(aqb, bf[fp + 2], z4, 0, 0, 0);
            f32x4 ta0 = __builtin_amdgcn_mfma_f32_16x16x32_f16(ata, bf[fp],     z4, 0, 0, 0);
            f32x4 ta1 = __builtin_amdgcn_mfma_f32_16x16x32_f16(ata, bf[fp + 2], z4, 0, 0, 0);
            f32x4 tb0 = __builtin_amdgcn_mfma_f32_16x16x32_f16(atb, bf[fp],     z4, 0, 0, 0);
            f32x4 tb1 = __builtin_amdgcn_mfma_f32_16x16x32_f16(atb, bf[fp + 2], z4, 0, 0, 0);
            unsigned int pqa[4], pqb[4], pta[4], ptb[4];
            #pragma unroll
            for (int r = 0; r < 4; r++) {
                float ha = hsv[0][fp][r], hb = hsv[1][fp][r];
                pqa[r] = pk2_(qa0[r] * ha, qa1[r] * ha);
                pqb[r] = pk2_(qb0[r] * hb, qb1[r] * hb);
                pta[r] = pk2_(ta0[r] * ha, ta1[r] * ha);
                ptb[r] = pk2_(tb0[r] * hb, tb1[r] * hb);
            }
            const int f = fp * 16 + cb;
            *(uint4*)&DqU[f * 16 + e0]       = make_uint4(pqa[0], pqa[1], pqa[2], pqa[3]);
            *(uint4*)&DqU[512 + f * 16 + e0] = make_uint4(pqb[0], pqb[1], pqb[2], pqb[3]);
            *(uint4*)&DtU[f * 16 + e0]       = make_uint4(pta[0], pta[1], pta[2], pta[3]);
            *(uint4*)&DtU[512 + f * 16 + e0] = make_uint4(ptb[0], ptb[1], ptb[2], ptb[3]);
        }
    }

    // ---- phase 3: transposed epilogue; both halves accumulate (f split), then pair-reduce ----
    {
        const unsigned int* DqU = (const unsigned int*)&sR1[w][0];
        const unsigned int* DtU = (const unsigned int*)&sR2[w][0];
        const int tb = (l32 >> 4) * 512;
        const int me = l32 & 15;
        const int fb = (lane >> 5) * 16;     // lower half: f 0..15, upper half: f 16..31
        const float* gb = g_all + (size_t)dstI * 128;
        float Aa = 0.f, Bb = 0.f, Cc = 0.f, Pp = 0.f;
        float Ap = 0.f, Bp = 0.f, Cp = 0.f, Qq = 0.f;
        #pragma unroll 8
        for (int ff = 0; ff < 16; ff++) {
            const int f = fb + ff;
            unsigned int qp = DqU[tb + f * 16 + me];
            unsigned int tp = DtU[tb + f * 16 + me];
            float rw0 = lo16_(qp), rw1 = hi16_(qp);
            float u0 = lo16_(tp), u1 = hi16_(tp);
            float4 g4 = *(const float4*)(gb + f * 4);
            Pp += rw0 * g4.x; Qq += u0 * g4.x;
            Aa += rw1 * g4.y; Bb += rw1 * g4.z; Cc += rw1 * g4.w;
            Ap += u1 * g4.y;  Bp += u1 * g4.z;  Cp += u1 * g4.w;
        }
        // cross-half pair reduction (wave64)
        Pp += __shfl_xor(Pp, 32, 64); Qq += __shfl_xor(Qq, 32, 64);
        Aa += __shfl_xor(Aa, 32, 64); Bb += __shfl_xor(Bb, 32, 64);
        Cc += __shfl_xor(Cc, 32, 64); Ap += __shfl_xor(Ap, 32, 64);
        Bp += __shfl_xor(Bp, 32, 64); Cp += __shfl_xor(Cp, 32, 64);

        if (lane < 32) {
            float Gx = env * Aa, Gy = env * Bb, Gz = env * Cc;
            float genv = Pp + rhx * Aa + rhy * Bb + rhz * Cc;
            float pc = env * (Qq + rhx * Ap + rhy * Bp + rhz * Cp) + genv * denv;
            float dotg = Gx * rhx + Gy * rhy + Gz * rhz;
            float cx = pc * rhx + (Gx - dotg * rhx) * rinv;
            float cy = pc * rhy + (Gy - dotg * rhy) * rinv;
            float cz = pc * rhz + (Gz - dotg * rhz) * rinv;

            const float SC = EV2KJ_C * NM2A_C;
            if (valid) {
                unsafeAtomicAdd(&forces[(size_t)srcI * 3 + 0], SC * cx);
                unsafeAtomicAdd(&forces[(size_t)srcI * 3 + 1], SC * cy);
                unsafeAtomicAdd(&forces[(size_t)srcI * 3 + 2], SC * cz);
            }
            // segmented inclusive scan over contiguous dst runs
            int kk = key;
            #pragma unroll
            for (int d = 1; d < 32; d <<= 1) {
                float ux = __shfl_up(cx, d, 32);
                float uy = __shfl_up(cy, d, 32);
                float uz = __shfl_up(cz, d, 32);
                int uk = __shfl_up(kk, d, 32);
                if (l32 >= d && uk == kk) { cx += ux; cy += uy; cz += uz; }
            }
            int nk = __shfl_down(kk, 1, 32);
            bool leader = (l32 == 31) || (nk != kk);
            if (valid && leader) {
                unsafeAtomicAdd(&forces[(size_t)dstI * 3 + 0], -SC * cx);
                unsafeAtomicAdd(&forces[(size_t)dstI * 3 + 1], -SC * cy);
                unsafeAtomicAdd(&forces[(size_t)dstI * 3 + 2], -SC * cz);
            }
        }
    }
}

// ---------------- reductions & correction ----------------
__global__ __launch_bounds__(256) void reduce_energy(
    const float* __restrict__ e_partial, int n, float* __restrict__ out)
{
    __shared__ float red[256];
    float s = 0.0f;
    for (int i = threadIdx.x; i < n; i += 256) s += e_partial[i];
    red[threadIdx.x] = s;
    __syncthreads();
    for (int k = 128; k; k >>= 1) {
        if (threadIdx.x < k) red[threadIdx.x] += red[threadIdx.x + k];
        __syncthreads();
    }
    if (threadIdx.x == 0) out[0] = red[0] * EV2KJ_C;
}

__global__ __launch_bounds__(256) void reduce_net(
    const float* __restrict__ f, const float* __restrict__ masses,
    float* __restrict__ accum, int N)
{
    float nx = 0, ny = 0, nz = 0, ms = 0;
    for (int i = blockIdx.x * 256 + threadIdx.x; i < N; i += gridDim.x * 256) {
        nx += f[i * 3 + 0]; ny += f[i * 3 + 1]; nz += f[i * 3 + 2]; ms += masses[i];
    }
    #pragma unroll
    for (int m = 32; m; m >>= 1) {
        nx += __shfl_xor(nx, m, 64);
        ny += __shfl_xor(ny, m, 64);
        nz += __shfl_xor(nz, m, 64);
        ms += __shfl_xor(ms, m, 64);
    }
    __shared__ float red[4][4];
    int w = threadIdx.x >> 6;
    if ((threadIdx.x & 63) == 0) { red[w][0] = nx; red[w][1] = ny; red[w][2] = nz; red[w][3] = ms; }
    __syncthreads();
    if (threadIdx.x == 0) {
        float a0 = 0, a1 = 0, a2 = 0, a3 = 0;
        for (int i = 0; i < 4; i++) { a0 += red[i][0]; a1 += red[i][1]; a2 += red[i][2]; a3 += red[i][3]; }
        unsafeAtomicAdd(accum + 0, a0);
        unsafeAtomicAdd(accum + 1, a1);
        unsafeAtomicAdd(accum + 2, a2);
        unsafeAtomicAdd(accum + 3, a3);
    }
}

__global__ __launch_bounds__(256) void correct_forces(
    float* __restrict__ f, const float* __restrict__ masses,
    const float* __restrict__ accum, int N)
{
    int i = blockIdx.x * 256 + threadIdx.x;
    if (i < N) {
        float c = masses[i] / accum[3];
        f[i * 3 + 0] -= c * accum[0];
        f[i * 3 + 1] -= c * accum[1];
        f[i * 3 + 2] -= c * accum[2];
    }
}

extern "C" void kernel_launch(void* const* d_in, const int* in_sizes, int n_in,
                              void* d_out, int out_size, void* d_ws, size_t ws_size,
                              hipStream_t stream)
{
    (void)n_in; (void)ws_size;
    const float* pos    = (const float*)d_in[0];
    const float* masses = (const float*)d_in[1];
    const float* temb   = (const float*)d_in[2];
    const float* Wr1    = (const float*)d_in[3];
    const float* br1    = (const float*)d_in[4];
    const float* Wr2    = (const float*)d_in[5];
    const float* Wself  = (const float*)d_in[6];
    const float* Wo1    = (const float*)d_in[7];
    const float* bo1    = (const float*)d_in[8];
    const float* Wo2    = (const float*)d_in[9];
    const int* types    = (const int*)d_in[10];
    const int* eidx     = (const int*)d_in[11];
    const int N = in_sizes[1];
    const int E = in_sizes[11] / 2;

    float* out = (float*)d_out;
    float* forces = out + 1;

    float* ws = (float*)d_ws;
    float* s_acc = ws;                               // N*32
    float* v_acc = s_acc + (size_t)N * FDIM;         // N*96
    float* g_all = v_acc + (size_t)N * 96;           // N*128 (packed gradients)
    int nAtomBlocks = (N + 63) / 64;
    float* e_partial = g_all + (size_t)N * 128;      // nAtomBlocks
    float* accum = e_partial + nAtomBlocks;          // 4
    int* counts = (int*)(accum + 4);                 // N
    int* cursor = counts + N;                        // N
    int2* order_sd = (int2*)(cursor + N);            // E int2
    int nScan = (N + SCH - 1) / SCH;
    int* bsum = (int*)(order_sd + E);                // nScan

    hipMemsetAsync(d_out, 0, (size_t)out_size * sizeof(float), stream);
    hipMemsetAsync(s_acc, 0, (size_t)N * 128 * sizeof(float), stream);
    hipMemsetAsync(counts, 0, (size_t)N * sizeof(int), stream);
    hipMemsetAsync(accum, 0, 4 * sizeof(float), stream);

    hist_dst<<<2048, 256, 0, stream>>>(eidx, counts, E);
    scan_partial<<<nScan, 256, 0, stream>>>(counts, bsum, N);
    scan_bsum<<<1, 64, 0, stream>>>(bsum, nScan);
    scan_write<<<nScan, 256, 0, stream>>>(counts, bsum, cursor, N);
    scatter_edges<<<2048, 256, 0, stream>>>(eidx, cursor, order_sd, E);

    int nEdgeBlocks = (E + 127) / 128;
    edge_fwd_mfma<<<nEdgeBlocks, 256, 0, stream>>>(pos, types, order_sd,
                                                   Wr1, br1, Wr2, temb,
                                                   s_acc, v_acc, E);
    atom_mlp<<<nAtomBlocks, 256, 0, stream>>>(types, temb, Wself, Wo1, bo1, Wo2,
                                              s_acc, v_acc, g_all, e_partial, N);
    reduce_energy<<<1, 256, 0, stream>>>(e_partial, nAtomBlocks, out);
    edge_bwd_mfma<<<nEdgeBlocks, 256, 0, stream>>>(pos, types, order_sd,
                                                   Wr1, br1, Wr2, temb,
                                                   g_all, forces, E);
    reduce_net<<<64, 256, 0, stream>>>(forces, masses, accum, N);
    correct_forces<<<(N + 255) / 256, 256, 0, stream>>>(forces, masses, accum, N);
}

// Round 17
// 547.503 us; speedup vs baseline: 1.2709x; 1.0096x over previous
//
#include <hip/hip_runtime.h>
#include <math.h>

#define FDIM 32
#define NBASIS 8
#define QP 40     // A-stage row pad (f16 units) -> 80B rows, 16B-aligned quads
#define SCH 4096  // scan chunk per block (256 thr x 16)

constexpr float RCUT_C = 20.0f;
constexpr float PI_F = 3.14159265358979323846f;
constexpr float EV2KJ_C = 96.4853f;
constexpr float NM2A_C = 10.0f;

typedef _Float16 f16x8 __attribute__((ext_vector_type(8)));
typedef _Float16 f16x4 __attribute__((ext_vector_type(4)));
typedef float f32x4 __attribute__((ext_vector_type(4)));

__device__ __forceinline__ float sigmoidf_(float z) { return 1.0f / (1.0f + __expf(-z)); }

__device__ __forceinline__ unsigned int pk2_(float a, float b) {
    unsigned short lo = __builtin_bit_cast(unsigned short, (_Float16)a);
    unsigned short hi = __builtin_bit_cast(unsigned short, (_Float16)b);
    return (unsigned int)lo | ((unsigned int)hi << 16);
}
__device__ __forceinline__ float lo16_(unsigned int v) {
    return (float)__builtin_bit_cast(_Float16, (unsigned short)(v & 0xffffu));
}
__device__ __forceinline__ float hi16_(unsigned int v) {
    return (float)__builtin_bit_cast(_Float16, (unsigned short)(v >> 16));
}

// ---------------- CSR build: histogram, 3-kernel scan, scatter ----------------
__global__ __launch_bounds__(256) void hist_dst(
    const int* __restrict__ eidx, int* __restrict__ counts, int E)
{
    for (int e = blockIdx.x * 256 + threadIdx.x; e < E; e += gridDim.x * 256)
        atomicAdd(&counts[eidx[E + e]], 1);
}

__global__ __launch_bounds__(256) void scan_partial(
    const int* __restrict__ counts, int* __restrict__ bsum, int N)
{
    __shared__ int red[256];
    const int t = threadIdx.x;
    const int st = blockIdx.x * SCH + t * 16;
    int s = 0;
    #pragma unroll
    for (int i = 0; i < 16; i++) { int idx = st + i; if (idx < N) s += counts[idx]; }
    red[t] = s;
    __syncthreads();
    for (int k = 128; k; k >>= 1) {
        if (t < k) red[t] += red[t + k];
        __syncthreads();
    }
    if (t == 0) bsum[blockIdx.x] = red[0];
}

__global__ __launch_bounds__(64) void scan_bsum(int* __restrict__ bsum, int nb)
{
    if (threadIdx.x == 0) {
        int run = 0;
        for (int i = 0; i < nb; i++) { int v = bsum[i]; bsum[i] = run; run += v; }
    }
}

__global__ __launch_bounds__(256) void scan_write(
    const int* __restrict__ counts, const int* __restrict__ bsum,
    int* __restrict__ cursor, int N)
{
    __shared__ int lds[256];
    const int t = threadIdx.x;
    const int st = blockIdx.x * SCH + t * 16;
    int vals[16];
    int s = 0;
    #pragma unroll
    for (int i = 0; i < 16; i++) {
        int idx = st + i;
        int v = (idx < N) ? counts[idx] : 0;
        vals[i] = v; s += v;
    }
    lds[t] = s;
    __syncthreads();
    for (int off = 1; off < 256; off <<= 1) {
        int v = (t >= off) ? lds[t - off] : 0;
        __syncthreads();
        lds[t] += v;
        __syncthreads();
    }
    int run = bsum[blockIdx.x] + lds[t] - s;   // exclusive prefix
    #pragma unroll
    for (int i = 0; i < 16; i++) {
        int idx = st + i;
        if (idx < N) cursor[idx] = run;
        run += vals[i];
    }
}

__global__ __launch_bounds__(256) void scatter_edges(
    const int* __restrict__ eidx, int* __restrict__ cursor,
    int2* __restrict__ order_sd, int E)
{
    for (int e = blockIdx.x * 256 + threadIdx.x; e < E; e += gridDim.x * 256) {
        int dst = eidx[E + e];
        int p = atomicAdd(&cursor[dst], 1);
        order_sd[p] = make_int2(eidx[e], dst);
    }
}

// ---------------- edge forward: hs*env folded into packed D; LDS-stashed keys (r16 form) ----------------
__global__ __launch_bounds__(256) void edge_fwd_mfma(
    const float* __restrict__ pos, const int* __restrict__ types,
    const int2* __restrict__ order_sd,
    const float* __restrict__ Wr1, const float* __restrict__ br1,
    const float* __restrict__ Wr2, const float* __restrict__ temb,
    float* __restrict__ s_acc, float* __restrict__ v_acc, int E)
{
    __shared__ __align__(16) _Float16 sR[4][2560];
    __shared__ float sSt[4][32][4];         // env, rhx, rhy, rhz
    __shared__ int sTy[4][32];
    __shared__ int sKey[4][32];
    __shared__ float sTemb[96];

    const int lane = threadIdx.x & 63;
    const int l32 = threadIdx.x & 31;
    const int hw = (threadIdx.x >> 5) & 1;
    const int w = threadIdx.x >> 6;
    const int gbase = blockIdx.x * 128 + w * 32;

    for (int i = threadIdx.x; i < 96; i += 256) sTemb[i] = temb[i];
    __syncthreads();

    const int kb = (lane >> 4) * 8, nb = lane & 15;
    f16x8 bz[2];
    #pragma unroll
    for (int t = 0; t < 2; t++)
        #pragma unroll
        for (int j = 0; j < 8; j++) {
            int k = kb + j;
            bz[t][j] = (k < 8) ? (_Float16)Wr1[k * FDIM + t * 16 + nb] : (_Float16)0.0f;
        }
    f16x8 bf[4];
    #pragma unroll
    for (int t = 0; t < 4; t++)
        #pragma unroll
        for (int j = 0; j < 8; j++)
            bf[t][j] = (_Float16)Wr2[(kb + j) * 64 + t * 16 + nb];

    // ---- phase 0: lane-parallel geometry + basis (lanes 0..31) ----
    if (lane < 32) {
        const int ed = l32;
        const int p = gbase + ed;
        const bool vld = (p < E);
        int2 sd = vld ? order_sd[p] : make_int2(0, 0);
        float rx = (pos[sd.y * 3 + 0] - pos[sd.x * 3 + 0]) * NM2A_C;
        float ry = (pos[sd.y * 3 + 1] - pos[sd.x * 3 + 1]) * NM2A_C;
        float rz = (pos[sd.y * 3 + 2] - pos[sd.x * 3 + 2]) * NM2A_C;
        float r2 = rx * rx + ry * ry + rz * rz + 1e-12f;
        float r = sqrtf(r2);
        float rinv = 1.0f / r;
        float x = r * (1.0f / RCUT_C);
        float x2 = x * x, x4 = x2 * x2, x6 = x4 * x2, x7 = x6 * x, x8 = x6 * x2;
        float env = (x < 1.0f) ? (1.0f - 28.0f * x6 + 48.0f * x7 - 21.0f * x8) : 0.0f;

        float th = PI_F * x, s1, c1;
        __sincosf(th, &s1, &c1);
        float sp = 0.0f, sn = s1;
        _Float16 av[8];
        #pragma unroll
        for (int n = 0; n < NBASIS; n++) {
            av[n] = (_Float16)(sn * rinv);
            float snx = 2.0f * c1 * sn - sp; sp = sn; sn = snx;
        }
        _Float16* dstA = &sR[w][(ed < 16 ? 0 : 640) + (ed & 15) * QP];
        *(f16x8*)&dstA[0] = *(f16x8*)&av[0];
        *(float4*)&dstA[8]  = make_float4(0.f, 0.f, 0.f, 0.f);
        *(float4*)&dstA[16] = make_float4(0.f, 0.f, 0.f, 0.f);
        *(float4*)&dstA[24] = make_float4(0.f, 0.f, 0.f, 0.f);
        sSt[w][ed][0] = env;
        sSt[w][ed][1] = rx * rinv;
        sSt[w][ed][2] = ry * rinv;
        sSt[w][ed][3] = rz * rinv;
        sTy[w][ed] = types[sd.x];
        sKey[w][ed] = vld ? sd.y : -1;
    }

    // ---- phase 1: MFMA basis layer -> z, silu -> Q (both tiles) ----
    {
        const int me = lane & 15;
        f16x8 a1a = *(const f16x8*)&sR[w][me * QP + kb];
        f16x8 a1b = *(const f16x8*)&sR[w][640 + me * QP + kb];
        const f32x4 z4 = {0.f, 0.f, 0.f, 0.f};
        f32x4 Dz0a = __builtin_amdgcn_mfma_f32_16x16x32_f16(a1a, bz[0], z4, 0, 0, 0);
        f32x4 Dz1a = __builtin_amdgcn_mfma_f32_16x16x32_f16(a1a, bz[1], z4, 0, 0, 0);
        f32x4 Dz0b = __builtin_amdgcn_mfma_f32_16x16x32_f16(a1b, bz[0], z4, 0, 0, 0);
        f32x4 Dz1b = __builtin_amdgcn_mfma_f32_16x16x32_f16(a1b, bz[1], z4, 0, 0, 0);
        const int f0 = lane & 15, e0 = (lane >> 4) * 4;
        const float bb0 = br1[f0], bb1 = br1[16 + f0];
        #pragma unroll
        for (int t = 0; t < 2; t++) {
            f32x4 Dza = t ? Dz1a : Dz0a;
            f32x4 Dzb = t ? Dz1b : Dz0b;
            float bb = t ? bb1 : bb0;
            #pragma unroll
            for (int r = 0; r < 4; r++) {
                float za = Dza[r] + bb;
                float zb = Dzb[r] + bb;
                sR[w][1280 + (e0 + r) * QP + t * 16 + f0] = (_Float16)(za * sigmoidf_(za));
                sR[w][1920 + (e0 + r) * QP + t * 16 + f0] = (_Float16)(zb * sigmoidf_(zb));
            }
        }
    }

    // ---- phase 2: MFMA W2; fold hs*env; pack (ch, ch+32) pairs; D[edge*32+ch] ----
    {
        const int me = lane & 15;
        f16x8 aqa = *(const f16x8*)&sR[w][1280 + me * QP + kb];
        f16x8 aqb = *(const f16x8*)&sR[w][1920 + me * QP + kb];
        const int cb = lane & 15, e0 = (lane >> 4) * 4;
        float hev[2][2][4];   // [tile][fpair][r] = hs(ch)*env
        #pragma unroll
        for (int tl = 0; tl < 2; tl++)
            #pragma unroll
            for (int fp = 0; fp < 2; fp++)
                #pragma unroll
                for (int r = 0; r < 4; r++) {
                    int ed = tl * 16 + e0 + r;
                    hev[tl][fp][r] = sTemb[sTy[w][ed] * 32 + fp * 16 + cb] * sSt[w][ed][0];
                }
        const f32x4 z4 = {0.f, 0.f, 0.f, 0.f};
        unsigned int* DU = (unsigned int*)&sR[w][0];
        #pragma unroll
        for (int fp = 0; fp < 2; fp++) {
            f32x4 a0 = __builtin_amdgcn_mfma_f32_16x16x32_f16(aqa, bf[fp],     z4, 0, 0, 0);
            f32x4 a1 = __builtin_amdgcn_mfma_f32_16x16x32_f16(aqa, bf[fp + 2], z4, 0, 0, 0);
            f32x4 b0 = __builtin_amdgcn_mfma_f32_16x16x32_f16(aqb, bf[fp],     z4, 0, 0, 0);
            f32x4 b1 = __builtin_amdgcn_mfma_f32_16x16x32_f16(aqb, bf[fp + 2], z4, 0, 0, 0);
            #pragma unroll
            for (int r = 0; r < 4; r++) {
                float ha = hev[0][fp][r], hb = hev[1][fp][r];
                DU[(e0 + r) * 32 + fp * 16 + cb]        = pk2_(a0[r] * ha, a1[r] * ha);
                DU[(16 + e0 + r) * 32 + fp * 16 + cb]   = pk2_(b0[r] * hb, b1[r] * hb);
            }
        }
    }

    // ---- phase 3: epilogue, run-merge carried across both tiles (keys from LDS) ----
    const unsigned int* DU = (const unsigned int*)&sR[w][0];
    int runKey = -1;
    float sAcc = 0.f, vXA = 0.f, vYA = 0.f, vZA = 0.f;
    #pragma unroll
    for (int t = 0; t < 2; t++) {
        #pragma unroll
        for (int i = 0; i < 8; i++) {
            const int m = t * 16 + hw * 8 + i;
            const int p = gbase + m;
            if (p >= E) break;
            int k = sKey[w][m];
            if (k != runKey) {
                if (runKey >= 0) {
                    unsafeAtomicAdd(&s_acc[(size_t)runKey * 32 + l32], sAcc);
                    unsafeAtomicAdd(&v_acc[(size_t)runKey * 96 + 0 * 32 + l32], vXA);
                    unsafeAtomicAdd(&v_acc[(size_t)runKey * 96 + 1 * 32 + l32], vYA);
                    unsafeAtomicAdd(&v_acc[(size_t)runKey * 96 + 2 * 32 + l32], vZA);
                }
                runKey = k;
                sAcc = vXA = vYA = vZA = 0.f;
            }
            unsigned int qp = DU[m * 32 + l32];
            float s0 = lo16_(qp);       // hs*env*rw0
            float h1 = hi16_(qp);       // hs*env*rw1
            sAcc += s0;
            vXA += h1 * sSt[w][m][1];
            vYA += h1 * sSt[w][m][2];
            vZA += h1 * sSt[w][m][3];
        }
    }
    if (runKey >= 0) {
        unsafeAtomicAdd(&s_acc[(size_t)runKey * 32 + l32], sAcc);
        unsafeAtomicAdd(&v_acc[(size_t)runKey * 96 + 0 * 32 + l32], vXA);
        unsafeAtomicAdd(&v_acc[(size_t)runKey * 96 + 1 * 32 + l32], vYA);
        unsafeAtomicAdd(&v_acc[(size_t)runKey * 96 + 2 * 32 + l32], vZA);
    }
}

// -------- atom MLP: 64 atoms/block; packed g_all writes; energy fused (atomic) --------
__global__ __launch_bounds__(256) void atom_mlp(
    const int* __restrict__ types, const float* __restrict__ temb,
    const float* __restrict__ Wself, const float* __restrict__ Wo1,
    const float* __restrict__ bo1, const float* __restrict__ Wo2,
    const float* __restrict__ s_acc, const float* __restrict__ v_acc,
    float* __restrict__ g_all, float* __restrict__ out, int N)
{
    __shared__ float sWs[FDIM * FDIM], sWsT[FDIM * FDIM];
    __shared__ float sWo1[2 * FDIM * FDIM], sWo1T[2 * FDIM * FDIM];
    __shared__ float sb[FDIM], sW2o[FDIM], sTE[96];
    __shared__ float gred[8];
    for (int i = threadIdx.x; i < FDIM * FDIM; i += 256) {
        sWs[i] = Wself[i];
        sWsT[i] = Wself[(i & 31) * FDIM + (i >> 5)];
    }
    for (int i = threadIdx.x; i < 2 * FDIM * FDIM; i += 256) {
        sWo1[i] = Wo1[i];
        sWo1T[i] = Wo1[(i & 63) * FDIM + (i >> 6)];
    }
    for (int i = threadIdx.x; i < FDIM; i += 256) { sb[i] = bo1[i]; sW2o[i] = Wo2[i]; }
    for (int i = threadIdx.x; i < 96; i += 256) sTE[i] = temb[i];
    __syncthreads();

    const int lane = threadIdx.x & 31;
    const int g = threadIdx.x >> 5;
    float eAcc = 0.0f;

    for (int it = 0; it < 8; it++) {
        int a = blockIdx.x * 64 + it * 8 + g;
        const bool valid = (a < N);
        if (!valid) a = 0;

        float sv = s_acc[(size_t)a * FDIM + lane];
        float vx = v_acc[(size_t)a * 96 + 0 * 32 + lane];
        float vy = v_acc[(size_t)a * 96 + 1 * 32 + lane];
        float vz = v_acc[(size_t)a * 96 + 2 * 32 + lane];
        float h = sTE[types[a] * FDIM + lane];
        float vn = sqrtf(vx * vx + vy * vy + vz * vz + 1e-12f);

        float row = h;
        #pragma unroll
        for (int f = 0; f < FDIM; f++) {
            float t = __shfl(sv, f, 32);
            row += t * sWs[f * FDIM + lane];
        }
        float u = sb[lane];
        #pragma unroll
        for (int j = 0; j < FDIM; j++) {
            float rv = __shfl(row, j, 32);
            float vv = __shfl(vn, j, 32);
            u += rv * sWo1[j * FDIM + lane] + vv * sWo1[(j + FDIM) * FDIM + lane];
        }
        float sg = sigmoidf_(u);
        float au = u * sg;
        float pa = valid ? au * sW2o[lane] : 0.0f;
        #pragma unroll
        for (int m = 16; m; m >>= 1) pa += __shfl_xor(pa, m, 32);
        if (lane == 0) eAcc += pa;

        float gu = sW2o[lane] * (sg * (1.0f + u * (1.0f - sg)));
        float gfr = 0.0f, gfv = 0.0f;
        #pragma unroll
        for (int k = 0; k < FDIM; k++) {
            float gv_ = __shfl(gu, k, 32);
            gfr += gv_ * sWo1T[k * 64 + lane];
            gfv += gv_ * sWo1T[k * 64 + 32 + lane];
        }
        float gs = 0.0f;
        #pragma unroll
        for (int k = 0; k < FDIM; k++) {
            float gr = __shfl(gfr, k, 32);
            gs += gr * sWsT[k * FDIM + lane];
        }
        if (valid) {
            float sc = gfv / vn;
            *(float4*)&g_all[(size_t)a * 128 + lane * 4] =
                make_float4(gs, sc * vx, sc * vy, sc * vz);
        }
    }
    if (lane == 0) gred[g] = eAcc;
    __syncthreads();
    if (threadIdx.x == 0) {
        float t = 0.0f;
        #pragma unroll
        for (int i = 0; i < 8; i++) t += gred[i];
        unsafeAtomicAdd(out, t * EV2KJ_C);
    }
}

// ---------------- edge backward: single tile/wave (16 edges), 4-lanes-per-edge epilogue ----------------
// LDS per wave (f16): sR1[1280] = A[0,640) | T[640,1280); Dq (uint[512]) overlays [0,1024).
//                     sR2[1024] = Q[0,640); Dt (uint[512]) overlays [0,1024).
__global__ __launch_bounds__(256) void edge_bwd_mfma(
    const float* __restrict__ pos, const int* __restrict__ types,
    const int2* __restrict__ order_sd,
    const float* __restrict__ Wr1, const float* __restrict__ br1,
    const float* __restrict__ Wr2, const float* __restrict__ temb,
    const float* __restrict__ g_all,
    float* __restrict__ forces, int E)
{
    __shared__ __align__(16) _Float16 sR1[4][1280];
    __shared__ __align__(16) _Float16 sR2[4][1024];
    __shared__ int   sTy[4][16];
    __shared__ float sTemb[96];

    const int lane = threadIdx.x & 63;
    const int l16 = lane & 15;
    const int w = threadIdx.x >> 6;
    const int gbase = blockIdx.x * 64 + w * 16;

    for (int i = threadIdx.x; i < 96; i += 256) sTemb[i] = temb[i];
    __syncthreads();

    const int kb = (lane >> 4) * 8, nb = lane & 15;
    f16x8 bz[2], bt[2];
    #pragma unroll
    for (int t = 0; t < 2; t++)
        #pragma unroll
        for (int j = 0; j < 8; j++) {
            int k = kb + j;
            bz[t][j] = (k < 8) ? (_Float16)Wr1[k * FDIM + t * 16 + nb] : (_Float16)0.0f;
            bt[t][j] = (k >= 8 && k < 16) ? (_Float16)Wr1[(k - 8) * FDIM + t * 16 + nb] : (_Float16)0.0f;
        }
    f16x8 bf[4];
    #pragma unroll
    for (int t = 0; t < 4; t++)
        #pragma unroll
        for (int j = 0; j < 8; j++)
            bf[t][j] = (_Float16)Wr2[(kb + j) * 64 + t * 16 + nb];

    // ---- phase 0: edge descriptors for ALL lanes (4 lanes mirror each edge) ----
    const int p_e = gbase + l16;
    const bool valid = (p_e < E);
    int2 sd = valid ? order_sd[p_e] : make_int2(0, 0);
    const int srcI = sd.x, dstI = sd.y;
    const int key = valid ? sd.y : (-2 - l16);

    float rinv = 1.f, env = 0.f, denv = 0.f, rhx = 0.f, rhy = 0.f, rhz = 0.f;
    if (lane < 16) {
        float rx = (pos[sd.y * 3 + 0] - pos[sd.x * 3 + 0]) * NM2A_C;
        float ry = (pos[sd.y * 3 + 1] - pos[sd.x * 3 + 1]) * NM2A_C;
        float rz = (pos[sd.y * 3 + 2] - pos[sd.x * 3 + 2]) * NM2A_C;
        float r2 = rx * rx + ry * ry + rz * rz + 1e-12f;
        float r = sqrtf(r2);
        rinv = 1.0f / r;
        float x = r * (1.0f / RCUT_C);
        float x2 = x * x, x4 = x2 * x2, x5 = x4 * x, x6 = x4 * x2, x7 = x6 * x, x8 = x6 * x2;
        env = (x < 1.0f) ? (1.0f - 28.0f * x6 + 48.0f * x7 - 21.0f * x8) : 0.0f;
        denv = (x < 1.0f) ? (-168.0f * x5 + 336.0f * x6 - 168.0f * x7) * (1.0f / RCUT_C) : 0.0f;
        rhx = rx * rinv; rhy = ry * rinv; rhz = rz * rinv;

        float th = PI_F * x, s1, c1;
        __sincosf(th, &s1, &c1);
        float sp = 0.0f, sn = s1, cp = 1.0f, cn = c1;
        _Float16 av[16];
        #pragma unroll
        for (int n = 0; n < NBASIS; n++) {
            float basis = sn * rinv;
            float dbdr = (PI_F * (float)(n + 1) * (1.0f / RCUT_C)) * cn * rinv - basis * rinv;
            av[n] = (_Float16)basis;
            av[8 + n] = (_Float16)dbdr;
            float snx = 2.0f * c1 * sn - sp; sp = sn; sn = snx;
            float cnx = 2.0f * c1 * cn - cp; cp = cn; cn = cnx;
        }
        _Float16* dstA = &sR1[w][l16 * QP];
        *(f16x8*)&dstA[0] = *(f16x8*)&av[0];
        *(f16x8*)&dstA[8] = *(f16x8*)&av[8];
        *(float4*)&dstA[16] = make_float4(0.f, 0.f, 0.f, 0.f);
        *(float4*)&dstA[24] = make_float4(0.f, 0.f, 0.f, 0.f);
        sTy[w][l16] = types[sd.x];
    }

    // ---- phase 1: 4 MFMAs (z, tacc over 2 ch-tiles); silu/tf -> Q (sR2) / T (sR1 upper) ----
    {
        const int me = lane & 15;
        f16x8 a1 = *(const f16x8*)&sR1[w][me * QP + kb];
        const f32x4 z4 = {0.f, 0.f, 0.f, 0.f};
        f32x4 Dz0 = __builtin_amdgcn_mfma_f32_16x16x32_f16(a1, bz[0], z4, 0, 0, 0);
        f32x4 Dz1 = __builtin_amdgcn_mfma_f32_16x16x32_f16(a1, bz[1], z4, 0, 0, 0);
        f32x4 Dt0 = __builtin_amdgcn_mfma_f32_16x16x32_f16(a1, bt[0], z4, 0, 0, 0);
        f32x4 Dt1 = __builtin_amdgcn_mfma_f32_16x16x32_f16(a1, bt[1], z4, 0, 0, 0);
        const int f0 = lane & 15, e0 = (lane >> 4) * 4;
        const float bb0 = br1[f0], bb1 = br1[16 + f0];
        #pragma unroll
        for (int t = 0; t < 2; t++) {
            f32x4 Dz = t ? Dz1 : Dz0;
            f32x4 Dt = t ? Dt1 : Dt0;
            float bb = t ? bb1 : bb0;
            #pragma unroll
            for (int r = 0; r < 4; r++) {
                float z = Dz[r] + bb;
                float sg = sigmoidf_(z);
                sR2[w][(e0 + r) * QP + t * 16 + f0] = (_Float16)(z * sg);
                sR1[w][640 + (e0 + r) * QP + t * 16 + f0] =
                    (_Float16)((sg * (1.0f + z * (1.0f - sg))) * Dt[r]);
            }
        }
    }

    // ---- phase 2: 8 MFMAs; fold hs; pack (x, x+32) channel pairs ----
    {
        const int me = lane & 15;
        f16x8 aq = *(const f16x8*)&sR2[w][me * QP + kb];
        f16x8 at = *(const f16x8*)&sR1[w][640 + me * QP + kb];
        const int cb = lane & 15, e0 = (lane >> 4) * 4;
        float hsv[2][4];   // [fpair][r]
        #pragma unroll
        for (int r = 0; r < 4; r++) {
            int ty = sTy[w][e0 + r];
            hsv[0][r] = sTemb[ty * 32 + cb];
            hsv[1][r] = sTemb[ty * 32 + 16 + cb];
        }
        const f32x4 z4 = {0.f, 0.f, 0.f, 0.f};
        unsigned int* DqU = (unsigned int*)&sR1[w][0];
        unsigned int* DtU = (unsigned int*)&sR2[w][0];
        #pragma unroll
        for (int fp = 0; fp < 2; fp++) {
            f32x4 q0 = __builtin_amdgcn_mfma_f32_16x16x32_f16(aq, bf[fp],     z4, 0, 0, 0);
            f32x4 q1 = __builtin_amdgcn_mfma_f32_16x16x32_f16(aq, bf[fp + 2], z4, 0, 0, 0);
            f32x4 t0 = __builtin_amdgcn_mfma_f32_16x16x32_f16(at, bf[fp],     z4, 0, 0, 0);
            f32x4 t1 = __builtin_amdgcn_mfma_f32_16x16x32_f16(at, bf[fp + 2], z4, 0, 0, 0);
            unsigned int pq[4], pt[4];
            #pragma unroll
            for (int r = 0; r < 4; r++) {
                float h = hsv[fp][r];
                pq[r] = pk2_(q0[r] * h, q1[r] * h);
                pt[r] = pk2_(t0[r] * h, t1[r] * h);
            }
            const int f = fp * 16 + cb;
            *(uint4*)&DqU[f * 16 + e0] = make_uint4(pq[0], pq[1], pq[2], pq[3]);
            *(uint4*)&DtU[f * 16 + e0] = make_uint4(pt[0], pt[1], pt[2], pt[3]);
        }
    }

    // ---- phase 3: epilogue; 4 lanes per edge (f split in 4), 2-step reduce ----
    {
        const unsigned int* DqU = (const unsigned int*)&sR1[w][0];
        const unsigned int* DtU = (const unsigned int*)&sR2[w][0];
        const int fb = (lane >> 4) * 8;     // f-group: 0..7, 8..15, 16..23, 24..31
        const float* gb = g_all + (size_t)dstI * 128;
        float Aa = 0.f, Bb = 0.f, Cc = 0.f, Pp = 0.f;
        float Ap = 0.f, Bp = 0.f, Cp = 0.f, Qq = 0.f;
        #pragma unroll
        for (int ff = 0; ff < 8; ff++) {
            const int f = fb + ff;
            unsigned int qp = DqU[f * 16 + l16];
            unsigned int tp = DtU[f * 16 + l16];
            float rw0 = lo16_(qp), rw1 = hi16_(qp);
            float u0 = lo16_(tp), u1 = hi16_(tp);
            float4 g4 = *(const float4*)(gb + f * 4);
            Pp += rw0 * g4.x; Qq += u0 * g4.x;
            Aa += rw1 * g4.y; Bb += rw1 * g4.z; Cc += rw1 * g4.w;
            Ap += u1 * g4.y;  Bp += u1 * g4.z;  Cp += u1 * g4.w;
        }
        // reduce across the 4 f-groups (lane bits 4 and 5)
        Pp += __shfl_xor(Pp, 16, 64); Qq += __shfl_xor(Qq, 16, 64);
        Aa += __shfl_xor(Aa, 16, 64); Bb += __shfl_xor(Bb, 16, 64);
        Cc += __shfl_xor(Cc, 16, 64); Ap += __shfl_xor(Ap, 16, 64);
        Bp += __shfl_xor(Bp, 16, 64); Cp += __shfl_xor(Cp, 16, 64);
        Pp += __shfl_xor(Pp, 32, 64); Qq += __shfl_xor(Qq, 32, 64);
        Aa += __shfl_xor(Aa, 32, 64); Bb += __shfl_xor(Bb, 32, 64);
        Cc += __shfl_xor(Cc, 32, 64); Ap += __shfl_xor(Ap, 32, 64);
        Bp += __shfl_xor(Bp, 32, 64); Cp += __shfl_xor(Cp, 32, 64);

        if (lane < 16) {
            float Gx = env * Aa, Gy = env * Bb, Gz = env * Cc;
            float genv = Pp + rhx * Aa + rhy * Bb + rhz * Cc;
            float pc = env * (Qq + rhx * Ap + rhy * Bp + rhz * Cp) + genv * denv;
            float dotg = Gx * rhx + Gy * rhy + Gz * rhz;
            float cx = pc * rhx + (Gx - dotg * rhx) * rinv;
            float cy = pc * rhy + (Gy - dotg * rhy) * rinv;
            float cz = pc * rhz + (Gz - dotg * rhz) * rinv;

            const float SC = EV2KJ_C * NM2A_C;
            if (valid) {
                unsafeAtomicAdd(&forces[(size_t)srcI * 3 + 0], SC * cx);
                unsafeAtomicAdd(&forces[(size_t)srcI * 3 + 1], SC * cy);
                unsafeAtomicAdd(&forces[(size_t)srcI * 3 + 2], SC * cz);
            }
            // segmented inclusive scan over contiguous dst runs (16 edges)
            int kk = key;
            #pragma unroll
            for (int d = 1; d < 16; d <<= 1) {
                float ux = __shfl_up(cx, d, 32);
                float uy = __shfl_up(cy, d, 32);
                float uz = __shfl_up(cz, d, 32);
                int uk = __shfl_up(kk, d, 32);
                if (l16 >= d && uk == kk) { cx += ux; cy += uy; cz += uz; }
            }
            int nk = __shfl_down(kk, 1, 32);
            bool leader = (l16 == 15) || (nk != kk);
            if (valid && leader) {
                unsafeAtomicAdd(&forces[(size_t)dstI * 3 + 0], -SC * cx);
                unsafeAtomicAdd(&forces[(size_t)dstI * 3 + 1], -SC * cy);
                unsafeAtomicAdd(&forces[(size_t)dstI * 3 + 2], -SC * cz);
            }
        }
    }
}

// ---------------- reductions & correction ----------------
__global__ __launch_bounds__(256) void reduce_net(
    const float* __restrict__ f, const float* __restrict__ masses,
    float* __restrict__ accum, int N)
{
    float nx = 0, ny = 0, nz = 0, ms = 0;
    for (int i = blockIdx.x * 256 + threadIdx.x; i < N; i += gridDim.x * 256) {
        nx += f[i * 3 + 0]; ny += f[i * 3 + 1]; nz += f[i * 3 + 2]; ms += masses[i];
    }
    #pragma unroll
    for (int m = 32; m; m >>= 1) {
        nx += __shfl_xor(nx, m, 64);
        ny += __shfl_xor(ny, m, 64);
        nz += __shfl_xor(nz, m, 64);
        ms += __shfl_xor(ms, m, 64);
    }
    __shared__ float red[4][4];
    int w = threadIdx.x >> 6;
    if ((threadIdx.x & 63) == 0) { red[w][0] = nx; red[w][1] = ny; red[w][2] = nz; red[w][3] = ms; }
    __syncthreads();
    if (threadIdx.x == 0) {
        float a0 = 0, a1 = 0, a2 = 0, a3 = 0;
        for (int i = 0; i < 4; i++) { a0 += red[i][0]; a1 += red[i][1]; a2 += red[i][2]; a3 += red[i][3]; }
        unsafeAtomicAdd(accum + 0, a0);
        unsafeAtomicAdd(accum + 1, a1);
        unsafeAtomicAdd(accum + 2, a2);
        unsafeAtomicAdd(accum + 3, a3);
    }
}

__global__ __launch_bounds__(256) void correct_forces(
    float* __restrict__ f, const float* __restrict__ masses,
    const float* __restrict__ accum, int N)
{
    int i = blockIdx.x * 256 + threadIdx.x;
    if (i < N) {
        float c = masses[i] / accum[3];
        f[i * 3 + 0] -= c * accum[0];
        f[i * 3 + 1] -= c * accum[1];
        f[i * 3 + 2] -= c * accum[2];
    }
}

extern "C" void kernel_launch(void* const* d_in, const int* in_sizes, int n_in,
                              void* d_out, int out_size, void* d_ws, size_t ws_size,
                              hipStream_t stream)
{
    (void)n_in; (void)ws_size;
    const float* pos    = (const float*)d_in[0];
    const float* masses = (const float*)d_in[1];
    const float* temb   = (const float*)d_in[2];
    const float* Wr1    = (const float*)d_in[3];
    const float* br1    = (const float*)d_in[4];
    const float* Wr2    = (const float*)d_in[5];
    const float* Wself  = (const float*)d_in[6];
    const float* Wo1    = (const float*)d_in[7];
    const float* bo1    = (const float*)d_in[8];
    const float* Wo2    = (const float*)d_in[9];
    const int* types    = (const int*)d_in[10];
    const int* eidx     = (const int*)d_in[11];
    const int N = in_sizes[1];
    const int E = in_sizes[11] / 2;

    float* out = (float*)d_out;
    float* forces = out + 1;

    float* ws = (float*)d_ws;
    float* s_acc = ws;                               // N*32
    float* v_acc = s_acc + (size_t)N * FDIM;         // N*96
    float* g_all = v_acc + (size_t)N * 96;           // N*128 (packed gradients)
    float* accum = g_all + (size_t)N * 128;          // 4
    int* counts = (int*)(accum + 4);                 // N
    int* cursor = counts + N;                        // N
    int2* order_sd = (int2*)(cursor + N);            // E int2
    int nScan = (N + SCH - 1) / SCH;
    int* bsum = (int*)(order_sd + E);                // nScan

    hipMemsetAsync(d_out, 0, (size_t)out_size * sizeof(float), stream);
    hipMemsetAsync(s_acc, 0, (size_t)N * 128 * sizeof(float), stream);
    hipMemsetAsync(counts, 0, (size_t)N * sizeof(int), stream);
    hipMemsetAsync(accum, 0, 4 * sizeof(float), stream);

    hist_dst<<<2048, 256, 0, stream>>>(eidx, counts, E);
    scan_partial<<<nScan, 256, 0, stream>>>(counts, bsum, N);
    scan_bsum<<<1, 64, 0, stream>>>(bsum, nScan);
    scan_write<<<nScan, 256, 0, stream>>>(counts, bsum, cursor, N);
    scatter_edges<<<2048, 256, 0, stream>>>(eidx, cursor, order_sd, E);

    int nAtomBlocks = (N + 63) / 64;
    int nFwdBlocks = (E + 127) / 128;
    int nBwdBlocks = (E + 63) / 64;
    edge_fwd_mfma<<<nFwdBlocks, 256, 0, stream>>>(pos, types, order_sd,
                                                  Wr1, br1, Wr2, temb,
                                                  s_acc, v_acc, E);
    atom_mlp<<<nAtomBlocks, 256, 0, stream>>>(types, temb, Wself, Wo1, bo1, Wo2,
                                              s_acc, v_acc, g_all, out, N);
    edge_bwd_mfma<<<nBwdBlocks, 256, 0, stream>>>(pos, types, order_sd,
                                                  Wr1, br1, Wr2, temb,
                                                  g_all, forces, E);
    reduce_net<<<64, 256, 0, stream>>>(forces, masses, accum, N);
    correct_forces<<<(N + 255) / 256, 256, 0, stream>>>(forces, masses, accum, N);
}

// Round 18
// 540.942 us; speedup vs baseline: 1.2863x; 1.0121x over previous
//
#include <hip/hip_runtime.h>
#include <math.h>

#define FDIM 32
#define NBASIS 8
#define QP 40     // A-stage row pad (f16 units) -> 80B rows, 16B-aligned quads
#define DS 18     // bwd D-stage stride (uints): (8*DS)%32=16 -> 2-way bank aliasing (free)
#define SCH 4096  // scan chunk per block (256 thr x 16)

constexpr float RCUT_C = 20.0f;
constexpr float PI_F = 3.14159265358979323846f;
constexpr float EV2KJ_C = 96.4853f;
constexpr float NM2A_C = 10.0f;

typedef _Float16 f16x8 __attribute__((ext_vector_type(8)));
typedef _Float16 f16x4 __attribute__((ext_vector_type(4)));
typedef float f32x4 __attribute__((ext_vector_type(4)));

__device__ __forceinline__ float sigmoidf_(float z) { return 1.0f / (1.0f + __expf(-z)); }

__device__ __forceinline__ unsigned int pk2_(float a, float b) {
    unsigned short lo = __builtin_bit_cast(unsigned short, (_Float16)a);
    unsigned short hi = __builtin_bit_cast(unsigned short, (_Float16)b);
    return (unsigned int)lo | ((unsigned int)hi << 16);
}
__device__ __forceinline__ float lo16_(unsigned int v) {
    return (float)__builtin_bit_cast(_Float16, (unsigned short)(v & 0xffffu));
}
__device__ __forceinline__ float hi16_(unsigned int v) {
    return (float)__builtin_bit_cast(_Float16, (unsigned short)(v >> 16));
}

// ---------------- CSR build: histogram, 3-kernel scan, scatter ----------------
__global__ __launch_bounds__(256) void hist_dst(
    const int* __restrict__ eidx, int* __restrict__ counts, int E)
{
    for (int e = blockIdx.x * 256 + threadIdx.x; e < E; e += gridDim.x * 256)
        atomicAdd(&counts[eidx[E + e]], 1);
}

__global__ __launch_bounds__(256) void scan_partial(
    const int* __restrict__ counts, int* __restrict__ bsum, int N)
{
    __shared__ int red[256];
    const int t = threadIdx.x;
    const int st = blockIdx.x * SCH + t * 16;
    int s = 0;
    #pragma unroll
    for (int i = 0; i < 16; i++) { int idx = st + i; if (idx < N) s += counts[idx]; }
    red[t] = s;
    __syncthreads();
    for (int k = 128; k; k >>= 1) {
        if (t < k) red[t] += red[t + k];
        __syncthreads();
    }
    if (t == 0) bsum[blockIdx.x] = red[0];
}

__global__ __launch_bounds__(64) void scan_bsum(int* __restrict__ bsum, int nb)
{
    if (threadIdx.x == 0) {
        int run = 0;
        for (int i = 0; i < nb; i++) { int v = bsum[i]; bsum[i] = run; run += v; }
    }
}

__global__ __launch_bounds__(256) void scan_write(
    const int* __restrict__ counts, const int* __restrict__ bsum,
    int* __restrict__ cursor, int N)
{
    __shared__ int lds[256];
    const int t = threadIdx.x;
    const int st = blockIdx.x * SCH + t * 16;
    int vals[16];
    int s = 0;
    #pragma unroll
    for (int i = 0; i < 16; i++) {
        int idx = st + i;
        int v = (idx < N) ? counts[idx] : 0;
        vals[i] = v; s += v;
    }
    lds[t] = s;
    __syncthreads();
    for (int off = 1; off < 256; off <<= 1) {
        int v = (t >= off) ? lds[t - off] : 0;
        __syncthreads();
        lds[t] += v;
        __syncthreads();
    }
    int run = bsum[blockIdx.x] + lds[t] - s;   // exclusive prefix
    #pragma unroll
    for (int i = 0; i < 16; i++) {
        int idx = st + i;
        if (idx < N) cursor[idx] = run;
        run += vals[i];
    }
}

__global__ __launch_bounds__(256) void scatter_edges(
    const int* __restrict__ eidx, int* __restrict__ cursor,
    int2* __restrict__ order_sd, int E)
{
    for (int e = blockIdx.x * 256 + threadIdx.x; e < E; e += gridDim.x * 256) {
        int dst = eidx[E + e];
        int p = atomicAdd(&cursor[dst], 1);
        order_sd[p] = make_int2(eidx[e], dst);
    }
}

// ---------------- edge forward: hs*env folded into packed D; LDS-stashed keys (r16 form) ----------------
__global__ __launch_bounds__(256) void edge_fwd_mfma(
    const float* __restrict__ pos, const int* __restrict__ types,
    const int2* __restrict__ order_sd,
    const float* __restrict__ Wr1, const float* __restrict__ br1,
    const float* __restrict__ Wr2, const float* __restrict__ temb,
    float* __restrict__ s_acc, float* __restrict__ v_acc, int E)
{
    __shared__ __align__(16) _Float16 sR[4][2560];
    __shared__ float sSt[4][32][4];         // env, rhx, rhy, rhz
    __shared__ int sTy[4][32];
    __shared__ int sKey[4][32];
    __shared__ float sTemb[96];

    const int lane = threadIdx.x & 63;
    const int l32 = threadIdx.x & 31;
    const int hw = (threadIdx.x >> 5) & 1;
    const int w = threadIdx.x >> 6;
    const int gbase = blockIdx.x * 128 + w * 32;

    for (int i = threadIdx.x; i < 96; i += 256) sTemb[i] = temb[i];
    __syncthreads();

    const int kb = (lane >> 4) * 8, nb = lane & 15;
    f16x8 bz[2];
    #pragma unroll
    for (int t = 0; t < 2; t++)
        #pragma unroll
        for (int j = 0; j < 8; j++) {
            int k = kb + j;
            bz[t][j] = (k < 8) ? (_Float16)Wr1[k * FDIM + t * 16 + nb] : (_Float16)0.0f;
        }
    f16x8 bf[4];
    #pragma unroll
    for (int t = 0; t < 4; t++)
        #pragma unroll
        for (int j = 0; j < 8; j++)
            bf[t][j] = (_Float16)Wr2[(kb + j) * 64 + t * 16 + nb];

    // ---- phase 0: lane-parallel geometry + basis (lanes 0..31) ----
    if (lane < 32) {
        const int ed = l32;
        const int p = gbase + ed;
        const bool vld = (p < E);
        int2 sd = vld ? order_sd[p] : make_int2(0, 0);
        float rx = (pos[sd.y * 3 + 0] - pos[sd.x * 3 + 0]) * NM2A_C;
        float ry = (pos[sd.y * 3 + 1] - pos[sd.x * 3 + 1]) * NM2A_C;
        float rz = (pos[sd.y * 3 + 2] - pos[sd.x * 3 + 2]) * NM2A_C;
        float r2 = rx * rx + ry * ry + rz * rz + 1e-12f;
        float r = sqrtf(r2);
        float rinv = 1.0f / r;
        float x = r * (1.0f / RCUT_C);
        float x2 = x * x, x4 = x2 * x2, x6 = x4 * x2, x7 = x6 * x, x8 = x6 * x2;
        float env = (x < 1.0f) ? (1.0f - 28.0f * x6 + 48.0f * x7 - 21.0f * x8) : 0.0f;

        float th = PI_F * x, s1, c1;
        __sincosf(th, &s1, &c1);
        float sp = 0.0f, sn = s1;
        _Float16 av[8];
        #pragma unroll
        for (int n = 0; n < NBASIS; n++) {
            av[n] = (_Float16)(sn * rinv);
            float snx = 2.0f * c1 * sn - sp; sp = sn; sn = snx;
        }
        _Float16* dstA = &sR[w][(ed < 16 ? 0 : 640) + (ed & 15) * QP];
        *(f16x8*)&dstA[0] = *(f16x8*)&av[0];
        *(float4*)&dstA[8]  = make_float4(0.f, 0.f, 0.f, 0.f);
        *(float4*)&dstA[16] = make_float4(0.f, 0.f, 0.f, 0.f);
        *(float4*)&dstA[24] = make_float4(0.f, 0.f, 0.f, 0.f);
        sSt[w][ed][0] = env;
        sSt[w][ed][1] = rx * rinv;
        sSt[w][ed][2] = ry * rinv;
        sSt[w][ed][3] = rz * rinv;
        sTy[w][ed] = types[sd.x];
        sKey[w][ed] = vld ? sd.y : -1;
    }

    // ---- phase 1: MFMA basis layer -> z, silu -> Q (both tiles) ----
    {
        const int me = lane & 15;
        f16x8 a1a = *(const f16x8*)&sR[w][me * QP + kb];
        f16x8 a1b = *(const f16x8*)&sR[w][640 + me * QP + kb];
        const f32x4 z4 = {0.f, 0.f, 0.f, 0.f};
        f32x4 Dz0a = __builtin_amdgcn_mfma_f32_16x16x32_f16(a1a, bz[0], z4, 0, 0, 0);
        f32x4 Dz1a = __builtin_amdgcn_mfma_f32_16x16x32_f16(a1a, bz[1], z4, 0, 0, 0);
        f32x4 Dz0b = __builtin_amdgcn_mfma_f32_16x16x32_f16(a1b, bz[0], z4, 0, 0, 0);
        f32x4 Dz1b = __builtin_amdgcn_mfma_f32_16x16x32_f16(a1b, bz[1], z4, 0, 0, 0);
        const int f0 = lane & 15, e0 = (lane >> 4) * 4;
        const float bb0 = br1[f0], bb1 = br1[16 + f0];
        #pragma unroll
        for (int t = 0; t < 2; t++) {
            f32x4 Dza = t ? Dz1a : Dz0a;
            f32x4 Dzb = t ? Dz1b : Dz0b;
            float bb = t ? bb1 : bb0;
            #pragma unroll
            for (int r = 0; r < 4; r++) {
                float za = Dza[r] + bb;
                float zb = Dzb[r] + bb;
                sR[w][1280 + (e0 + r) * QP + t * 16 + f0] = (_Float16)(za * sigmoidf_(za));
                sR[w][1920 + (e0 + r) * QP + t * 16 + f0] = (_Float16)(zb * sigmoidf_(zb));
            }
        }
    }

    // ---- phase 2: MFMA W2; fold hs*env; pack (ch, ch+32) pairs; D[edge*32+ch] ----
    {
        const int me = lane & 15;
        f16x8 aqa = *(const f16x8*)&sR[w][1280 + me * QP + kb];
        f16x8 aqb = *(const f16x8*)&sR[w][1920 + me * QP + kb];
        const int cb = lane & 15, e0 = (lane >> 4) * 4;
        float hev[2][2][4];   // [tile][fpair][r] = hs(ch)*env
        #pragma unroll
        for (int tl = 0; tl < 2; tl++)
            #pragma unroll
            for (int fp = 0; fp < 2; fp++)
                #pragma unroll
                for (int r = 0; r < 4; r++) {
                    int ed = tl * 16 + e0 + r;
                    hev[tl][fp][r] = sTemb[sTy[w][ed] * 32 + fp * 16 + cb] * sSt[w][ed][0];
                }
        const f32x4 z4 = {0.f, 0.f, 0.f, 0.f};
        unsigned int* DU = (unsigned int*)&sR[w][0];
        #pragma unroll
        for (int fp = 0; fp < 2; fp++) {
            f32x4 a0 = __builtin_amdgcn_mfma_f32_16x16x32_f16(aqa, bf[fp],     z4, 0, 0, 0);
            f32x4 a1 = __builtin_amdgcn_mfma_f32_16x16x32_f16(aqa, bf[fp + 2], z4, 0, 0, 0);
            f32x4 b0 = __builtin_amdgcn_mfma_f32_16x16x32_f16(aqb, bf[fp],     z4, 0, 0, 0);
            f32x4 b1 = __builtin_amdgcn_mfma_f32_16x16x32_f16(aqb, bf[fp + 2], z4, 0, 0, 0);
            #pragma unroll
            for (int r = 0; r < 4; r++) {
                float ha = hev[0][fp][r], hb = hev[1][fp][r];
                DU[(e0 + r) * 32 + fp * 16 + cb]        = pk2_(a0[r] * ha, a1[r] * ha);
                DU[(16 + e0 + r) * 32 + fp * 16 + cb]   = pk2_(b0[r] * hb, b1[r] * hb);
            }
        }
    }

    // ---- phase 3: epilogue, run-merge carried across both tiles (keys from LDS) ----
    const unsigned int* DU = (const unsigned int*)&sR[w][0];
    int runKey = -1;
    float sAcc = 0.f, vXA = 0.f, vYA = 0.f, vZA = 0.f;
    #pragma unroll
    for (int t = 0; t < 2; t++) {
        #pragma unroll
        for (int i = 0; i < 8; i++) {
            const int m = t * 16 + hw * 8 + i;
            const int p = gbase + m;
            if (p >= E) break;
            int k = sKey[w][m];
            if (k != runKey) {
                if (runKey >= 0) {
                    unsafeAtomicAdd(&s_acc[(size_t)runKey * 32 + l32], sAcc);
                    unsafeAtomicAdd(&v_acc[(size_t)runKey * 96 + 0 * 32 + l32], vXA);
                    unsafeAtomicAdd(&v_acc[(size_t)runKey * 96 + 1 * 32 + l32], vYA);
                    unsafeAtomicAdd(&v_acc[(size_t)runKey * 96 + 2 * 32 + l32], vZA);
                }
                runKey = k;
                sAcc = vXA = vYA = vZA = 0.f;
            }
            unsigned int qp = DU[m * 32 + l32];
            float s0 = lo16_(qp);       // hs*env*rw0
            float h1 = hi16_(qp);       // hs*env*rw1
            sAcc += s0;
            vXA += h1 * sSt[w][m][1];
            vYA += h1 * sSt[w][m][2];
            vZA += h1 * sSt[w][m][3];
        }
    }
    if (runKey >= 0) {
        unsafeAtomicAdd(&s_acc[(size_t)runKey * 32 + l32], sAcc);
        unsafeAtomicAdd(&v_acc[(size_t)runKey * 96 + 0 * 32 + l32], vXA);
        unsafeAtomicAdd(&v_acc[(size_t)runKey * 96 + 1 * 32 + l32], vYA);
        unsafeAtomicAdd(&v_acc[(size_t)runKey * 96 + 2 * 32 + l32], vZA);
    }
}

// -------- atom MLP: 64 atoms/block; packed g_all writes; energy fused (atomic) --------
__global__ __launch_bounds__(256) void atom_mlp(
    const int* __restrict__ types, const float* __restrict__ temb,
    const float* __restrict__ Wself, const float* __restrict__ Wo1,
    const float* __restrict__ bo1, const float* __restrict__ Wo2,
    const float* __restrict__ s_acc, const float* __restrict__ v_acc,
    float* __restrict__ g_all, float* __restrict__ out, int N)
{
    __shared__ float sWs[FDIM * FDIM], sWsT[FDIM * FDIM];
    __shared__ float sWo1[2 * FDIM * FDIM], sWo1T[2 * FDIM * FDIM];
    __shared__ float sb[FDIM], sW2o[FDIM], sTE[96];
    __shared__ float gred[8];
    for (int i = threadIdx.x; i < FDIM * FDIM; i += 256) {
        sWs[i] = Wself[i];
        sWsT[i] = Wself[(i & 31) * FDIM + (i >> 5)];
    }
    for (int i = threadIdx.x; i < 2 * FDIM * FDIM; i += 256) {
        sWo1[i] = Wo1[i];
        sWo1T[i] = Wo1[(i & 63) * FDIM + (i >> 6)];
    }
    for (int i = threadIdx.x; i < FDIM; i += 256) { sb[i] = bo1[i]; sW2o[i] = Wo2[i]; }
    for (int i = threadIdx.x; i < 96; i += 256) sTE[i] = temb[i];
    __syncthreads();

    const int lane = threadIdx.x & 31;
    const int g = threadIdx.x >> 5;
    float eAcc = 0.0f;

    for (int it = 0; it < 8; it++) {
        int a = blockIdx.x * 64 + it * 8 + g;
        const bool valid = (a < N);
        if (!valid) a = 0;

        float sv = s_acc[(size_t)a * FDIM + lane];
        float vx = v_acc[(size_t)a * 96 + 0 * 32 + lane];
        float vy = v_acc[(size_t)a * 96 + 1 * 32 + lane];
        float vz = v_acc[(size_t)a * 96 + 2 * 32 + lane];
        float h = sTE[types[a] * FDIM + lane];
        float vn = sqrtf(vx * vx + vy * vy + vz * vz + 1e-12f);

        float row = h;
        #pragma unroll
        for (int f = 0; f < FDIM; f++) {
            float t = __shfl(sv, f, 32);
            row += t * sWs[f * FDIM + lane];
        }
        float u = sb[lane];
        #pragma unroll
        for (int j = 0; j < FDIM; j++) {
            float rv = __shfl(row, j, 32);
            float vv = __shfl(vn, j, 32);
            u += rv * sWo1[j * FDIM + lane] + vv * sWo1[(j + FDIM) * FDIM + lane];
        }
        float sg = sigmoidf_(u);
        float au = u * sg;
        float pa = valid ? au * sW2o[lane] : 0.0f;
        #pragma unroll
        for (int m = 16; m; m >>= 1) pa += __shfl_xor(pa, m, 32);
        if (lane == 0) eAcc += pa;

        float gu = sW2o[lane] * (sg * (1.0f + u * (1.0f - sg)));
        float gfr = 0.0f, gfv = 0.0f;
        #pragma unroll
        for (int k = 0; k < FDIM; k++) {
            float gv_ = __shfl(gu, k, 32);
            gfr += gv_ * sWo1T[k * 64 + lane];
            gfv += gv_ * sWo1T[k * 64 + 32 + lane];
        }
        float gs = 0.0f;
        #pragma unroll
        for (int k = 0; k < FDIM; k++) {
            float gr = __shfl(gfr, k, 32);
            gs += gr * sWsT[k * FDIM + lane];
        }
        if (valid) {
            float sc = gfv / vn;
            *(float4*)&g_all[(size_t)a * 128 + lane * 4] =
                make_float4(gs, sc * vx, sc * vy, sc * vz);
        }
    }
    if (lane == 0) gred[g] = eAcc;
    __syncthreads();
    if (threadIdx.x == 0) {
        float t = 0.0f;
        #pragma unroll
        for (int i = 0; i < 8; i++) t += gred[i];
        unsafeAtomicAdd(out, t * EV2KJ_C);
    }
}

// ---------------- edge backward: single tile/wave; DS-strided D-stage (bank-conflict fix) ----------------
// LDS per wave (f16): sR1[1280] = A[0,640) | T[640,1280); Dq (uint, stride DS) overlays [0,1146).
//                     sR2[1152] = Q[0,640); Dt overlays [0,1146).
__global__ __launch_bounds__(256) void edge_bwd_mfma(
    const float* __restrict__ pos, const int* __restrict__ types,
    const int2* __restrict__ order_sd,
    const float* __restrict__ Wr1, const float* __restrict__ br1,
    const float* __restrict__ Wr2, const float* __restrict__ temb,
    const float* __restrict__ g_all,
    float* __restrict__ forces, int E)
{
    __shared__ __align__(16) _Float16 sR1[4][1280];
    __shared__ __align__(16) _Float16 sR2[4][1152];
    __shared__ int   sTy[4][16];
    __shared__ float sTemb[96];

    const int lane = threadIdx.x & 63;
    const int l16 = lane & 15;
    const int w = threadIdx.x >> 6;
    const int gbase = blockIdx.x * 64 + w * 16;

    for (int i = threadIdx.x; i < 96; i += 256) sTemb[i] = temb[i];
    __syncthreads();

    const int kb = (lane >> 4) * 8, nb = lane & 15;
    f16x8 bz[2], bt[2];
    #pragma unroll
    for (int t = 0; t < 2; t++)
        #pragma unroll
        for (int j = 0; j < 8; j++) {
            int k = kb + j;
            bz[t][j] = (k < 8) ? (_Float16)Wr1[k * FDIM + t * 16 + nb] : (_Float16)0.0f;
            bt[t][j] = (k >= 8 && k < 16) ? (_Float16)Wr1[(k - 8) * FDIM + t * 16 + nb] : (_Float16)0.0f;
        }
    f16x8 bf[4];
    #pragma unroll
    for (int t = 0; t < 4; t++)
        #pragma unroll
        for (int j = 0; j < 8; j++)
            bf[t][j] = (_Float16)Wr2[(kb + j) * 64 + t * 16 + nb];

    // ---- phase 0: edge descriptors for ALL lanes (4 lanes mirror each edge) ----
    const int p_e = gbase + l16;
    const bool valid = (p_e < E);
    int2 sd = valid ? order_sd[p_e] : make_int2(0, 0);
    const int srcI = sd.x, dstI = sd.y;
    const int key = valid ? sd.y : (-2 - l16);

    float rinv = 1.f, env = 0.f, denv = 0.f, rhx = 0.f, rhy = 0.f, rhz = 0.f;
    if (lane < 16) {
        float rx = (pos[sd.y * 3 + 0] - pos[sd.x * 3 + 0]) * NM2A_C;
        float ry = (pos[sd.y * 3 + 1] - pos[sd.x * 3 + 1]) * NM2A_C;
        float rz = (pos[sd.y * 3 + 2] - pos[sd.x * 3 + 2]) * NM2A_C;
        float r2 = rx * rx + ry * ry + rz * rz + 1e-12f;
        float r = sqrtf(r2);
        rinv = 1.0f / r;
        float x = r * (1.0f / RCUT_C);
        float x2 = x * x, x4 = x2 * x2, x5 = x4 * x, x6 = x4 * x2, x7 = x6 * x, x8 = x6 * x2;
        env = (x < 1.0f) ? (1.0f - 28.0f * x6 + 48.0f * x7 - 21.0f * x8) : 0.0f;
        denv = (x < 1.0f) ? (-168.0f * x5 + 336.0f * x6 - 168.0f * x7) * (1.0f / RCUT_C) : 0.0f;
        rhx = rx * rinv; rhy = ry * rinv; rhz = rz * rinv;

        float th = PI_F * x, s1, c1;
        __sincosf(th, &s1, &c1);
        float sp = 0.0f, sn = s1, cp = 1.0f, cn = c1;
        _Float16 av[16];
        #pragma unroll
        for (int n = 0; n < NBASIS; n++) {
            float basis = sn * rinv;
            float dbdr = (PI_F * (float)(n + 1) * (1.0f / RCUT_C)) * cn * rinv - basis * rinv;
            av[n] = (_Float16)basis;
            av[8 + n] = (_Float16)dbdr;
            float snx = 2.0f * c1 * sn - sp; sp = sn; sn = snx;
            float cnx = 2.0f * c1 * cn - cp; cp = cn; cn = cnx;
        }
        _Float16* dstA = &sR1[w][l16 * QP];
        *(f16x8*)&dstA[0] = *(f16x8*)&av[0];
        *(f16x8*)&dstA[8] = *(f16x8*)&av[8];
        *(float4*)&dstA[16] = make_float4(0.f, 0.f, 0.f, 0.f);
        *(float4*)&dstA[24] = make_float4(0.f, 0.f, 0.f, 0.f);
        sTy[w][l16] = types[sd.x];
    }

    // ---- phase 1: 4 MFMAs (z, tacc over 2 ch-tiles); silu/tf -> Q (sR2) / T (sR1 upper) ----
    {
        const int me = lane & 15;
        f16x8 a1 = *(const f16x8*)&sR1[w][me * QP + kb];
        const f32x4 z4 = {0.f, 0.f, 0.f, 0.f};
        f32x4 Dz0 = __builtin_amdgcn_mfma_f32_16x16x32_f16(a1, bz[0], z4, 0, 0, 0);
        f32x4 Dz1 = __builtin_amdgcn_mfma_f32_16x16x32_f16(a1, bz[1], z4, 0, 0, 0);
        f32x4 Dt0 = __builtin_amdgcn_mfma_f32_16x16x32_f16(a1, bt[0], z4, 0, 0, 0);
        f32x4 Dt1 = __builtin_amdgcn_mfma_f32_16x16x32_f16(a1, bt[1], z4, 0, 0, 0);
        const int f0 = lane & 15, e0 = (lane >> 4) * 4;
        const float bb0 = br1[f0], bb1 = br1[16 + f0];
        #pragma unroll
        for (int t = 0; t < 2; t++) {
            f32x4 Dz = t ? Dz1 : Dz0;
            f32x4 Dt = t ? Dt1 : Dt0;
            float bb = t ? bb1 : bb0;
            #pragma unroll
            for (int r = 0; r < 4; r++) {
                float z = Dz[r] + bb;
                float sg = sigmoidf_(z);
                sR2[w][(e0 + r) * QP + t * 16 + f0] = (_Float16)(z * sg);
                sR1[w][640 + (e0 + r) * QP + t * 16 + f0] =
                    (_Float16)((sg * (1.0f + z * (1.0f - sg))) * Dt[r]);
            }
        }
    }

    // ---- phase 2: 8 MFMAs; fold hs; pack (x, x+32) channel pairs; DS-strided stores ----
    {
        const int me = lane & 15;
        f16x8 aq = *(const f16x8*)&sR2[w][me * QP + kb];
        f16x8 at = *(const f16x8*)&sR1[w][640 + me * QP + kb];
        const int cb = lane & 15, e0 = (lane >> 4) * 4;
        float hsv[2][4];   // [fpair][r]
        #pragma unroll
        for (int r = 0; r < 4; r++) {
            int ty = sTy[w][e0 + r];
            hsv[0][r] = sTemb[ty * 32 + cb];
            hsv[1][r] = sTemb[ty * 32 + 16 + cb];
        }
        const f32x4 z4 = {0.f, 0.f, 0.f, 0.f};
        unsigned int* DqU = (unsigned int*)&sR1[w][0];
        unsigned int* DtU = (unsigned int*)&sR2[w][0];
        #pragma unroll
        for (int fp = 0; fp < 2; fp++) {
            f32x4 q0 = __builtin_amdgcn_mfma_f32_16x16x32_f16(aq, bf[fp],     z4, 0, 0, 0);
            f32x4 q1 = __builtin_amdgcn_mfma_f32_16x16x32_f16(aq, bf[fp + 2], z4, 0, 0, 0);
            f32x4 t0 = __builtin_amdgcn_mfma_f32_16x16x32_f16(at, bf[fp],     z4, 0, 0, 0);
            f32x4 t1 = __builtin_amdgcn_mfma_f32_16x16x32_f16(at, bf[fp + 2], z4, 0, 0, 0);
            unsigned int pq[4], pt[4];
            #pragma unroll
            for (int r = 0; r < 4; r++) {
                float h = hsv[fp][r];
                pq[r] = pk2_(q0[r] * h, q1[r] * h);
                pt[r] = pk2_(t0[r] * h, t1[r] * h);
            }
            const int f = fp * 16 + cb;
            *(uint2*)&DqU[f * DS + e0]     = make_uint2(pq[0], pq[1]);
            *(uint2*)&DqU[f * DS + e0 + 2] = make_uint2(pq[2], pq[3]);
            *(uint2*)&DtU[f * DS + e0]     = make_uint2(pt[0], pt[1]);
            *(uint2*)&DtU[f * DS + e0 + 2] = make_uint2(pt[2], pt[3]);
        }
    }

    // ---- phase 3: epilogue; 4 lanes per edge (f split in 4), 2-step reduce ----
    {
        const unsigned int* DqU = (const unsigned int*)&sR1[w][0];
        const unsigned int* DtU = (const unsigned int*)&sR2[w][0];
        const int fb = (lane >> 4) * 8;     // f-group: 0..7, 8..15, 16..23, 24..31
        const float* gb = g_all + (size_t)dstI * 128;
        float Aa = 0.f, Bb = 0.f, Cc = 0.f, Pp = 0.f;
        float Ap = 0.f, Bp = 0.f, Cp = 0.f, Qq = 0.f;
        #pragma unroll
        for (int ff = 0; ff < 8; ff++) {
            const int f = fb + ff;
            unsigned int qp = DqU[f * DS + l16];
            unsigned int tp = DtU[f * DS + l16];
            float rw0 = lo16_(qp), rw1 = hi16_(qp);
            float u0 = lo16_(tp), u1 = hi16_(tp);
            float4 g4 = *(const float4*)(gb + f * 4);
            Pp += rw0 * g4.x; Qq += u0 * g4.x;
            Aa += rw1 * g4.y; Bb += rw1 * g4.z; Cc += rw1 * g4.w;
            Ap += u1 * g4.y;  Bp += u1 * g4.z;  Cp += u1 * g4.w;
        }
        // reduce across the 4 f-groups (lane bits 4 and 5)
        Pp += __shfl_xor(Pp, 16, 64); Qq += __shfl_xor(Qq, 16, 64);
        Aa += __shfl_xor(Aa, 16, 64); Bb += __shfl_xor(Bb, 16, 64);
        Cc += __shfl_xor(Cc, 16, 64); Ap += __shfl_xor(Ap, 16, 64);
        Bp += __shfl_xor(Bp, 16, 64); Cp += __shfl_xor(Cp, 16, 64);
        Pp += __shfl_xor(Pp, 32, 64); Qq += __shfl_xor(Qq, 32, 64);
        Aa += __shfl_xor(Aa, 32, 64); Bb += __shfl_xor(Bb, 32, 64);
        Cc += __shfl_xor(Cc, 32, 64); Ap += __shfl_xor(Ap, 32, 64);
        Bp += __shfl_xor(Bp, 32, 64); Cp += __shfl_xor(Cp, 32, 64);

        if (lane < 16) {
            float Gx = env * Aa, Gy = env * Bb, Gz = env * Cc;
            float genv = Pp + rhx * Aa + rhy * Bb + rhz * Cc;
            float pc = env * (Qq + rhx * Ap + rhy * Bp + rhz * Cp) + genv * denv;
            float dotg = Gx * rhx + Gy * rhy + Gz * rhz;
            float cx = pc * rhx + (Gx - dotg * rhx) * rinv;
            float cy = pc * rhy + (Gy - dotg * rhy) * rinv;
            float cz = pc * rhz + (Gz - dotg * rhz) * rinv;

            const float SC = EV2KJ_C * NM2A_C;
            if (valid) {
                unsafeAtomicAdd(&forces[(size_t)srcI * 3 + 0], SC * cx);
                unsafeAtomicAdd(&forces[(size_t)srcI * 3 + 1], SC * cy);
                unsafeAtomicAdd(&forces[(size_t)srcI * 3 + 2], SC * cz);
            }
            // segmented inclusive scan over contiguous dst runs (16 edges)
            int kk = key;
            #pragma unroll
            for (int d = 1; d < 16; d <<= 1) {
                float ux = __shfl_up(cx, d, 32);
                float uy = __shfl_up(cy, d, 32);
                float uz = __shfl_up(cz, d, 32);
                int uk = __shfl_up(kk, d, 32);
                if (l16 >= d && uk == kk) { cx += ux; cy += uy; cz += uz; }
            }
            int nk = __shfl_down(kk, 1, 32);
            bool leader = (l16 == 15) || (nk != kk);
            if (valid && leader) {
                unsafeAtomicAdd(&forces[(size_t)dstI * 3 + 0], -SC * cx);
                unsafeAtomicAdd(&forces[(size_t)dstI * 3 + 1], -SC * cy);
                unsafeAtomicAdd(&forces[(size_t)dstI * 3 + 2], -SC * cz);
            }
        }
    }
}

// ---------------- reductions & correction ----------------
__global__ __launch_bounds__(256) void reduce_net(
    const float* __restrict__ f, const float* __restrict__ masses,
    float* __restrict__ accum, int N)
{
    float nx = 0, ny = 0, nz = 0, ms = 0;
    for (int i = blockIdx.x * 256 + threadIdx.x; i < N; i += gridDim.x * 256) {
        nx += f[i * 3 + 0]; ny += f[i * 3 + 1]; nz += f[i * 3 + 2]; ms += masses[i];
    }
    #pragma unroll
    for (int m = 32; m; m >>= 1) {
        nx += __shfl_xor(nx, m, 64);
        ny += __shfl_xor(ny, m, 64);
        nz += __shfl_xor(nz, m, 64);
        ms += __shfl_xor(ms, m, 64);
    }
    __shared__ float red[4][4];
    int w = threadIdx.x >> 6;
    if ((threadIdx.x & 63) == 0) { red[w][0] = nx; red[w][1] = ny; red[w][2] = nz; red[w][3] = ms; }
    __syncthreads();
    if (threadIdx.x == 0) {
        float a0 = 0, a1 = 0, a2 = 0, a3 = 0;
        for (int i = 0; i < 4; i++) { a0 += red[i][0]; a1 += red[i][1]; a2 += red[i][2]; a3 += red[i][3]; }
        unsafeAtomicAdd(accum + 0, a0);
        unsafeAtomicAdd(accum + 1, a1);
        unsafeAtomicAdd(accum + 2, a2);
        unsafeAtomicAdd(accum + 3, a3);
    }
}

__global__ __launch_bounds__(256) void correct_forces(
    float* __restrict__ f, const float* __restrict__ masses,
    const float* __restrict__ accum, int N)
{
    int i = blockIdx.x * 256 + threadIdx.x;
    if (i < N) {
        float c = masses[i] / accum[3];
        f[i * 3 + 0] -= c * accum[0];
        f[i * 3 + 1] -= c * accum[1];
        f[i * 3 + 2] -= c * accum[2];
    }
}

extern "C" void kernel_launch(void* const* d_in, const int* in_sizes, int n_in,
                              void* d_out, int out_size, void* d_ws, size_t ws_size,
                              hipStream_t stream)
{
    (void)n_in; (void)ws_size;
    const float* pos    = (const float*)d_in[0];
    const float* masses = (const float*)d_in[1];
    const float* temb   = (const float*)d_in[2];
    const float* Wr1    = (const float*)d_in[3];
    const float* br1    = (const float*)d_in[4];
    const float* Wr2    = (const float*)d_in[5];
    const float* Wself  = (const float*)d_in[6];
    const float* Wo1    = (const float*)d_in[7];
    const float* bo1    = (const float*)d_in[8];
    const float* Wo2    = (const float*)d_in[9];
    const int* types    = (const int*)d_in[10];
    const int* eidx     = (const int*)d_in[11];
    const int N = in_sizes[1];
    const int E = in_sizes[11] / 2;

    float* out = (float*)d_out;
    float* forces = out + 1;

    float* ws = (float*)d_ws;
    float* s_acc = ws;                               // N*32
    float* v_acc = s_acc + (size_t)N * FDIM;         // N*96
    float* g_all = v_acc + (size_t)N * 96;           // N*128 (packed gradients)
    float* accum = g_all + (size_t)N * 128;          // 4
    int* counts = (int*)(accum + 4);                 // N
    int* cursor = counts + N;                        // N
    int2* order_sd = (int2*)(cursor + N);            // E int2
    int nScan = (N + SCH - 1) / SCH;
    int* bsum = (int*)(order_sd + E);                // nScan

    hipMemsetAsync(d_out, 0, (size_t)out_size * sizeof(float), stream);
    hipMemsetAsync(s_acc, 0, (size_t)N * 128 * sizeof(float), stream);
    hipMemsetAsync(counts, 0, (size_t)N * sizeof(int), stream);
    hipMemsetAsync(accum, 0, 4 * sizeof(float), stream);

    hist_dst<<<2048, 256, 0, stream>>>(eidx, counts, E);
    scan_partial<<<nScan, 256, 0, stream>>>(counts, bsum, N);
    scan_bsum<<<1, 64, 0, stream>>>(bsum, nScan);
    scan_write<<<nScan, 256, 0, stream>>>(counts, bsum, cursor, N);
    scatter_edges<<<2048, 256, 0, stream>>>(eidx, cursor, order_sd, E);

    int nAtomBlocks = (N + 63) / 64;
    int nFwdBlocks = (E + 127) / 128;
    int nBwdBlocks = (E + 63) / 64;
    edge_fwd_mfma<<<nFwdBlocks, 256, 0, stream>>>(pos, types, order_sd,
                                                  Wr1, br1, Wr2, temb,
                                                  s_acc, v_acc, E);
    atom_mlp<<<nAtomBlocks, 256, 0, stream>>>(types, temb, Wself, Wo1, bo1, Wo2,
                                              s_acc, v_acc, g_all, out, N);
    edge_bwd_mfma<<<nBwdBlocks, 256, 0, stream>>>(pos, types, order_sd,
                                                  Wr1, br1, Wr2, temb,
                                                  g_all, forces, E);
    reduce_net<<<64, 256, 0, stream>>>(forces, masses, accum, N);
    correct_forces<<<(N + 255) / 256, 256, 0, stream>>>(forces, masses, accum, N);
}